// Round 1
// baseline (5263.066 us; speedup 1.0000x reference)
//
#include <hip/hip_runtime.h>
#include <hip/hip_bf16.h>

typedef unsigned short u16;

#define NB 128
#define BANDS 30
#define HWD 15
#define NPIX 225
#define DIMC 512
#define NHEAD 8
#define HD 64
#define NSPA 226
#define NSPE 31
#define EPSF 1e-5f

__device__ __forceinline__ float b2f(u16 u) { return __uint_as_float(((unsigned)u) << 16); }
__device__ __forceinline__ u16 f2b(float f) {
  __hip_bfloat16 h = __float2bfloat16(f);
  return *reinterpret_cast<u16*>(&h);
}

// ---------------- CLS row init: xs[:,0,:], ys[:,0,:] ----------------
__global__ __launch_bounds__(256) void cls_init_k(const float* __restrict__ spa_cls,
    const float* __restrict__ spe_cls, const float* __restrict__ spa_pos,
    const float* __restrict__ spe_pos, float* __restrict__ xs, float* __restrict__ ys) {
  int b = blockIdx.x, t = threadIdx.x;
  int d0 = t, d1 = t + 256;
  xs[(size_t)b * NSPA * DIMC + d0] = spa_cls[d0] + spa_pos[d0];
  xs[(size_t)b * NSPA * DIMC + d1] = spa_cls[d1] + spa_pos[d1];
  ys[(size_t)b * NSPE * DIMC + d0] = spe_cls[d0] + spe_pos[d0];
  ys[(size_t)b * NSPE * DIMC + d1] = spe_cls[d1] + spe_pos[d1];
}

// ------------- conv stem 30->512 + BN + ReLU + transpose + pos -> xs tokens 1..225 -------------
__global__ __launch_bounds__(256) void conv_spa_k(const float* __restrict__ x,
    const float* __restrict__ w, const float* __restrict__ cb, const float* __restrict__ g,
    const float* __restrict__ bb, const float* __restrict__ bm, const float* __restrict__ bv,
    const float* __restrict__ spa_pos, float* __restrict__ xs) {
  __shared__ float xl[BANDS * NPIX];
  int b = blockIdx.x, og = blockIdx.y;
  int t = threadIdx.x;
  for (int idx = t; idx < BANDS * NPIX; idx += 256) xl[idx] = x[(size_t)b * BANDS * NPIX + idx];
  __syncthreads();
  int o = og * 32 + (t & 31);
  int p0 = t >> 5;  // 0..7
  float inv = g[o] * rsqrtf(bv[o] + EPSF);
  float beta = bb[o] - bm[o] * inv;
  float bias = cb[o];
  float acc[29];
#pragma unroll
  for (int k = 0; k < 29; k++) acc[k] = bias;
  const float* wo = w + (size_t)o * (BANDS * 9);
  for (int c = 0; c < BANDS; c++) {
    float w9[9];
#pragma unroll
    for (int q = 0; q < 9; q++) w9[q] = wo[c * 9 + q];
    const float* xc = xl + c * NPIX;
#pragma unroll
    for (int k = 0; k < 29; k++) {
      int p = p0 + (k << 3);
      if (p < NPIX) {
        int i = p / 15, j = p - i * 15;
#pragma unroll
        for (int di = 0; di < 3; di++) {
          int ii = i + di - 1;
          if ((unsigned)ii < 15u) {
#pragma unroll
            for (int dj = 0; dj < 3; dj++) {
              int jj = j + dj - 1;
              if ((unsigned)jj < 15u) acc[k] = fmaf(w9[di * 3 + dj], xc[ii * 15 + jj], acc[k]);
            }
          }
        }
      }
    }
  }
#pragma unroll
  for (int k = 0; k < 29; k++) {
    int p = p0 + (k << 3);
    if (p < NPIX) {
      float v = fmaxf(acc[k] * inv + beta, 0.0f);
      xs[((size_t)b * NSPA + p + 1) * DIMC + o] = v + spa_pos[(size_t)(p + 1) * DIMC + o];
    }
  }
}

// ------------- per-band CNN conv 1->128 + BN + ReLU + spatial mean -> pooled (3840,128) -------------
__global__ __launch_bounds__(128) void cnn_conv_k(const float* __restrict__ x,
    const float* __restrict__ w, const float* __restrict__ cb, const float* __restrict__ g,
    const float* __restrict__ bb, const float* __restrict__ bm, const float* __restrict__ bv,
    float* __restrict__ pooled) {
  __shared__ float img[NPIX];
  int band = blockIdx.x;  // 0..3839
  int t = threadIdx.x;
  for (int idx = t; idx < NPIX; idx += 128) img[idx] = x[(size_t)band * NPIX + idx];
  __syncthreads();
  int ch = t;
  float w9[9];
#pragma unroll
  for (int q = 0; q < 9; q++) w9[q] = w[ch * 9 + q];
  float inv = g[ch] * rsqrtf(bv[ch] + EPSF);
  float beta = bb[ch] - bm[ch] * inv;
  float bias = cb[ch];
  float sum = 0.0f;
  for (int p = 0; p < NPIX; p++) {
    int i = p / 15, j = p - i * 15;
    float a = bias;
#pragma unroll
    for (int di = 0; di < 3; di++) {
      int ii = i + di - 1;
      if ((unsigned)ii < 15u) {
#pragma unroll
        for (int dj = 0; dj < 3; dj++) {
          int jj = j + dj - 1;
          if ((unsigned)jj < 15u) a = fmaf(w9[di * 3 + dj], img[ii * 15 + jj], a);
        }
      }
    }
    sum += fmaxf(a * inv + beta, 0.0f);
  }
  pooled[(size_t)band * 128 + ch] = sum * (1.0f / 225.0f);
}

// ------------- fc 128->512 + ReLU + pos -> ys tokens 1..30 -------------
__global__ __launch_bounds__(256) void fc_spe_k(const float* __restrict__ pooled,
    const float* __restrict__ fw, const float* __restrict__ fb,
    const float* __restrict__ spe_pos, float* __restrict__ ys) {
  __shared__ float rowv[128];
  int r = blockIdx.x;  // 0..3839
  int t = threadIdx.x;
  if (t < 128) rowv[t] = pooled[(size_t)r * 128 + t];
  __syncthreads();
  int b = r / BANDS, band = r % BANDS;
  for (int n = t; n < DIMC; n += 256) {
    float a = fb[n];
    for (int k2 = 0; k2 < 128; k2++) a = fmaf(rowv[k2], fw[(size_t)n * 128 + k2], a);
    a = fmaxf(a, 0.0f);
    ys[((size_t)b * NSPE + band + 1) * DIMC + n] = a + spe_pos[(size_t)(band + 1) * DIMC + n];
  }
}

// ------------- LayerNorm over 512 with CLS-row gather; f32 in -> bf16 out -------------
__global__ __launch_bounds__(256) void ln_k(const float* __restrict__ src_main,
    const float* __restrict__ src_cls, size_t stride_main, size_t stride_cls, int Ntok,
    const float* __restrict__ w, const float* __restrict__ bprm, u16* __restrict__ out) {
  int row = blockIdx.x;
  int b = row / Ntok, tk = row % Ntok;
  const float* src = (tk == 0) ? (src_cls + (size_t)b * stride_cls)
                               : (src_main + (size_t)b * stride_main + (size_t)tk * DIMC);
  int t = threadIdx.x;
  float x0 = src[t], x1 = src[t + 256];
  float s = x0 + x1, sq = x0 * x0 + x1 * x1;
  for (int off = 32; off; off >>= 1) { s += __shfl_down(s, off); sq += __shfl_down(sq, off); }
  __shared__ float sa[4], sb4[4];
  int wid = t >> 6;
  if ((t & 63) == 0) { sa[wid] = s; sb4[wid] = sq; }
  __syncthreads();
  s = sa[0] + sa[1] + sa[2] + sa[3];
  sq = sb4[0] + sb4[1] + sb4[2] + sb4[3];
  float mean = s * (1.0f / 512.0f);
  float var = sq * (1.0f / 512.0f) - mean * mean;
  float rstd = rsqrtf(var + EPSF);
  out[(size_t)row * DIMC + t] = f2b((x0 - mean) * rstd * w[t] + bprm[t]);
  out[(size_t)row * DIMC + t + 256] = f2b((x1 - mean) * rstd * w[t + 256] + bprm[t + 256]);
}

// ------------- final LN on CLS tokens -> f32 cls buffer (B,1024) -------------
__global__ __launch_bounds__(256) void ln_cls_k(const float* __restrict__ xs,
    const float* __restrict__ ys, const float* __restrict__ w1, const float* __restrict__ b1,
    const float* __restrict__ w2, const float* __restrict__ b2, float* __restrict__ cls) {
  int gb = blockIdx.x;
  int half = gb & 1, b = gb >> 1;
  const float* src = half ? (ys + (size_t)b * NSPE * DIMC) : (xs + (size_t)b * NSPA * DIMC);
  const float* w = half ? w2 : w1;
  const float* bp = half ? b2 : b1;
  int t = threadIdx.x;
  float x0 = src[t], x1 = src[t + 256];
  float s = x0 + x1, sq = x0 * x0 + x1 * x1;
  for (int off = 32; off; off >>= 1) { s += __shfl_down(s, off); sq += __shfl_down(sq, off); }
  __shared__ float sa[4], sb4[4];
  int wid = t >> 6;
  if ((t & 63) == 0) { sa[wid] = s; sb4[wid] = sq; }
  __syncthreads();
  s = sa[0] + sa[1] + sa[2] + sa[3];
  sq = sb4[0] + sb4[1] + sb4[2] + sb4[3];
  float mean = s * (1.0f / 512.0f);
  float var = sq * (1.0f / 512.0f) - mean * mean;
  float rstd = rsqrtf(var + EPSF);
  cls[(size_t)b * 1024 + half * DIMC + t] = (x0 - mean) * rstd * w[t] + bp[t];
  cls[(size_t)b * 1024 + half * DIMC + t + 256] = (x1 - mean) * rstd * w[t + 256] + bp[t + 256];
}

// ------------- tiled GEMM: out = act(A(bf16, MxK) @ W(f32, NxK)^T + bias) [+resid] -------------
// mode 0: bf16 out; mode 1: bf16 out + exact GELU; mode 2: f32 out + resid add
__global__ __launch_bounds__(256) void gemm_bt_k(const u16* __restrict__ A,
    const float* __restrict__ W, const float* __restrict__ bias, const float* __restrict__ resid,
    void* __restrict__ outp, int M, int N, int K, int mode) {
  __shared__ float As[32][64];
  __shared__ float Bs[32][64];
  const int t = threadIdx.x;
  const int n0 = blockIdx.x * 64;
  const int m0 = blockIdx.y * 64;
  const int tm = t >> 4, tn = t & 15;
  const int lm = t >> 2;         // 0..63
  const int lk = (t & 3) * 8;    // 0,8,16,24
  float acc[4][4] = {{0.f}};
  for (int kq = 0; kq < K; kq += 32) {
    uint4 av = *reinterpret_cast<const uint4*>(A + (size_t)(m0 + lm) * K + kq + lk);
    float4 w0 = *reinterpret_cast<const float4*>(W + (size_t)(n0 + lm) * K + kq + lk);
    float4 w1 = *reinterpret_cast<const float4*>(W + (size_t)(n0 + lm) * K + kq + lk + 4);
    __syncthreads();
    unsigned u[4] = {av.x, av.y, av.z, av.w};
#pragma unroll
    for (int q = 0; q < 4; q++) {
      As[lk + 2 * q + 0][lm] = __uint_as_float(u[q] << 16);
      As[lk + 2 * q + 1][lm] = __uint_as_float(u[q] & 0xffff0000u);
    }
    Bs[lk + 0][lm] = w0.x; Bs[lk + 1][lm] = w0.y; Bs[lk + 2][lm] = w0.z; Bs[lk + 3][lm] = w0.w;
    Bs[lk + 4][lm] = w1.x; Bs[lk + 5][lm] = w1.y; Bs[lk + 6][lm] = w1.z; Bs[lk + 7][lm] = w1.w;
    __syncthreads();
#pragma unroll
    for (int kk = 0; kk < 32; kk++) {
      float4 a = *reinterpret_cast<const float4*>(&As[kk][tm * 4]);
      float4 b = *reinterpret_cast<const float4*>(&Bs[kk][tn * 4]);
      float af[4] = {a.x, a.y, a.z, a.w};
      float bf[4] = {b.x, b.y, b.z, b.w};
#pragma unroll
      for (int i = 0; i < 4; i++)
#pragma unroll
        for (int j = 0; j < 4; j++) acc[i][j] = fmaf(af[i], bf[j], acc[i][j]);
    }
  }
#pragma unroll
  for (int i = 0; i < 4; i++) {
    int m = m0 + tm * 4 + i;
#pragma unroll
    for (int j = 0; j < 4; j++) {
      int n = n0 + tn * 4 + j;
      float v = acc[i][j] + bias[n];
      if (mode == 1) v = 0.5f * v * (1.0f + erff(v * 0.70710678118f));
      if (mode == 2) {
        float* of = (float*)outp;
        of[(size_t)m * N + n] = v + resid[(size_t)m * N + n];
      } else {
        u16* ob = (u16*)outp;
        ob[(size_t)m * N + n] = f2b(v);
      }
    }
  }
}

// ------------- flash attention: qkv (B*N, 1536) bf16 -> o (B*N, 512) bf16 -------------
__global__ __launch_bounds__(256) void flash_k(const u16* __restrict__ qkv, u16* __restrict__ o,
                                               int N, int nqt, float scale) {
  __shared__ u16 Qs[64][68], Ks[64][68], Vs[64][68], Ps[64][68];
  int blk = blockIdx.x;
  int qt = blk % nqt;
  int bh = blk / nqt;
  int h = bh % NHEAD;
  int b = bh / NHEAD;
  const int t = threadIdx.x;
  const int tm = t >> 4, tn = t & 15;
  const size_t rs = 3 * DIMC;
  const size_t base = (size_t)b * N * rs;
  for (int idx = t; idx < 64 * 64; idx += 256) {
    int d = idx & 63, r = idx >> 6;
    int n = qt * 64 + r;
    Qs[d][r] = (n < N) ? qkv[base + (size_t)n * rs + h * HD + d] : (u16)0;
  }
  float m_i[4], l_i[4], oacc[4][4];
#pragma unroll
  for (int i = 0; i < 4; i++) {
    m_i[i] = -1e30f; l_i[i] = 0.f;
#pragma unroll
    for (int j = 0; j < 4; j++) oacc[i][j] = 0.f;
  }
  int nkt = (N + 63) >> 6;
  for (int kt = 0; kt < nkt; kt++) {
    __syncthreads();
    for (int idx = t; idx < 64 * 64; idx += 256) {
      int d = idx & 63, c = idx >> 6;
      int n = kt * 64 + c;
      u16 kv = 0, vv = 0;
      if (n < N) {
        kv = qkv[base + (size_t)n * rs + DIMC + h * HD + d];
        vv = qkv[base + (size_t)n * rs + 2 * DIMC + h * HD + d];
      }
      Ks[d][c] = kv;
      Vs[c][d] = vv;
    }
    __syncthreads();
    float s[4][4] = {{0.f}};
#pragma unroll 8
    for (int kk = 0; kk < 64; kk++) {
      ushort4 qa = *reinterpret_cast<const ushort4*>(&Qs[kk][tm * 4]);
      ushort4 kb = *reinterpret_cast<const ushort4*>(&Ks[kk][tn * 4]);
      float qf[4] = {b2f(qa.x), b2f(qa.y), b2f(qa.z), b2f(qa.w)};
      float kf[4] = {b2f(kb.x), b2f(kb.y), b2f(kb.z), b2f(kb.w)};
#pragma unroll
      for (int i = 0; i < 4; i++)
#pragma unroll
        for (int j = 0; j < 4; j++) s[i][j] = fmaf(qf[i], kf[j], s[i][j]);
    }
#pragma unroll
    for (int i = 0; i < 4; i++)
#pragma unroll
      for (int j = 0; j < 4; j++) {
        int n = kt * 64 + tn * 4 + j;
        s[i][j] = (n < N) ? s[i][j] * scale : -1e30f;
      }
#pragma unroll
    for (int i = 0; i < 4; i++) {
      float rmax = fmaxf(fmaxf(s[i][0], s[i][1]), fmaxf(s[i][2], s[i][3]));
      for (int off = 1; off <= 8; off <<= 1) rmax = fmaxf(rmax, __shfl_xor(rmax, off));
      float mn = fmaxf(m_i[i], rmax);
      float corr = __expf(m_i[i] - mn);
      m_i[i] = mn;
      float rsum = 0.f;
#pragma unroll
      for (int j = 0; j < 4; j++) {
        float p = __expf(s[i][j] - mn);
        s[i][j] = p;
        rsum += p;
      }
      for (int off = 1; off <= 8; off <<= 1) rsum += __shfl_xor(rsum, off);
      l_i[i] = l_i[i] * corr + rsum;
#pragma unroll
      for (int j = 0; j < 4; j++) oacc[i][j] *= corr;
#pragma unroll
      for (int j = 0; j < 4; j++) Ps[tn * 4 + j][tm * 4 + i] = f2b(s[i][j]);
    }
    __syncthreads();
#pragma unroll 8
    for (int mm = 0; mm < 64; mm++) {
      ushort4 pa = *reinterpret_cast<const ushort4*>(&Ps[mm][tm * 4]);
      ushort4 vb = *reinterpret_cast<const ushort4*>(&Vs[mm][tn * 4]);
      float pf[4] = {b2f(pa.x), b2f(pa.y), b2f(pa.z), b2f(pa.w)};
      float vf[4] = {b2f(vb.x), b2f(vb.y), b2f(vb.z), b2f(vb.w)};
#pragma unroll
      for (int i = 0; i < 4; i++)
#pragma unroll
        for (int j = 0; j < 4; j++) oacc[i][j] = fmaf(pf[i], vf[j], oacc[i][j]);
    }
  }
#pragma unroll
  for (int i = 0; i < 4; i++) {
    int n = qt * 64 + tm * 4 + i;
    if (n < N) {
      float invl = 1.0f / l_i[i];
#pragma unroll
      for (int j = 0; j < 4; j++)
        o[((size_t)b * N + n) * DIMC + h * HD + tn * 4 + j] = f2b(oacc[i][j] * invl);
    }
  }
}

// ------------- residual combine with CLS swap (in-place xs, ys) -------------
__global__ __launch_bounds__(256) void combine_k(float* __restrict__ xs, float* __restrict__ ys,
    const u16* __restrict__ x_, const u16* __restrict__ y_) {
  int r = blockIdx.x;
  int b = r / (NSPA + NSPE);
  int tk = r % (NSPA + NSPE);
  int t = threadIdx.x;
  if (tk < NSPA) {
    size_t xrow = ((size_t)b * NSPA + tk) * DIMC;
    for (int d = t; d < DIMC; d += 256) {
      if (tk == 0)
        xs[xrow + d] = 2.0f * xs[xrow + d] + b2f(y_[((size_t)b * NSPE) * DIMC + d]);
      else
        xs[xrow + d] += b2f(x_[xrow + d]);
    }
  } else {
    int tt = tk - NSPA;
    size_t yrow = ((size_t)b * NSPE + tt) * DIMC;
    for (int d = t; d < DIMC; d += 256) {
      if (tt == 0)
        ys[yrow + d] = 2.0f * ys[yrow + d] + b2f(x_[((size_t)b * NSPA) * DIMC + d]);
      else
        ys[yrow + d] += b2f(y_[yrow + d]);
    }
  }
}

// ------------- head: out = cls @ head_w^T + head_b -------------
__global__ __launch_bounds__(256) void head_k(const float* __restrict__ cls,
    const float* __restrict__ hw, const float* __restrict__ hb, float* __restrict__ out) {
  __shared__ float cl[1024];
  __shared__ float part[256];
  int b = blockIdx.x, t = threadIdx.x;
  for (int idx = t; idx < 1024; idx += 256) cl[idx] = cls[(size_t)b * 1024 + idx];
  __syncthreads();
  int c = t >> 4, sl = t & 15;
  float p = 0.f;
  for (int j = 0; j < 64; j++) p += cl[sl * 64 + j] * hw[(size_t)c * 1024 + sl * 64 + j];
  part[t] = p;
  __syncthreads();
  if (sl == 0) {
    float sum = hb[c];
    for (int q = 0; q < 16; q++) sum += part[c * 16 + q];
    out[(size_t)b * 16 + c] = sum;
  }
}

extern "C" void kernel_launch(void* const* d_in, const int* in_sizes, int n_in,
                              void* d_out, int out_size, void* d_ws, size_t ws_size,
                              hipStream_t stream) {
  const float* x        = (const float*)d_in[0];
  const float* conv_h_w = (const float*)d_in[1];
  const float* conv_h_b = (const float*)d_in[2];
  const float* bn_h_g   = (const float*)d_in[3];
  const float* bn_h_b   = (const float*)d_in[4];
  const float* bn_h_m   = (const float*)d_in[5];
  const float* bn_h_v   = (const float*)d_in[6];
  const float* cnn_conv_w = (const float*)d_in[7];
  const float* cnn_conv_b = (const float*)d_in[8];
  const float* cnn_bn_g = (const float*)d_in[9];
  const float* cnn_bn_b = (const float*)d_in[10];
  const float* cnn_bn_m = (const float*)d_in[11];
  const float* cnn_bn_v = (const float*)d_in[12];
  const float* cnn_fc_w = (const float*)d_in[13];
  const float* cnn_fc_b = (const float*)d_in[14];
  const float* spa_cls  = (const float*)d_in[15];
  const float* spe_cls  = (const float*)d_in[16];
  const float* spa_pos  = (const float*)d_in[17];
  const float* spe_pos  = (const float*)d_in[18];
  const float* blk_n1_w = (const float*)d_in[19];
  const float* blk_n1_b = (const float*)d_in[20];
  const float* blk_n2_w = (const float*)d_in[21];
  const float* blk_n2_b = (const float*)d_in[22];
  const float* blk_qkv_w = (const float*)d_in[23];
  const float* blk_qkv_b = (const float*)d_in[24];
  const float* blk_proj_w = (const float*)d_in[25];
  const float* blk_proj_b = (const float*)d_in[26];
  const float* blk_fc1_w = (const float*)d_in[27];
  const float* blk_fc1_b = (const float*)d_in[28];
  const float* blk_fc2_w = (const float*)d_in[29];
  const float* blk_fc2_b = (const float*)d_in[30];
  const float* norm1_w  = (const float*)d_in[31];
  const float* norm1_b  = (const float*)d_in[32];
  const float* norm2_w  = (const float*)d_in[33];
  const float* norm2_b  = (const float*)d_in[34];
  const float* head_w   = (const float*)d_in[35];
  const float* head_b   = (const float*)d_in[36];

  char* ws = (char*)d_ws;
  size_t off = 0;
  auto take = [&](size_t bytes) -> char* {
    char* p = ws + off;
    off = (off + bytes + 255) & ~(size_t)255;
    return p;
  };
  const int Mx = NB * NSPA;  // 28928
  const int My = NB * NSPE;  // 3968
  float* xs   = (float*)take((size_t)Mx * DIMC * 4);
  float* ys   = (float*)take((size_t)My * DIMC * 4);
  u16* xin    = (u16*)take((size_t)Mx * DIMC * 2);   // also x_ and MLP ln_out
  u16* yin    = (u16*)take((size_t)My * DIMC * 2);   // also y_ and MLP ln_out (ys)
  u16* qkvx   = (u16*)take((size_t)Mx * 3 * DIMC * 2);  // also h1 (xs)
  u16* qkvy   = (u16*)take((size_t)My * 3 * DIMC * 2);  // also h1 (ys)
  u16* ox     = (u16*)take((size_t)Mx * DIMC * 2);
  u16* oy     = (u16*)take((size_t)My * DIMC * 2);
  float* clsb = (float*)take((size_t)NB * 1024 * 4);
  float* pooled = (float*)take((size_t)NB * BANDS * 128 * 4);

  // ---- stem ----
  cls_init_k<<<NB, 256, 0, stream>>>(spa_cls, spe_cls, spa_pos, spe_pos, xs, ys);
  conv_spa_k<<<dim3(NB, 16), 256, 0, stream>>>(x, conv_h_w, conv_h_b, bn_h_g, bn_h_b, bn_h_m,
                                               bn_h_v, spa_pos, xs);
  cnn_conv_k<<<NB * BANDS, 128, 0, stream>>>(x, cnn_conv_w, cnn_conv_b, cnn_bn_g, cnn_bn_b,
                                             cnn_bn_m, cnn_bn_v, pooled);
  fc_spe_k<<<NB * BANDS, 256, 0, stream>>>(pooled, cnn_fc_w, cnn_fc_b, spe_pos, ys);

  // ---- transformer blocks ----
  for (int i = 0; i < 2; i++) {
    const float* n1w = blk_n1_w + i * DIMC;
    const float* n1b = blk_n1_b + i * DIMC;
    const float* n2w = blk_n2_w + i * DIMC;
    const float* n2b = blk_n2_b + i * DIMC;
    const float* qkvW = blk_qkv_w + (size_t)i * 3 * DIMC * DIMC;
    const float* qkvB = blk_qkv_b + (size_t)i * 3 * DIMC;
    const float* projW = blk_proj_w + (size_t)i * DIMC * DIMC;
    const float* projB = blk_proj_b + (size_t)i * DIMC;
    const float* fc1W = blk_fc1_w + (size_t)i * DIMC * DIMC;
    const float* fc1B = blk_fc1_b + (size_t)i * DIMC;
    const float* fc2W = blk_fc2_w + (size_t)i * DIMC * DIMC;
    const float* fc2B = blk_fc2_b + (size_t)i * DIMC;

    ln_k<<<Mx, 256, 0, stream>>>(xs, ys, (size_t)NSPA * DIMC, (size_t)NSPE * DIMC, NSPA, n1w, n1b, xin);
    ln_k<<<My, 256, 0, stream>>>(ys, xs, (size_t)NSPE * DIMC, (size_t)NSPA * DIMC, NSPE, n1w, n1b, yin);

    gemm_bt_k<<<dim3(24, Mx / 64), 256, 0, stream>>>(xin, qkvW, qkvB, nullptr, qkvx, Mx, 1536, DIMC, 0);
    gemm_bt_k<<<dim3(24, My / 64), 256, 0, stream>>>(yin, qkvW, qkvB, nullptr, qkvy, My, 1536, DIMC, 0);

    flash_k<<<NB * NHEAD * 4, 256, 0, stream>>>(qkvx, ox, NSPA, 4, 0.125f);
    flash_k<<<NB * NHEAD * 1, 256, 0, stream>>>(qkvy, oy, NSPE, 1, 0.125f);

    gemm_bt_k<<<dim3(8, Mx / 64), 256, 0, stream>>>(ox, projW, projB, nullptr, xin, Mx, DIMC, DIMC, 0);
    gemm_bt_k<<<dim3(8, My / 64), 256, 0, stream>>>(oy, projW, projB, nullptr, yin, My, DIMC, DIMC, 0);

    combine_k<<<NB * (NSPA + NSPE), 256, 0, stream>>>(xs, ys, xin, yin);

    ln_k<<<Mx, 256, 0, stream>>>(xs, xs, (size_t)NSPA * DIMC, (size_t)NSPA * DIMC, NSPA, n2w, n2b, xin);
    gemm_bt_k<<<dim3(8, Mx / 64), 256, 0, stream>>>(xin, fc1W, fc1B, nullptr, qkvx, Mx, DIMC, DIMC, 1);
    gemm_bt_k<<<dim3(8, Mx / 64), 256, 0, stream>>>(qkvx, fc2W, fc2B, xs, xs, Mx, DIMC, DIMC, 2);

    ln_k<<<My, 256, 0, stream>>>(ys, ys, (size_t)NSPE * DIMC, (size_t)NSPE * DIMC, NSPE, n2w, n2b, yin);
    gemm_bt_k<<<dim3(8, My / 64), 256, 0, stream>>>(yin, fc1W, fc1B, nullptr, qkvy, My, DIMC, DIMC, 1);
    gemm_bt_k<<<dim3(8, My / 64), 256, 0, stream>>>(qkvy, fc2W, fc2B, ys, ys, My, DIMC, DIMC, 2);
  }

  // ---- head ----
  ln_cls_k<<<NB * 2, 256, 0, stream>>>(xs, ys, norm1_w, norm1_b, norm2_w, norm2_b, clsb);
  head_k<<<NB, 256, 0, stream>>>(clsb, head_w, head_b, (float*)d_out);
}

// Round 2
// 1689.472 us; speedup vs baseline: 3.1152x; 3.1152x over previous
//
#include <hip/hip_runtime.h>
#include <hip/hip_bf16.h>

typedef unsigned short u16;
typedef __attribute__((ext_vector_type(8))) short bf16x8;
typedef __attribute__((ext_vector_type(4))) float f32x4;

#define NB 128
#define BANDS 30
#define HWD 15
#define NPIX 225
#define DIMC 512
#define NHEAD 8
#define HD 64
#define NSPA 226
#define NSPE 31
#define EPSF 1e-5f
#define KCONV 288  // 270 padded to multiple of 32

__device__ __forceinline__ float b2f(u16 u) { return __uint_as_float(((unsigned)u) << 16); }
__device__ __forceinline__ u16 f2b(float f) {
  __hip_bfloat16 h = __float2bfloat16(f);
  return *reinterpret_cast<u16*>(&h);
}

#if __has_builtin(__builtin_amdgcn_global_load_lds)
#define HAVE_GLDS 1
__device__ __forceinline__ void gl_lds16(const void* g, void* l) {
  __builtin_amdgcn_global_load_lds((const __attribute__((address_space(1))) void*)g,
                                   (__attribute__((address_space(3))) void*)l, 16, 0, 0);
}
#else
#define HAVE_GLDS 0
#endif

// ---------------- weight f32 -> bf16 ----------------
__global__ __launch_bounds__(256) void cvt_k(const float* __restrict__ s, u16* __restrict__ d, int n) {
  for (int i = blockIdx.x * 256 + threadIdx.x; i < n; i += gridDim.x * 256) d[i] = f2b(s[i]);
}

// conv_h_w (512,270) -> padded bf16 (512,288)
__global__ __launch_bounds__(256) void convw_k(const float* __restrict__ w, u16* __restrict__ d) {
  int i = blockIdx.x * 256 + threadIdx.x;  // 512*288
  int r = i / KCONV, c = i - r * KCONV;
  d[i] = (c < 270) ? f2b(w[r * 270 + c]) : (u16)0;
}

// BN fold: sc = g/sqrt(v+eps), sh = (cb - m)*sc + b
__global__ __launch_bounds__(256) void bnprep_k(const float* __restrict__ g, const float* __restrict__ bb,
    const float* __restrict__ bm, const float* __restrict__ bv, const float* __restrict__ cb,
    float* __restrict__ sc, float* __restrict__ sh) {
  int n = blockIdx.x * 256 + threadIdx.x;
  if (n < DIMC) {
    float inv = g[n] * rsqrtf(bv[n] + EPSF);
    sc[n] = inv;
    sh[n] = (cb[n] - bm[n]) * inv + bb[n];
  }
}

// ---------------- im2col: x (128,30,15,15) f32 -> Acol (28800, 288) bf16 ----------------
__global__ __launch_bounds__(256) void im2col_k(const float* __restrict__ x, u16* __restrict__ Ac) {
  int idx = blockIdx.x * 256 + threadIdx.x;  // m*32 + chslot, total 28800*32
  if (idx >= 28800 * 32) return;
  int m = idx >> 5, chslot = idx & 31;
  int b = m / NPIX, p = m - b * NPIX;
  int i = p / 15, j = p - i * 15;
  u16* dst = Ac + (size_t)m * KCONV + chslot * 9;
  if (chslot >= BANDS) {  // pad cols 270..287 (chslot 30 -> 270..278, 31 -> 279..287)
#pragma unroll
    for (int q = 0; q < 9; q++) dst[q] = 0;
    return;
  }
  const float* xc = x + ((size_t)b * BANDS + chslot) * NPIX;
#pragma unroll
  for (int q = 0; q < 9; q++) {
    int di = q / 3, dj = q - di * 3;
    int ii = i + di - 1, jj = j + dj - 1;
    float v = ((unsigned)ii < 15u && (unsigned)jj < 15u) ? xc[ii * 15 + jj] : 0.f;
    dst[q] = f2b(v);
  }
}

// ---------------- CLS row init ----------------
__global__ __launch_bounds__(256) void cls_init_k(const float* __restrict__ spa_cls,
    const float* __restrict__ spe_cls, const float* __restrict__ spa_pos,
    const float* __restrict__ spe_pos, float* __restrict__ xs, float* __restrict__ ys) {
  int b = blockIdx.x, t = threadIdx.x;
  int d0 = t, d1 = t + 256;
  xs[(size_t)b * NSPA * DIMC + d0] = spa_cls[d0] + spa_pos[d0];
  xs[(size_t)b * NSPA * DIMC + d1] = spa_cls[d1] + spa_pos[d1];
  ys[(size_t)b * NSPE * DIMC + d0] = spe_cls[d0] + spe_pos[d0];
  ys[(size_t)b * NSPE * DIMC + d1] = spe_cls[d1] + spe_pos[d1];
}

// ------------- per-band CNN conv 1->128 + BN + ReLU + mean -> pooled (3840,128) bf16 -------------
__global__ __launch_bounds__(128) void cnn_conv_k(const float* __restrict__ x,
    const float* __restrict__ w, const float* __restrict__ cb, const float* __restrict__ g,
    const float* __restrict__ bb, const float* __restrict__ bm, const float* __restrict__ bv,
    u16* __restrict__ pooled) {
  __shared__ float img[NPIX];
  int band = blockIdx.x;
  int t = threadIdx.x;
  for (int idx = t; idx < NPIX; idx += 128) img[idx] = x[(size_t)band * NPIX + idx];
  __syncthreads();
  int ch = t;
  float w9[9];
#pragma unroll
  for (int q = 0; q < 9; q++) w9[q] = w[ch * 9 + q];
  float inv = g[ch] * rsqrtf(bv[ch] + EPSF);
  float beta = bb[ch] - bm[ch] * inv;
  float bias = cb[ch];
  float sum = 0.0f;
  for (int p = 0; p < NPIX; p++) {
    int i = p / 15, j = p - i * 15;
    float a = bias;
#pragma unroll
    for (int di = 0; di < 3; di++) {
      int ii = i + di - 1;
      if ((unsigned)ii < 15u) {
#pragma unroll
        for (int dj = 0; dj < 3; dj++) {
          int jj = j + dj - 1;
          if ((unsigned)jj < 15u) a = fmaf(w9[di * 3 + dj], img[ii * 15 + jj], a);
        }
      }
    }
    sum += fmaxf(a * inv + beta, 0.0f);
  }
  pooled[(size_t)band * 128 + ch] = f2b(sum * (1.0f / 225.0f));
}

// ---------------- LayerNorm (512) with CLS gather; f32 -> bf16 ----------------
__global__ __launch_bounds__(256) void ln_k(const float* __restrict__ src_main,
    const float* __restrict__ src_cls, size_t stride_main, size_t stride_cls, int Ntok,
    const float* __restrict__ w, const float* __restrict__ bprm, u16* __restrict__ out) {
  int row = blockIdx.x;
  int b = row / Ntok, tk = row % Ntok;
  const float* src = (tk == 0) ? (src_cls + (size_t)b * stride_cls)
                               : (src_main + (size_t)b * stride_main + (size_t)tk * DIMC);
  int t = threadIdx.x;
  float x0 = src[t], x1 = src[t + 256];
  float s = x0 + x1, sq = x0 * x0 + x1 * x1;
  for (int off = 32; off; off >>= 1) { s += __shfl_down(s, off); sq += __shfl_down(sq, off); }
  __shared__ float sa[4], sb4[4];
  int wid = t >> 6;
  if ((t & 63) == 0) { sa[wid] = s; sb4[wid] = sq; }
  __syncthreads();
  s = sa[0] + sa[1] + sa[2] + sa[3];
  sq = sb4[0] + sb4[1] + sb4[2] + sb4[3];
  float mean = s * (1.0f / 512.0f);
  float var = sq * (1.0f / 512.0f) - mean * mean;
  float rstd = rsqrtf(var + EPSF);
  out[(size_t)row * DIMC + t] = f2b((x0 - mean) * rstd * w[t] + bprm[t]);
  out[(size_t)row * DIMC + t + 256] = f2b((x1 - mean) * rstd * w[t + 256] + bprm[t + 256]);
}

// ---------------- final LN on CLS tokens -> f32 (B,1024) ----------------
__global__ __launch_bounds__(256) void ln_cls_k(const float* __restrict__ xs,
    const float* __restrict__ ys, const float* __restrict__ w1, const float* __restrict__ b1,
    const float* __restrict__ w2, const float* __restrict__ b2, float* __restrict__ cls) {
  int gb = blockIdx.x;
  int half = gb & 1, b = gb >> 1;
  const float* src = half ? (ys + (size_t)b * NSPE * DIMC) : (xs + (size_t)b * NSPA * DIMC);
  const float* w = half ? w2 : w1;
  const float* bp = half ? b2 : b1;
  int t = threadIdx.x;
  float x0 = src[t], x1 = src[t + 256];
  float s = x0 + x1, sq = x0 * x0 + x1 * x1;
  for (int off = 32; off; off >>= 1) { s += __shfl_down(s, off); sq += __shfl_down(sq, off); }
  __shared__ float sa[4], sb4[4];
  int wid = t >> 6;
  if ((t & 63) == 0) { sa[wid] = s; sb4[wid] = sq; }
  __syncthreads();
  s = sa[0] + sa[1] + sa[2] + sa[3];
  sq = sb4[0] + sb4[1] + sb4[2] + sb4[3];
  float mean = s * (1.0f / 512.0f);
  float var = sq * (1.0f / 512.0f) - mean * mean;
  float rstd = rsqrtf(var + EPSF);
  cls[(size_t)b * 1024 + half * DIMC + t] = (x0 - mean) * rstd * w[t] + bp[t];
  cls[(size_t)b * 1024 + half * DIMC + t + 256] = (x1 - mean) * rstd * w[t + 256] + bp[t + 256];
}

// ================= MFMA GEMM: C = A(bf16 MxK) @ Bw(bf16 NxK)^T =================
// 128x128 tile, 4 waves (2x2 of 64x64), BK=32, mfma_f32_16x16x32_bf16.
// LDS chunk-XOR swizzle: LDS[r][chunk c] holds global chunk c^(r&3); read chunk kg^(r&3).
// MODE 0: bf16 out = acc+bias            MODE 1: bf16 out = gelu(acc+bias)
// MODE 2: f32 out  = acc+bias+resid(aux0)
// MODE 3: conv scatter: xs[(b*226+p+1)*512+n] = relu(acc*sc[n]+sh[n]) + spa_pos  (aux0=sc,aux1=sh,aux2=pos)
// MODE 4: fc_spe scatter: ys[(b*31+band+1)*512+n] = relu(acc+bias) + spe_pos     (aux0=pos)
template <int MODE>
__global__ __launch_bounds__(256) void mgemm_k(const u16* __restrict__ A, const u16* __restrict__ Bw,
    const float* __restrict__ bias, float* outf, u16* outb, int M, int N, int K,
    const float* aux0, const float* aux1, const float* aux2) {
  __shared__ u16 As[128 * 32];
  __shared__ u16 Bs[128 * 32];
  const int t = threadIdx.x;
  const int wid = t >> 6, l = t & 63;
  const int wm = wid >> 1, wn = wid & 1;
  const int fr = l & 15, kg = l >> 4;
  const int n0 = blockIdx.x * 128, m0 = blockIdx.y * 128;
  const int sr = l >> 2;            // 0..15: row within 16-row staging slice
  const int sc4 = l & 3;            // linear chunk slot this lane's LDS bytes land in
  const int scg = sc4 ^ (sr & 3);   // XOR-swizzled source chunk
  const int rdsw = (fr & 3);        // read-side XOR

  f32x4 acc[4][4];
#pragma unroll
  for (int i = 0; i < 4; i++)
#pragma unroll
    for (int j = 0; j < 4; j++) acc[i][j] = (f32x4){0.f, 0.f, 0.f, 0.f};

  for (int kq = 0; kq < K; kq += 32) {
#if !HAVE_GLDS
    uint4 ra[2], rb[2];
#pragma unroll
    for (int i = 0; i < 2; i++) {
      int r = wid * 32 + i * 16 + sr;
      ra[i] = *reinterpret_cast<const uint4*>(A + (size_t)(m0 + r) * K + kq + scg * 8);
      rb[i] = *reinterpret_cast<const uint4*>(Bw + (size_t)(n0 + r) * K + kq + scg * 8);
    }
#endif
    __syncthreads();  // previous compute done before overwrite
#if HAVE_GLDS
#pragma unroll
    for (int i = 0; i < 2; i++) {
      int r = wid * 32 + i * 16 + sr;
      gl_lds16(A + (size_t)(m0 + r) * K + kq + scg * 8, &As[(wid * 32 + i * 16) * 32]);
      gl_lds16(Bw + (size_t)(n0 + r) * K + kq + scg * 8, &Bs[(wid * 32 + i * 16) * 32]);
    }
#else
#pragma unroll
    for (int i = 0; i < 2; i++) {
      int r = wid * 32 + i * 16 + sr;
      *reinterpret_cast<uint4*>(&As[r * 32 + sc4 * 8]) = ra[i];
      *reinterpret_cast<uint4*>(&Bs[r * 32 + sc4 * 8]) = rb[i];
    }
#endif
    __syncthreads();  // staged (vmcnt(0)+barrier drains the lds loads)
    bf16x8 af[4], bfr[4];
#pragma unroll
    for (int mi = 0; mi < 4; mi++) {
      int r = wm * 64 + mi * 16 + fr;
      af[mi] = *reinterpret_cast<const bf16x8*>(&As[r * 32 + (kg ^ rdsw) * 8]);
    }
#pragma unroll
    for (int nj = 0; nj < 4; nj++) {
      int n = wn * 64 + nj * 16 + fr;
      bfr[nj] = *reinterpret_cast<const bf16x8*>(&Bs[n * 32 + (kg ^ rdsw) * 8]);
    }
#pragma unroll
    for (int mi = 0; mi < 4; mi++)
#pragma unroll
      for (int nj = 0; nj < 4; nj++)
        acc[mi][nj] = __builtin_amdgcn_mfma_f32_16x16x32_bf16(af[mi], bfr[nj], acc[mi][nj], 0, 0, 0);
  }

  // epilogue: D[row=(kg*4+q)][col=fr] per 16x16 fragment
#pragma unroll
  for (int mi = 0; mi < 4; mi++) {
#pragma unroll
    for (int q = 0; q < 4; q++) {
      int m = m0 + wm * 64 + mi * 16 + kg * 4 + q;
#pragma unroll
      for (int nj = 0; nj < 4; nj++) {
        int n = n0 + wn * 64 + nj * 16 + fr;
        float v = acc[mi][nj][q];
        if (MODE == 0) {
          outb[(size_t)m * N + n] = f2b(v + bias[n]);
        } else if (MODE == 1) {
          float z = v + bias[n];
          outb[(size_t)m * N + n] = f2b(0.5f * z * (1.0f + erff(z * 0.70710678118f)));
        } else if (MODE == 2) {
          size_t idx = (size_t)m * N + n;
          outf[idx] = v + bias[n] + aux0[idx];
        } else if (MODE == 3) {
          int b = m / NPIX, p = m - b * NPIX;
          float z = fmaxf(v * aux0[n] + aux1[n], 0.f) + aux2[(size_t)(p + 1) * DIMC + n];
          outf[((size_t)b * NSPA + p + 1) * DIMC + n] = z;
        } else if (MODE == 4) {
          int b = m / BANDS, band = m - b * BANDS;
          float z = fmaxf(v + bias[n], 0.f) + aux0[(size_t)(band + 1) * DIMC + n];
          outf[((size_t)b * NSPE + band + 1) * DIMC + n] = z;
        }
      }
    }
  }
}

// ---------------- flash attention (f32 VALU, unchanged this round) ----------------
__global__ __launch_bounds__(256) void flash_k(const u16* __restrict__ qkv, u16* __restrict__ o,
                                               int N, int nqt, float scale) {
  __shared__ u16 Qs[64][68], Ks[64][68], Vs[64][68], Ps[64][68];
  int blk = blockIdx.x;
  int qt = blk % nqt;
  int bh = blk / nqt;
  int h = bh % NHEAD;
  int b = bh / NHEAD;
  const int t = threadIdx.x;
  const int tm = t >> 4, tn = t & 15;
  const size_t rs = 3 * DIMC;
  const size_t base = (size_t)b * N * rs;
  for (int idx = t; idx < 64 * 64; idx += 256) {
    int d = idx & 63, r = idx >> 6;
    int n = qt * 64 + r;
    Qs[d][r] = (n < N) ? qkv[base + (size_t)n * rs + h * HD + d] : (u16)0;
  }
  float m_i[4], l_i[4], oacc[4][4];
#pragma unroll
  for (int i = 0; i < 4; i++) {
    m_i[i] = -1e30f; l_i[i] = 0.f;
#pragma unroll
    for (int j = 0; j < 4; j++) oacc[i][j] = 0.f;
  }
  int nkt = (N + 63) >> 6;
  for (int kt = 0; kt < nkt; kt++) {
    __syncthreads();
    for (int idx = t; idx < 64 * 64; idx += 256) {
      int d = idx & 63, c = idx >> 6;
      int n = kt * 64 + c;
      u16 kv = 0, vv = 0;
      if (n < N) {
        kv = qkv[base + (size_t)n * rs + DIMC + h * HD + d];
        vv = qkv[base + (size_t)n * rs + 2 * DIMC + h * HD + d];
      }
      Ks[d][c] = kv;
      Vs[c][d] = vv;
    }
    __syncthreads();
    float s[4][4] = {{0.f}};
#pragma unroll 8
    for (int kk = 0; kk < 64; kk++) {
      ushort4 qa = *reinterpret_cast<const ushort4*>(&Qs[kk][tm * 4]);
      ushort4 kb = *reinterpret_cast<const ushort4*>(&Ks[kk][tn * 4]);
      float qf[4] = {b2f(qa.x), b2f(qa.y), b2f(qa.z), b2f(qa.w)};
      float kf[4] = {b2f(kb.x), b2f(kb.y), b2f(kb.z), b2f(kb.w)};
#pragma unroll
      for (int i = 0; i < 4; i++)
#pragma unroll
        for (int j = 0; j < 4; j++) s[i][j] = fmaf(qf[i], kf[j], s[i][j]);
    }
#pragma unroll
    for (int i = 0; i < 4; i++)
#pragma unroll
      for (int j = 0; j < 4; j++) {
        int n = kt * 64 + tn * 4 + j;
        s[i][j] = (n < N) ? s[i][j] * scale : -1e30f;
      }
#pragma unroll
    for (int i = 0; i < 4; i++) {
      float rmax = fmaxf(fmaxf(s[i][0], s[i][1]), fmaxf(s[i][2], s[i][3]));
      for (int off = 1; off <= 8; off <<= 1) rmax = fmaxf(rmax, __shfl_xor(rmax, off));
      float mn = fmaxf(m_i[i], rmax);
      float corr = __expf(m_i[i] - mn);
      m_i[i] = mn;
      float rsum = 0.f;
#pragma unroll
      for (int j = 0; j < 4; j++) {
        float p = __expf(s[i][j] - mn);
        s[i][j] = p;
        rsum += p;
      }
      for (int off = 1; off <= 8; off <<= 1) rsum += __shfl_xor(rsum, off);
      l_i[i] = l_i[i] * corr + rsum;
#pragma unroll
      for (int j = 0; j < 4; j++) oacc[i][j] *= corr;
#pragma unroll
      for (int j = 0; j < 4; j++) Ps[tn * 4 + j][tm * 4 + i] = f2b(s[i][j]);
    }
    __syncthreads();
#pragma unroll 8
    for (int mm = 0; mm < 64; mm++) {
      ushort4 pa = *reinterpret_cast<const ushort4*>(&Ps[mm][tm * 4]);
      ushort4 vb = *reinterpret_cast<const ushort4*>(&Vs[mm][tn * 4]);
      float pf[4] = {b2f(pa.x), b2f(pa.y), b2f(pa.z), b2f(pa.w)};
      float vf[4] = {b2f(vb.x), b2f(vb.y), b2f(vb.z), b2f(vb.w)};
#pragma unroll
      for (int i = 0; i < 4; i++)
#pragma unroll
        for (int j = 0; j < 4; j++) oacc[i][j] = fmaf(pf[i], vf[j], oacc[i][j]);
    }
  }
#pragma unroll
  for (int i = 0; i < 4; i++) {
    int n = qt * 64 + tm * 4 + i;
    if (n < N) {
      float invl = 1.0f / l_i[i];
#pragma unroll
      for (int j = 0; j < 4; j++)
        o[((size_t)b * N + n) * DIMC + h * HD + tn * 4 + j] = f2b(oacc[i][j] * invl);
    }
  }
}

// ---------------- residual combine with CLS swap ----------------
__global__ __launch_bounds__(256) void combine_k(float* __restrict__ xs, float* __restrict__ ys,
    const u16* __restrict__ x_, const u16* __restrict__ y_) {
  int r = blockIdx.x;
  int b = r / (NSPA + NSPE);
  int tk = r % (NSPA + NSPE);
  int t = threadIdx.x;
  if (tk < NSPA) {
    size_t xrow = ((size_t)b * NSPA + tk) * DIMC;
    for (int d = t; d < DIMC; d += 256) {
      if (tk == 0)
        xs[xrow + d] = 2.0f * xs[xrow + d] + b2f(y_[((size_t)b * NSPE) * DIMC + d]);
      else
        xs[xrow + d] += b2f(x_[xrow + d]);
    }
  } else {
    int tt = tk - NSPA;
    size_t yrow = ((size_t)b * NSPE + tt) * DIMC;
    for (int d = t; d < DIMC; d += 256) {
      if (tt == 0)
        ys[yrow + d] = 2.0f * ys[yrow + d] + b2f(x_[((size_t)b * NSPA) * DIMC + d]);
      else
        ys[yrow + d] += b2f(y_[yrow + d]);
    }
  }
}

// ---------------- head ----------------
__global__ __launch_bounds__(256) void head_k(const float* __restrict__ cls,
    const float* __restrict__ hw, const float* __restrict__ hb, float* __restrict__ out) {
  __shared__ float cl[1024];
  __shared__ float part[256];
  int b = blockIdx.x, t = threadIdx.x;
  for (int idx = t; idx < 1024; idx += 256) cl[idx] = cls[(size_t)b * 1024 + idx];
  __syncthreads();
  int c = t >> 4, sl = t & 15;
  float p = 0.f;
  for (int j = 0; j < 64; j++) p += cl[sl * 64 + j] * hw[(size_t)c * 1024 + sl * 64 + j];
  part[t] = p;
  __syncthreads();
  if (sl == 0) {
    float sum = hb[c];
    for (int q = 0; q < 16; q++) sum += part[c * 16 + q];
    out[(size_t)b * 16 + c] = sum;
  }
}

extern "C" void kernel_launch(void* const* d_in, const int* in_sizes, int n_in,
                              void* d_out, int out_size, void* d_ws, size_t ws_size,
                              hipStream_t stream) {
  const float* x        = (const float*)d_in[0];
  const float* conv_h_w = (const float*)d_in[1];
  const float* conv_h_b = (const float*)d_in[2];
  const float* bn_h_g   = (const float*)d_in[3];
  const float* bn_h_b   = (const float*)d_in[4];
  const float* bn_h_m   = (const float*)d_in[5];
  const float* bn_h_v   = (const float*)d_in[6];
  const float* cnn_conv_w = (const float*)d_in[7];
  const float* cnn_conv_b = (const float*)d_in[8];
  const float* cnn_bn_g = (const float*)d_in[9];
  const float* cnn_bn_b = (const float*)d_in[10];
  const float* cnn_bn_m = (const float*)d_in[11];
  const float* cnn_bn_v = (const float*)d_in[12];
  const float* cnn_fc_w = (const float*)d_in[13];
  const float* cnn_fc_b = (const float*)d_in[14];
  const float* spa_cls  = (const float*)d_in[15];
  const float* spe_cls  = (const float*)d_in[16];
  const float* spa_pos  = (const float*)d_in[17];
  const float* spe_pos  = (const float*)d_in[18];
  const float* blk_n1_w = (const float*)d_in[19];
  const float* blk_n1_b = (const float*)d_in[20];
  const float* blk_n2_w = (const float*)d_in[21];
  const float* blk_n2_b = (const float*)d_in[22];
  const float* blk_qkv_w = (const float*)d_in[23];
  const float* blk_qkv_b = (const float*)d_in[24];
  const float* blk_proj_w = (const float*)d_in[25];
  const float* blk_proj_b = (const float*)d_in[26];
  const float* blk_fc1_w = (const float*)d_in[27];
  const float* blk_fc1_b = (const float*)d_in[28];
  const float* blk_fc2_w = (const float*)d_in[29];
  const float* blk_fc2_b = (const float*)d_in[30];
  const float* norm1_w  = (const float*)d_in[31];
  const float* norm1_b  = (const float*)d_in[32];
  const float* norm2_w  = (const float*)d_in[33];
  const float* norm2_b  = (const float*)d_in[34];
  const float* head_w   = (const float*)d_in[35];
  const float* head_b   = (const float*)d_in[36];

  char* ws = (char*)d_ws;
  size_t off = 0;
  auto take = [&](size_t bytes) -> char* {
    char* p = ws + off;
    off = (off + bytes + 255) & ~(size_t)255;
    return p;
  };
  const int Mx = NB * NSPA;   // 28928 = 226*128
  const int My = NB * NSPE;   // 3968  = 31*128
  const int Mc = NB * NPIX;   // 28800 = 225*128
  const int Mf = NB * BANDS;  // 3840  = 30*128
  float* xs   = (float*)take((size_t)Mx * DIMC * 4);
  float* ys   = (float*)take((size_t)My * DIMC * 4);
  u16* xin    = (u16*)take((size_t)Mx * DIMC * 2);
  u16* yin    = (u16*)take((size_t)My * DIMC * 2);
  u16* qkvx   = (u16*)take((size_t)Mx * 3 * DIMC * 2);  // also aliases Acol (im2col) + h1
  u16* qkvy   = (u16*)take((size_t)My * 3 * DIMC * 2);
  u16* ox     = (u16*)take((size_t)Mx * DIMC * 2);
  u16* oy     = (u16*)take((size_t)My * DIMC * 2);
  float* clsb = (float*)take((size_t)NB * 1024 * 4);
  u16* pooled = (u16*)take((size_t)Mf * 128 * 2);
  u16* qkvWb  = (u16*)take((size_t)2 * 3 * DIMC * DIMC * 2);
  u16* projWb = (u16*)take((size_t)2 * DIMC * DIMC * 2);
  u16* fc1Wb  = (u16*)take((size_t)2 * DIMC * DIMC * 2);
  u16* fc2Wb  = (u16*)take((size_t)2 * DIMC * DIMC * 2);
  u16* fcWb   = (u16*)take((size_t)DIMC * 128 * 2);
  u16* convWb = (u16*)take((size_t)DIMC * KCONV * 2);
  float* bnsc = (float*)take(DIMC * 4);
  float* bnsh = (float*)take(DIMC * 4);
  u16* Acol   = qkvx;  // 28800*288*2 = 16.6MB << qkvx size; freed before qkv GEMM

  // ---- weight prep ----
  cvt_k<<<1024, 256, 0, stream>>>(blk_qkv_w, qkvWb, 2 * 3 * DIMC * DIMC);
  cvt_k<<<1024, 256, 0, stream>>>(blk_proj_w, projWb, 2 * DIMC * DIMC);
  cvt_k<<<1024, 256, 0, stream>>>(blk_fc1_w, fc1Wb, 2 * DIMC * DIMC);
  cvt_k<<<1024, 256, 0, stream>>>(blk_fc2_w, fc2Wb, 2 * DIMC * DIMC);
  cvt_k<<<256, 256, 0, stream>>>(cnn_fc_w, fcWb, DIMC * 128);
  convw_k<<<(DIMC * KCONV + 255) / 256, 256, 0, stream>>>(conv_h_w, convWb);
  bnprep_k<<<2, 256, 0, stream>>>(bn_h_g, bn_h_b, bn_h_m, bn_h_v, conv_h_b, bnsc, bnsh);

  // ---- stem ----
  cls_init_k<<<NB, 256, 0, stream>>>(spa_cls, spe_cls, spa_pos, spe_pos, xs, ys);
  im2col_k<<<(Mc * 32 + 255) / 256, 256, 0, stream>>>(x, Acol);
  mgemm_k<3><<<dim3(DIMC / 128, Mc / 128), 256, 0, stream>>>(Acol, convWb, nullptr, xs, nullptr,
      Mc, DIMC, KCONV, bnsc, bnsh, spa_pos);
  cnn_conv_k<<<Mf, 128, 0, stream>>>(x, cnn_conv_w, cnn_conv_b, cnn_bn_g, cnn_bn_b,
                                     cnn_bn_m, cnn_bn_v, pooled);
  mgemm_k<4><<<dim3(DIMC / 128, Mf / 128), 256, 0, stream>>>(pooled, fcWb, cnn_fc_b, ys, nullptr,
      Mf, DIMC, 128, spe_pos, nullptr, nullptr);

  // ---- transformer blocks ----
  for (int i = 0; i < 2; i++) {
    const float* n1w = blk_n1_w + i * DIMC;
    const float* n1b = blk_n1_b + i * DIMC;
    const float* n2w = blk_n2_w + i * DIMC;
    const float* n2b = blk_n2_b + i * DIMC;
    const u16* qkvW = qkvWb + (size_t)i * 3 * DIMC * DIMC;
    const float* qkvB = blk_qkv_b + (size_t)i * 3 * DIMC;
    const u16* projW = projWb + (size_t)i * DIMC * DIMC;
    const float* projB = blk_proj_b + (size_t)i * DIMC;
    const u16* fc1W = fc1Wb + (size_t)i * DIMC * DIMC;
    const float* fc1B = blk_fc1_b + (size_t)i * DIMC;
    const u16* fc2W = fc2Wb + (size_t)i * DIMC * DIMC;
    const float* fc2B = blk_fc2_b + (size_t)i * DIMC;

    ln_k<<<Mx, 256, 0, stream>>>(xs, ys, (size_t)NSPA * DIMC, (size_t)NSPE * DIMC, NSPA, n1w, n1b, xin);
    ln_k<<<My, 256, 0, stream>>>(ys, xs, (size_t)NSPE * DIMC, (size_t)NSPA * DIMC, NSPE, n1w, n1b, yin);

    mgemm_k<0><<<dim3(12, Mx / 128), 256, 0, stream>>>(xin, qkvW, qkvB, nullptr, qkvx,
        Mx, 3 * DIMC, DIMC, nullptr, nullptr, nullptr);
    mgemm_k<0><<<dim3(12, My / 128), 256, 0, stream>>>(yin, qkvW, qkvB, nullptr, qkvy,
        My, 3 * DIMC, DIMC, nullptr, nullptr, nullptr);

    flash_k<<<NB * NHEAD * 4, 256, 0, stream>>>(qkvx, ox, NSPA, 4, 0.125f);
    flash_k<<<NB * NHEAD * 1, 256, 0, stream>>>(qkvy, oy, NSPE, 1, 0.125f);

    mgemm_k<0><<<dim3(4, Mx / 128), 256, 0, stream>>>(ox, projW, projB, nullptr, xin,
        Mx, DIMC, DIMC, nullptr, nullptr, nullptr);
    mgemm_k<0><<<dim3(4, My / 128), 256, 0, stream>>>(oy, projW, projB, nullptr, yin,
        My, DIMC, DIMC, nullptr, nullptr, nullptr);

    combine_k<<<NB * (NSPA + NSPE), 256, 0, stream>>>(xs, ys, xin, yin);

    ln_k<<<Mx, 256, 0, stream>>>(xs, xs, (size_t)NSPA * DIMC, (size_t)NSPA * DIMC, NSPA, n2w, n2b, xin);
    mgemm_k<1><<<dim3(4, Mx / 128), 256, 0, stream>>>(xin, fc1W, fc1B, nullptr, qkvx,
        Mx, DIMC, DIMC, nullptr, nullptr, nullptr);
    mgemm_k<2><<<dim3(4, Mx / 128), 256, 0, stream>>>(qkvx, fc2W, fc2B, xs, nullptr,
        Mx, DIMC, DIMC, xs, nullptr, nullptr);

    ln_k<<<My, 256, 0, stream>>>(ys, ys, (size_t)NSPE * DIMC, (size_t)NSPE * DIMC, NSPE, n2w, n2b, yin);
    mgemm_k<1><<<dim3(4, My / 128), 256, 0, stream>>>(yin, fc1W, fc1B, nullptr, qkvy,
        My, DIMC, DIMC, nullptr, nullptr, nullptr);
    mgemm_k<2><<<dim3(4, My / 128), 256, 0, stream>>>(qkvy, fc2W, fc2B, ys, nullptr,
        My, DIMC, DIMC, ys, nullptr, nullptr);
  }

  // ---- head ----
  ln_cls_k<<<NB * 2, 256, 0, stream>>>(xs, ys, norm1_w, norm1_b, norm2_w, norm2_b, clsb);
  head_k<<<NB, 256, 0, stream>>>(clsb, head_w, head_b, (float*)d_out);
}

// Round 3
// 1137.562 us; speedup vs baseline: 4.6266x; 1.4852x over previous
//
#include <hip/hip_runtime.h>
#include <hip/hip_bf16.h>

typedef unsigned short u16;
typedef __attribute__((ext_vector_type(8))) short bf16x8;
typedef __attribute__((ext_vector_type(4))) float f32x4;

#define NB 128
#define BANDS 30
#define HWD 15
#define NPIX 225
#define DIMC 512
#define NHEAD 8
#define HD 64
#define NSPA 226
#define NSPE 31
#define EPSF 1e-5f
#define KCONV 288  // 270 padded to multiple of 32

__device__ __forceinline__ float b2f(u16 u) { return __uint_as_float(((unsigned)u) << 16); }
__device__ __forceinline__ u16 f2b(float f) {
  __hip_bfloat16 h = __float2bfloat16(f);
  return *reinterpret_cast<u16*>(&h);
}

#if __has_builtin(__builtin_amdgcn_global_load_lds)
#define HAVE_GLDS 1
__device__ __forceinline__ void gl_lds16(const void* g, void* l) {
  __builtin_amdgcn_global_load_lds((const __attribute__((address_space(1))) void*)g,
                                   (__attribute__((address_space(3))) void*)l, 16, 0, 0);
}
#else
#define HAVE_GLDS 0
#endif

// ---------------- weight f32 -> bf16 ----------------
__global__ __launch_bounds__(256) void cvt_k(const float* __restrict__ s, u16* __restrict__ d, int n) {
  for (int i = blockIdx.x * 256 + threadIdx.x; i < n; i += gridDim.x * 256) d[i] = f2b(s[i]);
}

// conv_h_w (512,270) -> padded bf16 (512,288)
__global__ __launch_bounds__(256) void convw_k(const float* __restrict__ w, u16* __restrict__ d) {
  int i = blockIdx.x * 256 + threadIdx.x;  // 512*288
  int r = i / KCONV, c = i - r * KCONV;
  d[i] = (c < 270) ? f2b(w[r * 270 + c]) : (u16)0;
}

// BN fold: sc = g/sqrt(v+eps), sh = (cb - m)*sc + b
__global__ __launch_bounds__(256) void bnprep_k(const float* __restrict__ g, const float* __restrict__ bb,
    const float* __restrict__ bm, const float* __restrict__ bv, const float* __restrict__ cb,
    float* __restrict__ sc, float* __restrict__ sh) {
  int n = blockIdx.x * 256 + threadIdx.x;
  if (n < DIMC) {
    float inv = g[n] * rsqrtf(bv[n] + EPSF);
    sc[n] = inv;
    sh[n] = (cb[n] - bm[n]) * inv + bb[n];
  }
}

// ---------------- im2col: x (128,30,15,15) f32 -> Acol (28800, 288) bf16 ----------------
__global__ __launch_bounds__(256) void im2col_k(const float* __restrict__ x, u16* __restrict__ Ac) {
  int idx = blockIdx.x * 256 + threadIdx.x;  // m*32 + chslot
  if (idx >= 28800 * 32) return;
  int m = idx >> 5, chslot = idx & 31;
  int b = m / NPIX, p = m - b * NPIX;
  int i = p / 15, j = p - i * 15;
  u16* dst = Ac + (size_t)m * KCONV + chslot * 9;
  if (chslot >= BANDS) {
#pragma unroll
    for (int q = 0; q < 9; q++) dst[q] = 0;
    return;
  }
  const float* xc = x + ((size_t)b * BANDS + chslot) * NPIX;
#pragma unroll
  for (int q = 0; q < 9; q++) {
    int di = q / 3, dj = q - di * 3;
    int ii = i + di - 1, jj = j + dj - 1;
    float v = ((unsigned)ii < 15u && (unsigned)jj < 15u) ? xc[ii * 15 + jj] : 0.f;
    dst[q] = f2b(v);
  }
}

// ---------------- CLS row init ----------------
__global__ __launch_bounds__(256) void cls_init_k(const float* __restrict__ spa_cls,
    const float* __restrict__ spe_cls, const float* __restrict__ spa_pos,
    const float* __restrict__ spe_pos, float* __restrict__ xs, float* __restrict__ ys) {
  int b = blockIdx.x, t = threadIdx.x;
  int d0 = t, d1 = t + 256;
  xs[(size_t)b * NSPA * DIMC + d0] = spa_cls[d0] + spa_pos[d0];
  xs[(size_t)b * NSPA * DIMC + d1] = spa_cls[d1] + spa_pos[d1];
  ys[(size_t)b * NSPE * DIMC + d0] = spe_cls[d0] + spe_pos[d0];
  ys[(size_t)b * NSPE * DIMC + d1] = spe_cls[d1] + spe_pos[d1];
}

// ------------- per-band CNN conv 1->128 + BN + ReLU + mean -> pooled (3840,128) bf16 -------------
__global__ __launch_bounds__(128) void cnn_conv_k(const float* __restrict__ x,
    const float* __restrict__ w, const float* __restrict__ cb, const float* __restrict__ g,
    const float* __restrict__ bb, const float* __restrict__ bm, const float* __restrict__ bv,
    u16* __restrict__ pooled) {
  __shared__ float img[NPIX];
  int band = blockIdx.x;
  int t = threadIdx.x;
  for (int idx = t; idx < NPIX; idx += 128) img[idx] = x[(size_t)band * NPIX + idx];
  __syncthreads();
  int ch = t;
  float w9[9];
#pragma unroll
  for (int q = 0; q < 9; q++) w9[q] = w[ch * 9 + q];
  float inv = g[ch] * rsqrtf(bv[ch] + EPSF);
  float beta = bb[ch] - bm[ch] * inv;
  float bias = cb[ch];
  float sum = 0.0f;
  for (int p = 0; p < NPIX; p++) {
    int i = p / 15, j = p - i * 15;
    float a = bias;
#pragma unroll
    for (int di = 0; di < 3; di++) {
      int ii = i + di - 1;
      if ((unsigned)ii < 15u) {
#pragma unroll
        for (int dj = 0; dj < 3; dj++) {
          int jj = j + dj - 1;
          if ((unsigned)jj < 15u) a = fmaf(w9[di * 3 + dj], img[ii * 15 + jj], a);
        }
      }
    }
    sum += fmaxf(a * inv + beta, 0.0f);
  }
  pooled[(size_t)band * 128 + ch] = f2b(sum * (1.0f / 225.0f));
}

// ---------------- LayerNorm (512) with CLS gather; f32 -> bf16 ----------------
__global__ __launch_bounds__(256) void ln_k(const float* __restrict__ src_main,
    const float* __restrict__ src_cls, size_t stride_main, size_t stride_cls, int Ntok,
    const float* __restrict__ w, const float* __restrict__ bprm, u16* __restrict__ out) {
  int row = blockIdx.x;
  int b = row / Ntok, tk = row % Ntok;
  const float* src = (tk == 0) ? (src_cls + (size_t)b * stride_cls)
                               : (src_main + (size_t)b * stride_main + (size_t)tk * DIMC);
  int t = threadIdx.x;
  float x0 = src[t], x1 = src[t + 256];
  float s = x0 + x1, sq = x0 * x0 + x1 * x1;
  for (int off = 32; off; off >>= 1) { s += __shfl_down(s, off); sq += __shfl_down(sq, off); }
  __shared__ float sa[4], sb4[4];
  int wid = t >> 6;
  if ((t & 63) == 0) { sa[wid] = s; sb4[wid] = sq; }
  __syncthreads();
  s = sa[0] + sa[1] + sa[2] + sa[3];
  sq = sb4[0] + sb4[1] + sb4[2] + sb4[3];
  float mean = s * (1.0f / 512.0f);
  float var = sq * (1.0f / 512.0f) - mean * mean;
  float rstd = rsqrtf(var + EPSF);
  out[(size_t)row * DIMC + t] = f2b((x0 - mean) * rstd * w[t] + bprm[t]);
  out[(size_t)row * DIMC + t + 256] = f2b((x1 - mean) * rstd * w[t + 256] + bprm[t + 256]);
}

// ---------------- final LN on CLS tokens -> f32 (B,1024) ----------------
__global__ __launch_bounds__(256) void ln_cls_k(const float* __restrict__ xs,
    const float* __restrict__ ys, const float* __restrict__ w1, const float* __restrict__ b1,
    const float* __restrict__ w2, const float* __restrict__ b2, float* __restrict__ cls) {
  int gb = blockIdx.x;
  int half = gb & 1, b = gb >> 1;
  const float* src = half ? (ys + (size_t)b * NSPE * DIMC) : (xs + (size_t)b * NSPA * DIMC);
  const float* w = half ? w2 : w1;
  const float* bp = half ? b2 : b1;
  int t = threadIdx.x;
  float x0 = src[t], x1 = src[t + 256];
  float s = x0 + x1, sq = x0 * x0 + x1 * x1;
  for (int off = 32; off; off >>= 1) { s += __shfl_down(s, off); sq += __shfl_down(sq, off); }
  __shared__ float sa[4], sb4[4];
  int wid = t >> 6;
  if ((t & 63) == 0) { sa[wid] = s; sb4[wid] = sq; }
  __syncthreads();
  s = sa[0] + sa[1] + sa[2] + sa[3];
  sq = sb4[0] + sb4[1] + sb4[2] + sb4[3];
  float mean = s * (1.0f / 512.0f);
  float var = sq * (1.0f / 512.0f) - mean * mean;
  float rstd = rsqrtf(var + EPSF);
  cls[(size_t)b * 1024 + half * DIMC + t] = (x0 - mean) * rstd * w[t] + bp[t];
  cls[(size_t)b * 1024 + half * DIMC + t + 256] = (x1 - mean) * rstd * w[t + 256] + bp[t + 256];
}

// ================= MFMA GEMM (unchanged from round 2) =================
template <int MODE>
__global__ __launch_bounds__(256) void mgemm_k(const u16* __restrict__ A, const u16* __restrict__ Bw,
    const float* __restrict__ bias, float* outf, u16* outb, int M, int N, int K,
    const float* aux0, const float* aux1, const float* aux2) {
  __shared__ u16 As[128 * 32];
  __shared__ u16 Bs[128 * 32];
  const int t = threadIdx.x;
  const int wid = t >> 6, l = t & 63;
  const int wm = wid >> 1, wn = wid & 1;
  const int fr = l & 15, kg = l >> 4;
  const int n0 = blockIdx.x * 128, m0 = blockIdx.y * 128;
  const int sr = l >> 2;
  const int sc4 = l & 3;
  const int scg = sc4 ^ (sr & 3);
  const int rdsw = (fr & 3);

  f32x4 acc[4][4];
#pragma unroll
  for (int i = 0; i < 4; i++)
#pragma unroll
    for (int j = 0; j < 4; j++) acc[i][j] = (f32x4){0.f, 0.f, 0.f, 0.f};

  for (int kq = 0; kq < K; kq += 32) {
#if !HAVE_GLDS
    uint4 ra[2], rb[2];
#pragma unroll
    for (int i = 0; i < 2; i++) {
      int r = wid * 32 + i * 16 + sr;
      ra[i] = *reinterpret_cast<const uint4*>(A + (size_t)(m0 + r) * K + kq + scg * 8);
      rb[i] = *reinterpret_cast<const uint4*>(Bw + (size_t)(n0 + r) * K + kq + scg * 8);
    }
#endif
    __syncthreads();
#if HAVE_GLDS
#pragma unroll
    for (int i = 0; i < 2; i++) {
      int r = wid * 32 + i * 16 + sr;
      gl_lds16(A + (size_t)(m0 + r) * K + kq + scg * 8, &As[(wid * 32 + i * 16) * 32]);
      gl_lds16(Bw + (size_t)(n0 + r) * K + kq + scg * 8, &Bs[(wid * 32 + i * 16) * 32]);
    }
#else
#pragma unroll
    for (int i = 0; i < 2; i++) {
      int r = wid * 32 + i * 16 + sr;
      *reinterpret_cast<uint4*>(&As[r * 32 + sc4 * 8]) = ra[i];
      *reinterpret_cast<uint4*>(&Bs[r * 32 + sc4 * 8]) = rb[i];
    }
#endif
    __syncthreads();
    bf16x8 af[4], bfr[4];
#pragma unroll
    for (int mi = 0; mi < 4; mi++) {
      int r = wm * 64 + mi * 16 + fr;
      af[mi] = *reinterpret_cast<const bf16x8*>(&As[r * 32 + (kg ^ rdsw) * 8]);
    }
#pragma unroll
    for (int nj = 0; nj < 4; nj++) {
      int n = wn * 64 + nj * 16 + fr;
      bfr[nj] = *reinterpret_cast<const bf16x8*>(&Bs[n * 32 + (kg ^ rdsw) * 8]);
    }
#pragma unroll
    for (int mi = 0; mi < 4; mi++)
#pragma unroll
      for (int nj = 0; nj < 4; nj++)
        acc[mi][nj] = __builtin_amdgcn_mfma_f32_16x16x32_bf16(af[mi], bfr[nj], acc[mi][nj], 0, 0, 0);
  }

#pragma unroll
  for (int mi = 0; mi < 4; mi++) {
#pragma unroll
    for (int q = 0; q < 4; q++) {
      int m = m0 + wm * 64 + mi * 16 + kg * 4 + q;
#pragma unroll
      for (int nj = 0; nj < 4; nj++) {
        int n = n0 + wn * 64 + nj * 16 + fr;
        float v = acc[mi][nj][q];
        if (MODE == 0) {
          outb[(size_t)m * N + n] = f2b(v + bias[n]);
        } else if (MODE == 1) {
          float z = v + bias[n];
          outb[(size_t)m * N + n] = f2b(0.5f * z * (1.0f + erff(z * 0.70710678118f)));
        } else if (MODE == 2) {
          size_t idx = (size_t)m * N + n;
          outf[idx] = v + bias[n] + aux0[idx];
        } else if (MODE == 3) {
          int b = m / NPIX, p = m - b * NPIX;
          float z = fmaxf(v * aux0[n] + aux1[n], 0.f) + aux2[(size_t)(p + 1) * DIMC + n];
          outf[((size_t)b * NSPA + p + 1) * DIMC + n] = z;
        } else if (MODE == 4) {
          int b = m / BANDS, band = m - b * BANDS;
          float z = fmaxf(v + bias[n], 0.f) + aux0[(size_t)(band + 1) * DIMC + n];
          outf[((size_t)b * NSPE + band + 1) * DIMC + n] = z;
        }
      }
    }
  }
}

// ================= MFMA flash attention =================
// One workgroup per (b, h, q-tile of 64). 4 waves, wave w owns q-rows w*16..w*16+15.
// LDS tiles 64x64 bf16, row stride 64 (128B), chunk-XOR swizzle: chunk ^= row&7.
// Q,K,P row-major; V transposed (Vt[d][j]) so all fragment reads are contiguous bf16x8.
__device__ __forceinline__ int fsw(int row, int chunk) {
  return row * 64 + ((chunk ^ (row & 7)) << 3);
}
__global__ __launch_bounds__(256) void flashm_k(const u16* __restrict__ qkv, u16* __restrict__ o,
                                                int N, float scale) {
  __shared__ u16 Qs[64 * 64], Ks[64 * 64], Vt[64 * 64], Ps[64 * 64];
  const int qt = blockIdx.x, h = blockIdx.y, b = blockIdx.z;
  const int t = threadIdx.x;
  const int w = t >> 6, l = t & 63;
  const int lr = l & 15, lk = l >> 4;
  const size_t rs = 3 * DIMC;
  const size_t base = (size_t)b * N * rs + h * HD;

  // stage Q tile (rows qt*64.., 64 dims)
#pragma unroll
  for (int it = 0; it < 2; it++) {
    int task = it * 256 + t;
    int r = task >> 3, c = task & 7;
    int n = qt * 64 + r;
    uint4 v = make_uint4(0, 0, 0, 0);
    if (n < N) v = *reinterpret_cast<const uint4*>(qkv + base + (size_t)n * rs + c * 8);
    *reinterpret_cast<uint4*>(&Qs[fsw(r, c)]) = v;
  }
  __syncthreads();
  // Q A-fragments in registers (reused across all K tiles)
  bf16x8 aq[2];
  {
    int row = w * 16 + lr;
    aq[0] = *reinterpret_cast<const bf16x8*>(&Qs[fsw(row, lk)]);
    aq[1] = *reinterpret_cast<const bf16x8*>(&Qs[fsw(row, 4 + lk)]);
  }

  float m_i[4], l_i[4];
  f32x4 oacc[4];
#pragma unroll
  for (int q = 0; q < 4; q++) { m_i[q] = -1e30f; l_i[q] = 0.f; }
#pragma unroll
  for (int nj = 0; nj < 4; nj++) oacc[nj] = (f32x4){0.f, 0.f, 0.f, 0.f};

  const int nkt = (N + 63) >> 6;
  for (int kt = 0; kt < nkt; kt++) {
    __syncthreads();  // previous PV reads of Ks/Vt done
#pragma unroll
    for (int it = 0; it < 2; it++) {
      int task = it * 256 + t;
      int r = task >> 3, c = task & 7;
      int n = kt * 64 + r;
      uint4 kv = make_uint4(0, 0, 0, 0), vv = make_uint4(0, 0, 0, 0);
      if (n < N) {
        kv = *reinterpret_cast<const uint4*>(qkv + base + (size_t)n * rs + DIMC + c * 8);
        vv = *reinterpret_cast<const uint4*>(qkv + base + (size_t)n * rs + 2 * DIMC + c * 8);
      }
      *reinterpret_cast<uint4*>(&Ks[fsw(r, c)]) = kv;
      const u16* ev = reinterpret_cast<const u16*>(&vv);
#pragma unroll
      for (int e = 0; e < 8; e++) {
        int d = c * 8 + e;
        Vt[d * 64 + ((((r >> 3) ^ (d & 7)) << 3) | (r & 7))] = ev[e];
      }
    }
    __syncthreads();

    // S = Q @ K^T  (wave rows w*16..+15, cols 64)
    f32x4 sc[4];
#pragma unroll
    for (int nj = 0; nj < 4; nj++) sc[nj] = (f32x4){0.f, 0.f, 0.f, 0.f};
#pragma unroll
    for (int nj = 0; nj < 4; nj++) {
      int krow = nj * 16 + lr;
      bf16x8 bk0 = *reinterpret_cast<const bf16x8*>(&Ks[fsw(krow, lk)]);
      bf16x8 bk1 = *reinterpret_cast<const bf16x8*>(&Ks[fsw(krow, 4 + lk)]);
      sc[nj] = __builtin_amdgcn_mfma_f32_16x16x32_bf16(aq[0], bk0, sc[nj], 0, 0, 0);
      sc[nj] = __builtin_amdgcn_mfma_f32_16x16x32_bf16(aq[1], bk1, sc[nj], 0, 0, 0);
    }

    // online softmax (rows w*16 + lk*4 + q; cols nj*16 + lr)
    float sv[4][4];
#pragma unroll
    for (int nj = 0; nj < 4; nj++) {
      int jn = kt * 64 + nj * 16 + lr;
#pragma unroll
      for (int q = 0; q < 4; q++) sv[nj][q] = (jn < N) ? sc[nj][q] * scale : -1e30f;
    }
#pragma unroll
    for (int q = 0; q < 4; q++) {
      float rmax = fmaxf(fmaxf(sv[0][q], sv[1][q]), fmaxf(sv[2][q], sv[3][q]));
      rmax = fmaxf(rmax, __shfl_xor(rmax, 1));
      rmax = fmaxf(rmax, __shfl_xor(rmax, 2));
      rmax = fmaxf(rmax, __shfl_xor(rmax, 4));
      rmax = fmaxf(rmax, __shfl_xor(rmax, 8));
      float mn = fmaxf(m_i[q], rmax);
      float corr = __expf(m_i[q] - mn);
      m_i[q] = mn;
      float rsum = 0.f;
#pragma unroll
      for (int nj = 0; nj < 4; nj++) {
        float p = __expf(sv[nj][q] - mn);
        sv[nj][q] = p;
        rsum += p;
      }
      rsum += __shfl_xor(rsum, 1);
      rsum += __shfl_xor(rsum, 2);
      rsum += __shfl_xor(rsum, 4);
      rsum += __shfl_xor(rsum, 8);
      l_i[q] = l_i[q] * corr + rsum;
#pragma unroll
      for (int nj = 0; nj < 4; nj++) oacc[nj][q] *= corr;
    }
    // P -> LDS in A-fragment layout (own wave's 16 rows only)
#pragma unroll
    for (int nj = 0; nj < 4; nj++) {
#pragma unroll
      for (int q = 0; q < 4; q++) {
        int prow = w * 16 + lk * 4 + q;
        int pcol = nj * 16 + lr;
        Ps[prow * 64 + ((((pcol >> 3) ^ (prow & 7)) << 3) | (pcol & 7))] = f2b(sv[nj][q]);
      }
    }
    __syncthreads();

    // O += P @ V
#pragma unroll
    for (int nj = 0; nj < 4; nj++) {
      int prow = w * 16 + lr;
      int vrow = nj * 16 + lr;
      bf16x8 ap0 = *reinterpret_cast<const bf16x8*>(&Ps[fsw(prow, lk)]);
      bf16x8 bv0 = *reinterpret_cast<const bf16x8*>(&Vt[fsw(vrow, lk)]);
      oacc[nj] = __builtin_amdgcn_mfma_f32_16x16x32_bf16(ap0, bv0, oacc[nj], 0, 0, 0);
      bf16x8 ap1 = *reinterpret_cast<const bf16x8*>(&Ps[fsw(prow, 4 + lk)]);
      bf16x8 bv1 = *reinterpret_cast<const bf16x8*>(&Vt[fsw(vrow, 4 + lk)]);
      oacc[nj] = __builtin_amdgcn_mfma_f32_16x16x32_bf16(ap1, bv1, oacc[nj], 0, 0, 0);
    }
  }

  // write O (cols h*64 + nj*16 + lr, rows qt*64 + w*16 + lk*4 + q)
#pragma unroll
  for (int q = 0; q < 4; q++) {
    int qrow = qt * 64 + w * 16 + lk * 4 + q;
    if (qrow < N) {
      float invl = 1.0f / l_i[q];
#pragma unroll
      for (int nj = 0; nj < 4; nj++)
        o[((size_t)b * N + qrow) * DIMC + h * HD + nj * 16 + lr] = f2b(oacc[nj][q] * invl);
    }
  }
}

// ---------------- residual combine with CLS swap ----------------
__global__ __launch_bounds__(256) void combine_k(float* __restrict__ xs, float* __restrict__ ys,
    const u16* __restrict__ x_, const u16* __restrict__ y_) {
  int r = blockIdx.x;
  int b = r / (NSPA + NSPE);
  int tk = r % (NSPA + NSPE);
  int t = threadIdx.x;
  if (tk < NSPA) {
    size_t xrow = ((size_t)b * NSPA + tk) * DIMC;
    for (int d = t; d < DIMC; d += 256) {
      if (tk == 0)
        xs[xrow + d] = 2.0f * xs[xrow + d] + b2f(y_[((size_t)b * NSPE) * DIMC + d]);
      else
        xs[xrow + d] += b2f(x_[xrow + d]);
    }
  } else {
    int tt = tk - NSPA;
    size_t yrow = ((size_t)b * NSPE + tt) * DIMC;
    for (int d = t; d < DIMC; d += 256) {
      if (tt == 0)
        ys[yrow + d] = 2.0f * ys[yrow + d] + b2f(x_[((size_t)b * NSPA) * DIMC + d]);
      else
        ys[yrow + d] += b2f(y_[yrow + d]);
    }
  }
}

// ---------------- head ----------------
__global__ __launch_bounds__(256) void head_k(const float* __restrict__ cls,
    const float* __restrict__ hw, const float* __restrict__ hb, float* __restrict__ out) {
  __shared__ float cl[1024];
  __shared__ float part[256];
  int b = blockIdx.x, t = threadIdx.x;
  for (int idx = t; idx < 1024; idx += 256) cl[idx] = cls[(size_t)b * 1024 + idx];
  __syncthreads();
  int c = t >> 4, sl = t & 15;
  float p = 0.f;
  for (int j = 0; j < 64; j++) p += cl[sl * 64 + j] * hw[(size_t)c * 1024 + sl * 64 + j];
  part[t] = p;
  __syncthreads();
  if (sl == 0) {
    float sum = hb[c];
    for (int q = 0; q < 16; q++) sum += part[c * 16 + q];
    out[(size_t)b * 16 + c] = sum;
  }
}

extern "C" void kernel_launch(void* const* d_in, const int* in_sizes, int n_in,
                              void* d_out, int out_size, void* d_ws, size_t ws_size,
                              hipStream_t stream) {
  const float* x        = (const float*)d_in[0];
  const float* conv_h_w = (const float*)d_in[1];
  const float* conv_h_b = (const float*)d_in[2];
  const float* bn_h_g   = (const float*)d_in[3];
  const float* bn_h_b   = (const float*)d_in[4];
  const float* bn_h_m   = (const float*)d_in[5];
  const float* bn_h_v   = (const float*)d_in[6];
  const float* cnn_conv_w = (const float*)d_in[7];
  const float* cnn_conv_b = (const float*)d_in[8];
  const float* cnn_bn_g = (const float*)d_in[9];
  const float* cnn_bn_b = (const float*)d_in[10];
  const float* cnn_bn_m = (const float*)d_in[11];
  const float* cnn_bn_v = (const float*)d_in[12];
  const float* cnn_fc_w = (const float*)d_in[13];
  const float* cnn_fc_b = (const float*)d_in[14];
  const float* spa_cls  = (const float*)d_in[15];
  const float* spe_cls  = (const float*)d_in[16];
  const float* spa_pos  = (const float*)d_in[17];
  const float* spe_pos  = (const float*)d_in[18];
  const float* blk_n1_w = (const float*)d_in[19];
  const float* blk_n1_b = (const float*)d_in[20];
  const float* blk_n2_w = (const float*)d_in[21];
  const float* blk_n2_b = (const float*)d_in[22];
  const float* blk_qkv_w = (const float*)d_in[23];
  const float* blk_qkv_b = (const float*)d_in[24];
  const float* blk_proj_w = (const float*)d_in[25];
  const float* blk_proj_b = (const float*)d_in[26];
  const float* blk_fc1_w = (const float*)d_in[27];
  const float* blk_fc1_b = (const float*)d_in[28];
  const float* blk_fc2_w = (const float*)d_in[29];
  const float* blk_fc2_b = (const float*)d_in[30];
  const float* norm1_w  = (const float*)d_in[31];
  const float* norm1_b  = (const float*)d_in[32];
  const float* norm2_w  = (const float*)d_in[33];
  const float* norm2_b  = (const float*)d_in[34];
  const float* head_w   = (const float*)d_in[35];
  const float* head_b   = (const float*)d_in[36];

  char* ws = (char*)d_ws;
  size_t off = 0;
  auto take = [&](size_t bytes) -> char* {
    char* p = ws + off;
    off = (off + bytes + 255) & ~(size_t)255;
    return p;
  };
  const int Mx = NB * NSPA;   // 28928
  const int My = NB * NSPE;   // 3968
  const int Mc = NB * NPIX;   // 28800
  const int Mf = NB * BANDS;  // 3840
  float* xs   = (float*)take((size_t)Mx * DIMC * 4);
  float* ys   = (float*)take((size_t)My * DIMC * 4);
  u16* xin    = (u16*)take((size_t)Mx * DIMC * 2);
  u16* yin    = (u16*)take((size_t)My * DIMC * 2);
  u16* qkvx   = (u16*)take((size_t)Mx * 3 * DIMC * 2);
  u16* qkvy   = (u16*)take((size_t)My * 3 * DIMC * 2);
  u16* ox     = (u16*)take((size_t)Mx * DIMC * 2);
  u16* oy     = (u16*)take((size_t)My * DIMC * 2);
  float* clsb = (float*)take((size_t)NB * 1024 * 4);
  u16* pooled = (u16*)take((size_t)Mf * 128 * 2);
  u16* qkvWb  = (u16*)take((size_t)2 * 3 * DIMC * DIMC * 2);
  u16* projWb = (u16*)take((size_t)2 * DIMC * DIMC * 2);
  u16* fc1Wb  = (u16*)take((size_t)2 * DIMC * DIMC * 2);
  u16* fc2Wb  = (u16*)take((size_t)2 * DIMC * DIMC * 2);
  u16* fcWb   = (u16*)take((size_t)DIMC * 128 * 2);
  u16* convWb = (u16*)take((size_t)DIMC * KCONV * 2);
  float* bnsc = (float*)take(DIMC * 4);
  float* bnsh = (float*)take(DIMC * 4);
  u16* Acol   = qkvx;

  // ---- weight prep ----
  cvt_k<<<1024, 256, 0, stream>>>(blk_qkv_w, qkvWb, 2 * 3 * DIMC * DIMC);
  cvt_k<<<1024, 256, 0, stream>>>(blk_proj_w, projWb, 2 * DIMC * DIMC);
  cvt_k<<<1024, 256, 0, stream>>>(blk_fc1_w, fc1Wb, 2 * DIMC * DIMC);
  cvt_k<<<1024, 256, 0, stream>>>(blk_fc2_w, fc2Wb, 2 * DIMC * DIMC);
  cvt_k<<<256, 256, 0, stream>>>(cnn_fc_w, fcWb, DIMC * 128);
  convw_k<<<(DIMC * KCONV + 255) / 256, 256, 0, stream>>>(conv_h_w, convWb);
  bnprep_k<<<2, 256, 0, stream>>>(bn_h_g, bn_h_b, bn_h_m, bn_h_v, conv_h_b, bnsc, bnsh);

  // ---- stem ----
  cls_init_k<<<NB, 256, 0, stream>>>(spa_cls, spe_cls, spa_pos, spe_pos, xs, ys);
  im2col_k<<<(Mc * 32 + 255) / 256, 256, 0, stream>>>(x, Acol);
  mgemm_k<3><<<dim3(DIMC / 128, Mc / 128), 256, 0, stream>>>(Acol, convWb, nullptr, xs, nullptr,
      Mc, DIMC, KCONV, bnsc, bnsh, spa_pos);
  cnn_conv_k<<<Mf, 128, 0, stream>>>(x, cnn_conv_w, cnn_conv_b, cnn_bn_g, cnn_bn_b,
                                     cnn_bn_m, cnn_bn_v, pooled);
  mgemm_k<4><<<dim3(DIMC / 128, Mf / 128), 256, 0, stream>>>(pooled, fcWb, cnn_fc_b, ys, nullptr,
      Mf, DIMC, 128, spe_pos, nullptr, nullptr);

  // ---- transformer blocks ----
  for (int i = 0; i < 2; i++) {
    const float* n1w = blk_n1_w + i * DIMC;
    const float* n1b = blk_n1_b + i * DIMC;
    const float* n2w = blk_n2_w + i * DIMC;
    const float* n2b = blk_n2_b + i * DIMC;
    const u16* qkvW = qkvWb + (size_t)i * 3 * DIMC * DIMC;
    const float* qkvB = blk_qkv_b + (size_t)i * 3 * DIMC;
    const u16* projW = projWb + (size_t)i * DIMC * DIMC;
    const float* projB = blk_proj_b + (size_t)i * DIMC;
    const u16* fc1W = fc1Wb + (size_t)i * DIMC * DIMC;
    const float* fc1B = blk_fc1_b + (size_t)i * DIMC;
    const u16* fc2W = fc2Wb + (size_t)i * DIMC * DIMC;
    const float* fc2B = blk_fc2_b + (size_t)i * DIMC;

    ln_k<<<Mx, 256, 0, stream>>>(xs, ys, (size_t)NSPA * DIMC, (size_t)NSPE * DIMC, NSPA, n1w, n1b, xin);
    ln_k<<<My, 256, 0, stream>>>(ys, xs, (size_t)NSPE * DIMC, (size_t)NSPA * DIMC, NSPE, n1w, n1b, yin);

    mgemm_k<0><<<dim3(12, Mx / 128), 256, 0, stream>>>(xin, qkvW, qkvB, nullptr, qkvx,
        Mx, 3 * DIMC, DIMC, nullptr, nullptr, nullptr);
    mgemm_k<0><<<dim3(12, My / 128), 256, 0, stream>>>(yin, qkvW, qkvB, nullptr, qkvy,
        My, 3 * DIMC, DIMC, nullptr, nullptr, nullptr);

    flashm_k<<<dim3(4, NHEAD, NB), 256, 0, stream>>>(qkvx, ox, NSPA, 0.125f);
    flashm_k<<<dim3(1, NHEAD, NB), 256, 0, stream>>>(qkvy, oy, NSPE, 0.125f);

    mgemm_k<0><<<dim3(4, Mx / 128), 256, 0, stream>>>(ox, projW, projB, nullptr, xin,
        Mx, DIMC, DIMC, nullptr, nullptr, nullptr);
    mgemm_k<0><<<dim3(4, My / 128), 256, 0, stream>>>(oy, projW, projB, nullptr, yin,
        My, DIMC, DIMC, nullptr, nullptr, nullptr);

    combine_k<<<NB * (NSPA + NSPE), 256, 0, stream>>>(xs, ys, xin, yin);

    ln_k<<<Mx, 256, 0, stream>>>(xs, xs, (size_t)NSPA * DIMC, (size_t)NSPA * DIMC, NSPA, n2w, n2b, xin);
    mgemm_k<1><<<dim3(4, Mx / 128), 256, 0, stream>>>(xin, fc1W, fc1B, nullptr, qkvx,
        Mx, DIMC, DIMC, nullptr, nullptr, nullptr);
    mgemm_k<2><<<dim3(4, Mx / 128), 256, 0, stream>>>(qkvx, fc2W, fc2B, xs, nullptr,
        Mx, DIMC, DIMC, xs, nullptr, nullptr);

    ln_k<<<My, 256, 0, stream>>>(ys, ys, (size_t)NSPE * DIMC, (size_t)NSPE * DIMC, NSPE, n2w, n2b, yin);
    mgemm_k<1><<<dim3(4, My / 128), 256, 0, stream>>>(yin, fc1W, fc1B, nullptr, qkvy,
        My, DIMC, DIMC, nullptr, nullptr, nullptr);
    mgemm_k<2><<<dim3(4, My / 128), 256, 0, stream>>>(qkvy, fc2W, fc2B, ys, nullptr,
        My, DIMC, DIMC, ys, nullptr, nullptr);
  }

  // ---- head ----
  ln_cls_k<<<NB * 2, 256, 0, stream>>>(xs, ys, norm1_w, norm1_b, norm2_w, norm2_b, clsb);
  head_k<<<NB, 256, 0, stream>>>(clsb, head_w, head_b, (float*)d_out);
}

// Round 4
// 969.619 us; speedup vs baseline: 5.4280x; 1.1732x over previous
//
#include <hip/hip_runtime.h>
#include <hip/hip_bf16.h>

typedef unsigned short u16;
typedef __attribute__((ext_vector_type(8))) short bf16x8;
typedef __attribute__((ext_vector_type(4))) float f32x4;

#define NB 128
#define BANDS 30
#define HWD 15
#define NPIX 225
#define DIMC 512
#define NHEAD 8
#define HD 64
#define NSPA 226
#define NSPE 31
#define EPSF 1e-5f
#define KCONV 288     // 270 padded to multiple of 32
#define MXROWS 28928  // NB*NSPA
#define MYROWS 3968   // NB*NSPE
#define M2ROWS 32896  // MXROWS+MYROWS

__device__ __forceinline__ float b2f(u16 u) { return __uint_as_float(((unsigned)u) << 16); }
__device__ __forceinline__ u16 f2b(float f) {
  __hip_bfloat16 h = __float2bfloat16(f);
  return *reinterpret_cast<u16*>(&h);
}

#if __has_builtin(__builtin_amdgcn_global_load_lds)
#define HAVE_GLDS 1
__device__ __forceinline__ void gl_lds16(const void* g, void* l) {
  __builtin_amdgcn_global_load_lds((const __attribute__((address_space(1))) void*)g,
                                   (__attribute__((address_space(3))) void*)l, 16, 0, 0);
}
#else
#define HAVE_GLDS 0
#endif

// ---------------- weight f32 -> bf16 ----------------
__global__ __launch_bounds__(256) void cvt_k(const float* __restrict__ s, u16* __restrict__ d, int n) {
  for (int i = blockIdx.x * 256 + threadIdx.x; i < n; i += gridDim.x * 256) d[i] = f2b(s[i]);
}

// conv_h_w (512,270) -> padded bf16 (512,288)
__global__ __launch_bounds__(256) void convw_k(const float* __restrict__ w, u16* __restrict__ d) {
  int i = blockIdx.x * 256 + threadIdx.x;
  int r = i / KCONV, c = i - r * KCONV;
  d[i] = (c < 270) ? f2b(w[r * 270 + c]) : (u16)0;
}

// BN fold: sc = g/sqrt(v+eps), sh = (cb - m)*sc + b
__global__ __launch_bounds__(256) void bnprep_k(const float* __restrict__ g, const float* __restrict__ bb,
    const float* __restrict__ bm, const float* __restrict__ bv, const float* __restrict__ cb,
    float* __restrict__ sc, float* __restrict__ sh) {
  int n = blockIdx.x * 256 + threadIdx.x;
  if (n < DIMC) {
    float inv = g[n] * rsqrtf(bv[n] + EPSF);
    sc[n] = inv;
    sh[n] = (cb[n] - bm[n]) * inv + bb[n];
  }
}

// ---------------- im2col: x (128,30,15,15) f32 -> Acol (28800, 288) bf16 ----------------
__global__ __launch_bounds__(256) void im2col_k(const float* __restrict__ x, u16* __restrict__ Ac) {
  int idx = blockIdx.x * 256 + threadIdx.x;
  if (idx >= 28800 * 32) return;
  int m = idx >> 5, chslot = idx & 31;
  int b = m / NPIX, p = m - b * NPIX;
  int i = p / 15, j = p - i * 15;
  u16* dst = Ac + (size_t)m * KCONV + chslot * 9;
  if (chslot >= BANDS) {
#pragma unroll
    for (int q = 0; q < 9; q++) dst[q] = 0;
    return;
  }
  const float* xc = x + ((size_t)b * BANDS + chslot) * NPIX;
#pragma unroll
  for (int q = 0; q < 9; q++) {
    int di = q / 3, dj = q - di * 3;
    int ii = i + di - 1, jj = j + dj - 1;
    float v = ((unsigned)ii < 15u && (unsigned)jj < 15u) ? xc[ii * 15 + jj] : 0.f;
    dst[q] = f2b(v);
  }
}

// ---------------- CLS row init ----------------
__global__ __launch_bounds__(256) void cls_init_k(const float* __restrict__ spa_cls,
    const float* __restrict__ spe_cls, const float* __restrict__ spa_pos,
    const float* __restrict__ spe_pos, float* __restrict__ xs, float* __restrict__ ys) {
  int b = blockIdx.x, t = threadIdx.x;
  int d0 = t, d1 = t + 256;
  xs[(size_t)b * NSPA * DIMC + d0] = spa_cls[d0] + spa_pos[d0];
  xs[(size_t)b * NSPA * DIMC + d1] = spa_cls[d1] + spa_pos[d1];
  ys[(size_t)b * NSPE * DIMC + d0] = spe_cls[d0] + spe_pos[d0];
  ys[(size_t)b * NSPE * DIMC + d1] = spe_cls[d1] + spe_pos[d1];
}

// ------------- per-band CNN conv 1->128 + BN + ReLU + mean; 2 bands/block -------------
// Register-rolling 3-row window; all j bounds compile-time; BN folded into weights.
__global__ __launch_bounds__(256) void cnn_conv_k(const float* __restrict__ x,
    const float* __restrict__ w, const float* __restrict__ cb, const float* __restrict__ g,
    const float* __restrict__ bb, const float* __restrict__ bm, const float* __restrict__ bv,
    u16* __restrict__ pooled) {
  __shared__ float img[2][NPIX];
  int b0 = blockIdx.x * 2;
  int t = threadIdx.x;
  for (int idx = t; idx < 2 * NPIX; idx += 256) ((float*)img)[idx] = x[(size_t)b0 * NPIX + idx];
  __syncthreads();
  int half = t >> 7, ch = t & 127;
  const float* im = img[half];
  float inv = g[ch] * rsqrtf(bv[ch] + EPSF);
  float beta = bb[ch] - bm[ch] * inv;
  float w9[9];
#pragma unroll
  for (int q = 0; q < 9; q++) w9[q] = w[ch * 9 + q] * inv;
  float bias = cb[ch] * inv + beta;

  float rm[15], rc[15], rp[15];
#pragma unroll
  for (int j = 0; j < 15; j++) { rm[j] = 0.f; rc[j] = im[j]; }
  float sum = 0.f;
  for (int i = 0; i < 15; i++) {
#pragma unroll
    for (int j = 0; j < 15; j++) rp[j] = (i < 14) ? im[(i + 1) * 15 + j] : 0.f;
    float a[15];
#pragma unroll
    for (int j = 0; j < 15; j++) a[j] = fmaf(w9[4], rc[j], bias);
#pragma unroll
    for (int j = 0; j < 15; j++) {
      if (j > 0)  a[j] = fmaf(w9[3], rc[j - 1], a[j]);
      if (j < 14) a[j] = fmaf(w9[5], rc[j + 1], a[j]);
      a[j] = fmaf(w9[1], rm[j], a[j]);
      if (j > 0)  a[j] = fmaf(w9[0], rm[j - 1], a[j]);
      if (j < 14) a[j] = fmaf(w9[2], rm[j + 1], a[j]);
      a[j] = fmaf(w9[7], rp[j], a[j]);
      if (j > 0)  a[j] = fmaf(w9[6], rp[j - 1], a[j]);
      if (j < 14) a[j] = fmaf(w9[8], rp[j + 1], a[j]);
    }
#pragma unroll
    for (int j = 0; j < 15; j++) sum += fmaxf(a[j], 0.f);
#pragma unroll
    for (int j = 0; j < 15; j++) { rm[j] = rc[j]; rc[j] = rp[j]; }
  }
  pooled[(size_t)(b0 + half) * 128 + ch] = f2b(sum * (1.0f / 225.0f));
}

// ---------------- LayerNorm over combined rows (x-stream then y-stream) ----------------
// GATHER=1: block-input LN with cross-stream CLS gather. GATHER=0: plain row LN.
template <int GATHER>
__global__ __launch_bounds__(256) void ln_c_k(const float* __restrict__ xsc,
    const float* __restrict__ w, const float* __restrict__ bprm, u16* __restrict__ out) {
  int row = blockIdx.x;
  const float* src;
  if (GATHER) {
    if (row < MXROWS) {
      int b = row / NSPA, tk = row - b * NSPA;
      src = (tk == 0) ? xsc + ((size_t)MXROWS + (size_t)b * NSPE) * DIMC
                      : xsc + (size_t)row * DIMC;
    } else {
      int ry = row - MXROWS;
      int b = ry / NSPE, tk = ry - b * NSPE;
      src = (tk == 0) ? xsc + (size_t)b * NSPA * DIMC : xsc + (size_t)row * DIMC;
    }
  } else {
    src = xsc + (size_t)row * DIMC;
  }
  int t = threadIdx.x;
  float x0 = src[t], x1 = src[t + 256];
  float s = x0 + x1, sq = x0 * x0 + x1 * x1;
  for (int off = 32; off; off >>= 1) { s += __shfl_down(s, off); sq += __shfl_down(sq, off); }
  __shared__ float sa[4], sb4[4];
  int wid = t >> 6;
  if ((t & 63) == 0) { sa[wid] = s; sb4[wid] = sq; }
  __syncthreads();
  s = sa[0] + sa[1] + sa[2] + sa[3];
  sq = sb4[0] + sb4[1] + sb4[2] + sb4[3];
  float mean = s * (1.0f / 512.0f);
  float var = sq * (1.0f / 512.0f) - mean * mean;
  float rstd = rsqrtf(var + EPSF);
  out[(size_t)row * DIMC + t] = f2b((x0 - mean) * rstd * w[t] + bprm[t]);
  out[(size_t)row * DIMC + t + 256] = f2b((x1 - mean) * rstd * w[t + 256] + bprm[t + 256]);
}

// ---------------- final LN on CLS tokens -> f32 (B,1024) ----------------
__global__ __launch_bounds__(256) void ln_cls_k(const float* __restrict__ xs,
    const float* __restrict__ ys, const float* __restrict__ w1, const float* __restrict__ b1,
    const float* __restrict__ w2, const float* __restrict__ b2, float* __restrict__ cls) {
  int gb = blockIdx.x;
  int half = gb & 1, b = gb >> 1;
  const float* src = half ? (ys + (size_t)b * NSPE * DIMC) : (xs + (size_t)b * NSPA * DIMC);
  const float* w = half ? w2 : w1;
  const float* bp = half ? b2 : b1;
  int t = threadIdx.x;
  float x0 = src[t], x1 = src[t + 256];
  float s = x0 + x1, sq = x0 * x0 + x1 * x1;
  for (int off = 32; off; off >>= 1) { s += __shfl_down(s, off); sq += __shfl_down(sq, off); }
  __shared__ float sa[4], sb4[4];
  int wid = t >> 6;
  if ((t & 63) == 0) { sa[wid] = s; sb4[wid] = sq; }
  __syncthreads();
  s = sa[0] + sa[1] + sa[2] + sa[3];
  sq = sb4[0] + sb4[1] + sb4[2] + sb4[3];
  float mean = s * (1.0f / 512.0f);
  float var = sq * (1.0f / 512.0f) - mean * mean;
  float rstd = rsqrtf(var + EPSF);
  cls[(size_t)b * 1024 + half * DIMC + t] = (x0 - mean) * rstd * w[t] + bp[t];
  cls[(size_t)b * 1024 + half * DIMC + t + 256] = (x1 - mean) * rstd * w[t + 256] + bp[t + 256];
}

// ================= MFMA GEMM =================
// MODE 0: bf16 out = acc+bias            MODE 1: bf16 out = gelu(acc+bias)
// MODE 2: f32 out  = acc+bias+resid(aux0)
// MODE 3: conv scatter: xs[(b*226+p+1)*512+n] = relu(acc*sc+sh) + spa_pos
// MODE 4: fc_spe scatter: ys[(b*31+band+1)*512+n] = relu(acc+bias) + spe_pos
// MODE 5: proj+residual-combine: non-CLS rows: outf[m*512+n] += acc+bias;
//         CLS rows -> outb (clsprj: slot b for x-stream, 128+b for y-stream)
template <int MODE>
__global__ __launch_bounds__(256) void mgemm_k(const u16* __restrict__ A, const u16* __restrict__ Bw,
    const float* __restrict__ bias, float* outf, u16* outb, int M, int N, int K,
    const float* aux0, const float* aux1, const float* aux2) {
  __shared__ u16 As[128 * 32];
  __shared__ u16 Bs[128 * 32];
  const int t = threadIdx.x;
  const int wid = t >> 6, l = t & 63;
  const int wm = wid >> 1, wn = wid & 1;
  const int fr = l & 15, kg = l >> 4;
  const int n0 = blockIdx.x * 128, m0 = blockIdx.y * 128;
  const int sr = l >> 2;
  const int sc4 = l & 3;
  const int scg = sc4 ^ (sr & 3);
  const int rdsw = (fr & 3);

  f32x4 acc[4][4];
#pragma unroll
  for (int i = 0; i < 4; i++)
#pragma unroll
    for (int j = 0; j < 4; j++) acc[i][j] = (f32x4){0.f, 0.f, 0.f, 0.f};

  for (int kq = 0; kq < K; kq += 32) {
#if !HAVE_GLDS
    uint4 ra[2], rb[2];
#pragma unroll
    for (int i = 0; i < 2; i++) {
      int r = wid * 32 + i * 16 + sr;
      ra[i] = *reinterpret_cast<const uint4*>(A + (size_t)(m0 + r) * K + kq + scg * 8);
      rb[i] = *reinterpret_cast<const uint4*>(Bw + (size_t)(n0 + r) * K + kq + scg * 8);
    }
#endif
    __syncthreads();
#if HAVE_GLDS
#pragma unroll
    for (int i = 0; i < 2; i++) {
      int r = wid * 32 + i * 16 + sr;
      gl_lds16(A + (size_t)(m0 + r) * K + kq + scg * 8, &As[(wid * 32 + i * 16) * 32]);
      gl_lds16(Bw + (size_t)(n0 + r) * K + kq + scg * 8, &Bs[(wid * 32 + i * 16) * 32]);
    }
#else
#pragma unroll
    for (int i = 0; i < 2; i++) {
      int r = wid * 32 + i * 16 + sr;
      *reinterpret_cast<uint4*>(&As[r * 32 + sc4 * 8]) = ra[i];
      *reinterpret_cast<uint4*>(&Bs[r * 32 + sc4 * 8]) = rb[i];
    }
#endif
    __syncthreads();
    bf16x8 af[4], bfr[4];
#pragma unroll
    for (int mi = 0; mi < 4; mi++) {
      int r = wm * 64 + mi * 16 + fr;
      af[mi] = *reinterpret_cast<const bf16x8*>(&As[r * 32 + (kg ^ rdsw) * 8]);
    }
#pragma unroll
    for (int nj = 0; nj < 4; nj++) {
      int n = wn * 64 + nj * 16 + fr;
      bfr[nj] = *reinterpret_cast<const bf16x8*>(&Bs[n * 32 + (kg ^ rdsw) * 8]);
    }
#pragma unroll
    for (int mi = 0; mi < 4; mi++)
#pragma unroll
      for (int nj = 0; nj < 4; nj++)
        acc[mi][nj] = __builtin_amdgcn_mfma_f32_16x16x32_bf16(af[mi], bfr[nj], acc[mi][nj], 0, 0, 0);
  }

#pragma unroll
  for (int mi = 0; mi < 4; mi++) {
#pragma unroll
    for (int q = 0; q < 4; q++) {
      int m = m0 + wm * 64 + mi * 16 + kg * 4 + q;
#pragma unroll
      for (int nj = 0; nj < 4; nj++) {
        int n = n0 + wn * 64 + nj * 16 + fr;
        float v = acc[mi][nj][q];
        if (MODE == 0) {
          outb[(size_t)m * N + n] = f2b(v + bias[n]);
        } else if (MODE == 1) {
          float z = v + bias[n];
          outb[(size_t)m * N + n] = f2b(0.5f * z * (1.0f + erff(z * 0.70710678118f)));
        } else if (MODE == 2) {
          size_t idx = (size_t)m * N + n;
          outf[idx] = v + bias[n] + aux0[idx];
        } else if (MODE == 3) {
          int b = m / NPIX, p = m - b * NPIX;
          float z = fmaxf(v * aux0[n] + aux1[n], 0.f) + aux2[(size_t)(p + 1) * DIMC + n];
          outf[((size_t)b * NSPA + p + 1) * DIMC + n] = z;
        } else if (MODE == 4) {
          int b = m / BANDS, band = m - b * BANDS;
          float z = fmaxf(v + bias[n], 0.f) + aux0[(size_t)(band + 1) * DIMC + n];
          outf[((size_t)b * NSPE + band + 1) * DIMC + n] = z;
        } else if (MODE == 5) {
          float z = v + bias[n];
          int tk, sidx;
          if (m < MXROWS) {
            int b = m / NSPA; tk = m - b * NSPA; sidx = b;
          } else {
            int ry = m - MXROWS; int b = ry / NSPE; tk = ry - b * NSPE; sidx = 128 + b;
          }
          if (tk == 0) outb[(size_t)sidx * DIMC + n] = f2b(z);
          else outf[(size_t)m * N + n] += z;
        }
      }
    }
  }
}

// ---------------- CLS swap: xs_cls = 2*xs_cls + proj_y_cls; ys_cls = 2*ys_cls + proj_x_cls ----------------
__global__ __launch_bounds__(256) void cls_swap_k(float* __restrict__ xsc,
                                                  const u16* __restrict__ clsprj) {
  int b = blockIdx.x, t = threadIdx.x;
  size_t xrow = (size_t)b * NSPA * DIMC;
  size_t yrow = ((size_t)MXROWS + (size_t)b * NSPE) * DIMC;
#pragma unroll
  for (int q = 0; q < 2; q++) {
    int d = t + q * 256;
    xsc[xrow + d] = 2.0f * xsc[xrow + d] + b2f(clsprj[(size_t)(128 + b) * DIMC + d]);
    xsc[yrow + d] = 2.0f * xsc[yrow + d] + b2f(clsprj[(size_t)b * DIMC + d]);
  }
}

// ================= MFMA flash attention (unchanged from round 3) =================
__device__ __forceinline__ int fsw(int row, int chunk) {
  return row * 64 + ((chunk ^ (row & 7)) << 3);
}
__global__ __launch_bounds__(256) void flashm_k(const u16* __restrict__ qkv, u16* __restrict__ o,
                                                int N, float scale) {
  __shared__ u16 Qs[64 * 64], Ks[64 * 64], Vt[64 * 64], Ps[64 * 64];
  const int qt = blockIdx.x, h = blockIdx.y, b = blockIdx.z;
  const int t = threadIdx.x;
  const int w = t >> 6, l = t & 63;
  const int lr = l & 15, lk = l >> 4;
  const size_t rs = 3 * DIMC;
  const size_t base = (size_t)b * N * rs + h * HD;

#pragma unroll
  for (int it = 0; it < 2; it++) {
    int task = it * 256 + t;
    int r = task >> 3, c = task & 7;
    int n = qt * 64 + r;
    uint4 v = make_uint4(0, 0, 0, 0);
    if (n < N) v = *reinterpret_cast<const uint4*>(qkv + base + (size_t)n * rs + c * 8);
    *reinterpret_cast<uint4*>(&Qs[fsw(r, c)]) = v;
  }
  __syncthreads();
  bf16x8 aq[2];
  {
    int row = w * 16 + lr;
    aq[0] = *reinterpret_cast<const bf16x8*>(&Qs[fsw(row, lk)]);
    aq[1] = *reinterpret_cast<const bf16x8*>(&Qs[fsw(row, 4 + lk)]);
  }

  float m_i[4], l_i[4];
  f32x4 oacc[4];
#pragma unroll
  for (int q = 0; q < 4; q++) { m_i[q] = -1e30f; l_i[q] = 0.f; }
#pragma unroll
  for (int nj = 0; nj < 4; nj++) oacc[nj] = (f32x4){0.f, 0.f, 0.f, 0.f};

  const int nkt = (N + 63) >> 6;
  for (int kt = 0; kt < nkt; kt++) {
    __syncthreads();
#pragma unroll
    for (int it = 0; it < 2; it++) {
      int task = it * 256 + t;
      int r = task >> 3, c = task & 7;
      int n = kt * 64 + r;
      uint4 kv = make_uint4(0, 0, 0, 0), vv = make_uint4(0, 0, 0, 0);
      if (n < N) {
        kv = *reinterpret_cast<const uint4*>(qkv + base + (size_t)n * rs + DIMC + c * 8);
        vv = *reinterpret_cast<const uint4*>(qkv + base + (size_t)n * rs + 2 * DIMC + c * 8);
      }
      *reinterpret_cast<uint4*>(&Ks[fsw(r, c)]) = kv;
      const u16* ev = reinterpret_cast<const u16*>(&vv);
#pragma unroll
      for (int e = 0; e < 8; e++) {
        int d = c * 8 + e;
        Vt[d * 64 + ((((r >> 3) ^ (d & 7)) << 3) | (r & 7))] = ev[e];
      }
    }
    __syncthreads();

    f32x4 sc[4];
#pragma unroll
    for (int nj = 0; nj < 4; nj++) sc[nj] = (f32x4){0.f, 0.f, 0.f, 0.f};
#pragma unroll
    for (int nj = 0; nj < 4; nj++) {
      int krow = nj * 16 + lr;
      bf16x8 bk0 = *reinterpret_cast<const bf16x8*>(&Ks[fsw(krow, lk)]);
      bf16x8 bk1 = *reinterpret_cast<const bf16x8*>(&Ks[fsw(krow, 4 + lk)]);
      sc[nj] = __builtin_amdgcn_mfma_f32_16x16x32_bf16(aq[0], bk0, sc[nj], 0, 0, 0);
      sc[nj] = __builtin_amdgcn_mfma_f32_16x16x32_bf16(aq[1], bk1, sc[nj], 0, 0, 0);
    }

    float sv[4][4];
#pragma unroll
    for (int nj = 0; nj < 4; nj++) {
      int jn = kt * 64 + nj * 16 + lr;
#pragma unroll
      for (int q = 0; q < 4; q++) sv[nj][q] = (jn < N) ? sc[nj][q] * scale : -1e30f;
    }
#pragma unroll
    for (int q = 0; q < 4; q++) {
      float rmax = fmaxf(fmaxf(sv[0][q], sv[1][q]), fmaxf(sv[2][q], sv[3][q]));
      rmax = fmaxf(rmax, __shfl_xor(rmax, 1));
      rmax = fmaxf(rmax, __shfl_xor(rmax, 2));
      rmax = fmaxf(rmax, __shfl_xor(rmax, 4));
      rmax = fmaxf(rmax, __shfl_xor(rmax, 8));
      float mn = fmaxf(m_i[q], rmax);
      float corr = __expf(m_i[q] - mn);
      m_i[q] = mn;
      float rsum = 0.f;
#pragma unroll
      for (int nj = 0; nj < 4; nj++) {
        float p = __expf(sv[nj][q] - mn);
        sv[nj][q] = p;
        rsum += p;
      }
      rsum += __shfl_xor(rsum, 1);
      rsum += __shfl_xor(rsum, 2);
      rsum += __shfl_xor(rsum, 4);
      rsum += __shfl_xor(rsum, 8);
      l_i[q] = l_i[q] * corr + rsum;
#pragma unroll
      for (int nj = 0; nj < 4; nj++) oacc[nj][q] *= corr;
    }
#pragma unroll
    for (int nj = 0; nj < 4; nj++) {
#pragma unroll
      for (int q = 0; q < 4; q++) {
        int prow = w * 16 + lk * 4 + q;
        int pcol = nj * 16 + lr;
        Ps[prow * 64 + ((((pcol >> 3) ^ (prow & 7)) << 3) | (pcol & 7))] = f2b(sv[nj][q]);
      }
    }
    __syncthreads();

#pragma unroll
    for (int nj = 0; nj < 4; nj++) {
      int prow = w * 16 + lr;
      int vrow = nj * 16 + lr;
      bf16x8 ap0 = *reinterpret_cast<const bf16x8*>(&Ps[fsw(prow, lk)]);
      bf16x8 bv0 = *reinterpret_cast<const bf16x8*>(&Vt[fsw(vrow, lk)]);
      oacc[nj] = __builtin_amdgcn_mfma_f32_16x16x32_bf16(ap0, bv0, oacc[nj], 0, 0, 0);
      bf16x8 ap1 = *reinterpret_cast<const bf16x8*>(&Ps[fsw(prow, 4 + lk)]);
      bf16x8 bv1 = *reinterpret_cast<const bf16x8*>(&Vt[fsw(vrow, 4 + lk)]);
      oacc[nj] = __builtin_amdgcn_mfma_f32_16x16x32_bf16(ap1, bv1, oacc[nj], 0, 0, 0);
    }
  }

#pragma unroll
  for (int q = 0; q < 4; q++) {
    int qrow = qt * 64 + w * 16 + lk * 4 + q;
    if (qrow < N) {
      float invl = 1.0f / l_i[q];
#pragma unroll
      for (int nj = 0; nj < 4; nj++)
        o[((size_t)b * N + qrow) * DIMC + h * HD + nj * 16 + lr] = f2b(oacc[nj][q] * invl);
    }
  }
}

// ---------------- head ----------------
__global__ __launch_bounds__(256) void head_k(const float* __restrict__ cls,
    const float* __restrict__ hw, const float* __restrict__ hb, float* __restrict__ out) {
  __shared__ float cl[1024];
  __shared__ float part[256];
  int b = blockIdx.x, t = threadIdx.x;
  for (int idx = t; idx < 1024; idx += 256) cl[idx] = cls[(size_t)b * 1024 + idx];
  __syncthreads();
  int c = t >> 4, sl = t & 15;
  float p = 0.f;
  for (int j = 0; j < 64; j++) p += cl[sl * 64 + j] * hw[(size_t)c * 1024 + sl * 64 + j];
  part[t] = p;
  __syncthreads();
  if (sl == 0) {
    float sum = hb[c];
    for (int q = 0; q < 16; q++) sum += part[c * 16 + q];
    out[(size_t)b * 16 + c] = sum;
  }
}

extern "C" void kernel_launch(void* const* d_in, const int* in_sizes, int n_in,
                              void* d_out, int out_size, void* d_ws, size_t ws_size,
                              hipStream_t stream) {
  const float* x        = (const float*)d_in[0];
  const float* conv_h_w = (const float*)d_in[1];
  const float* conv_h_b = (const float*)d_in[2];
  const float* bn_h_g   = (const float*)d_in[3];
  const float* bn_h_b   = (const float*)d_in[4];
  const float* bn_h_m   = (const float*)d_in[5];
  const float* bn_h_v   = (const float*)d_in[6];
  const float* cnn_conv_w = (const float*)d_in[7];
  const float* cnn_conv_b = (const float*)d_in[8];
  const float* cnn_bn_g = (const float*)d_in[9];
  const float* cnn_bn_b = (const float*)d_in[10];
  const float* cnn_bn_m = (const float*)d_in[11];
  const float* cnn_bn_v = (const float*)d_in[12];
  const float* cnn_fc_w = (const float*)d_in[13];
  const float* cnn_fc_b = (const float*)d_in[14];
  const float* spa_cls  = (const float*)d_in[15];
  const float* spe_cls  = (const float*)d_in[16];
  const float* spa_pos  = (const float*)d_in[17];
  const float* spe_pos  = (const float*)d_in[18];
  const float* blk_n1_w = (const float*)d_in[19];
  const float* blk_n1_b = (const float*)d_in[20];
  const float* blk_n2_w = (const float*)d_in[21];
  const float* blk_n2_b = (const float*)d_in[22];
  const float* blk_qkv_w = (const float*)d_in[23];
  const float* blk_qkv_b = (const float*)d_in[24];
  const float* blk_proj_w = (const float*)d_in[25];
  const float* blk_proj_b = (const float*)d_in[26];
  const float* blk_fc1_w = (const float*)d_in[27];
  const float* blk_fc1_b = (const float*)d_in[28];
  const float* blk_fc2_w = (const float*)d_in[29];
  const float* blk_fc2_b = (const float*)d_in[30];
  const float* norm1_w  = (const float*)d_in[31];
  const float* norm1_b  = (const float*)d_in[32];
  const float* norm2_w  = (const float*)d_in[33];
  const float* norm2_b  = (const float*)d_in[34];
  const float* head_w   = (const float*)d_in[35];
  const float* head_b   = (const float*)d_in[36];

  char* ws = (char*)d_ws;
  size_t off = 0;
  auto take = [&](size_t bytes) -> char* {
    char* p = ws + off;
    off = (off + bytes + 255) & ~(size_t)255;
    return p;
  };
  const int Mx = MXROWS, My = MYROWS, M2 = M2ROWS;
  const int Mc = NB * NPIX;   // 28800
  const int Mf = NB * BANDS;  // 3840
  float* xsc  = (float*)take((size_t)M2 * DIMC * 4);      // combined xs||ys residual (f32)
  float* ysb  = xsc + (size_t)Mx * DIMC;
  u16* xyin   = (u16*)take((size_t)M2 * DIMC * 2);        // LN outputs (combined)
  u16* qkvxy  = (u16*)take((size_t)M2 * 3 * DIMC * 2);    // qkv / h1 / Acol alias
  u16* oxy    = (u16*)take((size_t)M2 * DIMC * 2);        // attention out (combined)
  u16* clsprj = (u16*)take((size_t)256 * DIMC * 2);
  float* clsb = (float*)take((size_t)NB * 1024 * 4);
  u16* pooled = (u16*)take((size_t)Mf * 128 * 2);
  u16* qkvWb  = (u16*)take((size_t)2 * 3 * DIMC * DIMC * 2);
  u16* projWb = (u16*)take((size_t)2 * DIMC * DIMC * 2);
  u16* fc1Wb  = (u16*)take((size_t)2 * DIMC * DIMC * 2);
  u16* fc2Wb  = (u16*)take((size_t)2 * DIMC * DIMC * 2);
  u16* fcWb   = (u16*)take((size_t)DIMC * 128 * 2);
  u16* convWb = (u16*)take((size_t)DIMC * KCONV * 2);
  float* bnsc = (float*)take(DIMC * 4);
  float* bnsh = (float*)take(DIMC * 4);
  u16* Acol   = qkvxy;

  // ---- weight prep ----
  cvt_k<<<1024, 256, 0, stream>>>(blk_qkv_w, qkvWb, 2 * 3 * DIMC * DIMC);
  cvt_k<<<1024, 256, 0, stream>>>(blk_proj_w, projWb, 2 * DIMC * DIMC);
  cvt_k<<<1024, 256, 0, stream>>>(blk_fc1_w, fc1Wb, 2 * DIMC * DIMC);
  cvt_k<<<1024, 256, 0, stream>>>(blk_fc2_w, fc2Wb, 2 * DIMC * DIMC);
  cvt_k<<<256, 256, 0, stream>>>(cnn_fc_w, fcWb, DIMC * 128);
  convw_k<<<(DIMC * KCONV + 255) / 256, 256, 0, stream>>>(conv_h_w, convWb);
  bnprep_k<<<2, 256, 0, stream>>>(bn_h_g, bn_h_b, bn_h_m, bn_h_v, conv_h_b, bnsc, bnsh);

  // ---- stem ----
  cls_init_k<<<NB, 256, 0, stream>>>(spa_cls, spe_cls, spa_pos, spe_pos, xsc, ysb);
  im2col_k<<<(Mc * 32 + 255) / 256, 256, 0, stream>>>(x, Acol);
  mgemm_k<3><<<dim3(4, Mc / 128), 256, 0, stream>>>(Acol, convWb, nullptr, xsc, nullptr,
      Mc, DIMC, KCONV, bnsc, bnsh, spa_pos);
  cnn_conv_k<<<Mf / 2, 256, 0, stream>>>(x, cnn_conv_w, cnn_conv_b, cnn_bn_g, cnn_bn_b,
                                         cnn_bn_m, cnn_bn_v, pooled);
  mgemm_k<4><<<dim3(4, Mf / 128), 256, 0, stream>>>(pooled, fcWb, cnn_fc_b, ysb, nullptr,
      Mf, DIMC, 128, spe_pos, nullptr, nullptr);

  // ---- transformer blocks (x and y streams merged: M2 rows) ----
  for (int i = 0; i < 2; i++) {
    const float* n1w = blk_n1_w + i * DIMC;
    const float* n1b = blk_n1_b + i * DIMC;
    const float* n2w = blk_n2_w + i * DIMC;
    const float* n2b = blk_n2_b + i * DIMC;
    const u16* qkvW = qkvWb + (size_t)i * 3 * DIMC * DIMC;
    const float* qkvB = blk_qkv_b + (size_t)i * 3 * DIMC;
    const u16* projW = projWb + (size_t)i * DIMC * DIMC;
    const float* projB = blk_proj_b + (size_t)i * DIMC;
    const u16* fc1W = fc1Wb + (size_t)i * DIMC * DIMC;
    const float* fc1B = blk_fc1_b + (size_t)i * DIMC;
    const u16* fc2W = fc2Wb + (size_t)i * DIMC * DIMC;
    const float* fc2B = blk_fc2_b + (size_t)i * DIMC;

    ln_c_k<1><<<M2, 256, 0, stream>>>(xsc, n1w, n1b, xyin);

    mgemm_k<0><<<dim3(12, M2 / 128), 256, 0, stream>>>(xyin, qkvW, qkvB, nullptr, qkvxy,
        M2, 3 * DIMC, DIMC, nullptr, nullptr, nullptr);

    flashm_k<<<dim3(4, NHEAD, NB), 256, 0, stream>>>(qkvxy, oxy, NSPA, 0.125f);
    flashm_k<<<dim3(1, NHEAD, NB), 256, 0, stream>>>(qkvxy + (size_t)Mx * 3 * DIMC,
                                                     oxy + (size_t)Mx * DIMC, NSPE, 0.125f);

    mgemm_k<5><<<dim3(4, M2 / 128), 256, 0, stream>>>(oxy, projW, projB, xsc, clsprj,
        M2, DIMC, DIMC, nullptr, nullptr, nullptr);
    cls_swap_k<<<NB, 256, 0, stream>>>(xsc, clsprj);

    ln_c_k<0><<<M2, 256, 0, stream>>>(xsc, n2w, n2b, xyin);
    mgemm_k<1><<<dim3(4, M2 / 128), 256, 0, stream>>>(xyin, fc1W, fc1B, nullptr, qkvxy,
        M2, DIMC, DIMC, nullptr, nullptr, nullptr);
    mgemm_k<2><<<dim3(4, M2 / 128), 256, 0, stream>>>(qkvxy, fc2W, fc2B, xsc, nullptr,
        M2, DIMC, DIMC, xsc, nullptr, nullptr);
  }

  // ---- head ----
  ln_cls_k<<<NB * 2, 256, 0, stream>>>(xsc, ysb, norm1_w, norm1_b, norm2_w, norm2_b, clsb);
  head_k<<<NB, 256, 0, stream>>>(clsb, head_w, head_b, (float*)d_out);
}

// Round 5
// 938.794 us; speedup vs baseline: 5.6062x; 1.0328x over previous
//
#include <hip/hip_runtime.h>
#include <hip/hip_bf16.h>

typedef unsigned short u16;
typedef __attribute__((ext_vector_type(8))) short bf16x8;
typedef __attribute__((ext_vector_type(4))) float f32x4;

#define NB 128
#define BANDS 30
#define HWD 15
#define NPIX 225
#define DIMC 512
#define NHEAD 8
#define HD 64
#define NSPA 226
#define NSPE 31
#define EPSF 1e-5f
#define KCONV 288     // 270 padded to multiple of 32
#define MXROWS 28928  // NB*NSPA
#define MYROWS 3968   // NB*NSPE
#define M2ROWS 32896  // MXROWS+MYROWS

__device__ __forceinline__ float b2f(u16 u) { return __uint_as_float(((unsigned)u) << 16); }
__device__ __forceinline__ u16 f2b(float f) {
  __hip_bfloat16 h = __float2bfloat16(f);
  return *reinterpret_cast<u16*>(&h);
}

#if __has_builtin(__builtin_amdgcn_global_load_lds)
#define HAVE_GLDS 1
__device__ __forceinline__ void gl_lds16(const void* g, void* l) {
  __builtin_amdgcn_global_load_lds((const __attribute__((address_space(1))) void*)g,
                                   (__attribute__((address_space(3))) void*)l, 16, 0, 0);
}
#else
#define HAVE_GLDS 0
#endif

// ---------------- weight f32 -> bf16 ----------------
__global__ __launch_bounds__(256) void cvt_k(const float* __restrict__ s, u16* __restrict__ d, int n) {
  for (int i = blockIdx.x * 256 + threadIdx.x; i < n; i += gridDim.x * 256) d[i] = f2b(s[i]);
}

// conv_h_w (512,270) -> padded bf16 (512,288)
__global__ __launch_bounds__(256) void convw_k(const float* __restrict__ w, u16* __restrict__ d) {
  int i = blockIdx.x * 256 + threadIdx.x;
  int r = i / KCONV, c = i - r * KCONV;
  d[i] = (c < 270) ? f2b(w[r * 270 + c]) : (u16)0;
}

// BN fold
__global__ __launch_bounds__(256) void bnprep_k(const float* __restrict__ g, const float* __restrict__ bb,
    const float* __restrict__ bm, const float* __restrict__ bv, const float* __restrict__ cb,
    float* __restrict__ sc, float* __restrict__ sh) {
  int n = blockIdx.x * 256 + threadIdx.x;
  if (n < DIMC) {
    float inv = g[n] * rsqrtf(bv[n] + EPSF);
    sc[n] = inv;
    sh[n] = (cb[n] - bm[n]) * inv + bb[n];
  }
}

// ---------------- im2col ----------------
__global__ __launch_bounds__(256) void im2col_k(const float* __restrict__ x, u16* __restrict__ Ac) {
  int idx = blockIdx.x * 256 + threadIdx.x;
  if (idx >= 28800 * 32) return;
  int m = idx >> 5, chslot = idx & 31;
  int b = m / NPIX, p = m - b * NPIX;
  int i = p / 15, j = p - i * 15;
  u16* dst = Ac + (size_t)m * KCONV + chslot * 9;
  if (chslot >= BANDS) {
#pragma unroll
    for (int q = 0; q < 9; q++) dst[q] = 0;
    return;
  }
  const float* xc = x + ((size_t)b * BANDS + chslot) * NPIX;
#pragma unroll
  for (int q = 0; q < 9; q++) {
    int di = q / 3, dj = q - di * 3;
    int ii = i + di - 1, jj = j + dj - 1;
    float v = ((unsigned)ii < 15u && (unsigned)jj < 15u) ? xc[ii * 15 + jj] : 0.f;
    dst[q] = f2b(v);
  }
}

// ---------------- CLS row init ----------------
__global__ __launch_bounds__(256) void cls_init_k(const float* __restrict__ spa_cls,
    const float* __restrict__ spe_cls, const float* __restrict__ spa_pos,
    const float* __restrict__ spe_pos, float* __restrict__ xs, float* __restrict__ ys) {
  int b = blockIdx.x, t = threadIdx.x;
  int d0 = t, d1 = t + 256;
  xs[(size_t)b * NSPA * DIMC + d0] = spa_cls[d0] + spa_pos[d0];
  xs[(size_t)b * NSPA * DIMC + d1] = spa_cls[d1] + spa_pos[d1];
  ys[(size_t)b * NSPE * DIMC + d0] = spe_cls[d0] + spe_pos[d0];
  ys[(size_t)b * NSPE * DIMC + d1] = spe_cls[d1] + spe_pos[d1];
}

// ------------- per-band CNN conv + BN + ReLU + mean (register-rolling rows) -------------
__global__ __launch_bounds__(256) void cnn_conv_k(const float* __restrict__ x,
    const float* __restrict__ w, const float* __restrict__ cb, const float* __restrict__ g,
    const float* __restrict__ bb, const float* __restrict__ bm, const float* __restrict__ bv,
    u16* __restrict__ pooled) {
  __shared__ float img[2][NPIX];
  int b0 = blockIdx.x * 2;
  int t = threadIdx.x;
  for (int idx = t; idx < 2 * NPIX; idx += 256) ((float*)img)[idx] = x[(size_t)b0 * NPIX + idx];
  __syncthreads();
  int half = t >> 7, ch = t & 127;
  const float* im = img[half];
  float inv = g[ch] * rsqrtf(bv[ch] + EPSF);
  float beta = bb[ch] - bm[ch] * inv;
  float w9[9];
#pragma unroll
  for (int q = 0; q < 9; q++) w9[q] = w[ch * 9 + q] * inv;
  float bias = cb[ch] * inv + beta;

  float rm[15], rc[15], rp[15];
#pragma unroll
  for (int j = 0; j < 15; j++) { rm[j] = 0.f; rc[j] = im[j]; }
  float sum = 0.f;
  for (int i = 0; i < 15; i++) {
#pragma unroll
    for (int j = 0; j < 15; j++) rp[j] = (i < 14) ? im[(i + 1) * 15 + j] : 0.f;
    float a[15];
#pragma unroll
    for (int j = 0; j < 15; j++) a[j] = fmaf(w9[4], rc[j], bias);
#pragma unroll
    for (int j = 0; j < 15; j++) {
      if (j > 0)  a[j] = fmaf(w9[3], rc[j - 1], a[j]);
      if (j < 14) a[j] = fmaf(w9[5], rc[j + 1], a[j]);
      a[j] = fmaf(w9[1], rm[j], a[j]);
      if (j > 0)  a[j] = fmaf(w9[0], rm[j - 1], a[j]);
      if (j < 14) a[j] = fmaf(w9[2], rm[j + 1], a[j]);
      a[j] = fmaf(w9[7], rp[j], a[j]);
      if (j > 0)  a[j] = fmaf(w9[6], rp[j - 1], a[j]);
      if (j < 14) a[j] = fmaf(w9[8], rp[j + 1], a[j]);
    }
#pragma unroll
    for (int j = 0; j < 15; j++) sum += fmaxf(a[j], 0.f);
#pragma unroll
    for (int j = 0; j < 15; j++) { rm[j] = rc[j]; rc[j] = rp[j]; }
  }
  pooled[(size_t)(b0 + half) * 128 + ch] = f2b(sum * (1.0f / 225.0f));
}

// ---------------- LayerNorm over combined rows ----------------
template <int GATHER>
__global__ __launch_bounds__(256) void ln_c_k(const float* __restrict__ xsc,
    const float* __restrict__ w, const float* __restrict__ bprm, u16* __restrict__ out) {
  int row = blockIdx.x;
  const float* src;
  if (GATHER) {
    if (row < MXROWS) {
      int b = row / NSPA, tk = row - b * NSPA;
      src = (tk == 0) ? xsc + ((size_t)MXROWS + (size_t)b * NSPE) * DIMC
                      : xsc + (size_t)row * DIMC;
    } else {
      int ry = row - MXROWS;
      int b = ry / NSPE, tk = ry - b * NSPE;
      src = (tk == 0) ? xsc + (size_t)b * NSPA * DIMC : xsc + (size_t)row * DIMC;
    }
  } else {
    src = xsc + (size_t)row * DIMC;
  }
  int t = threadIdx.x;
  float x0 = src[t], x1 = src[t + 256];
  float s = x0 + x1, sq = x0 * x0 + x1 * x1;
  for (int off = 32; off; off >>= 1) { s += __shfl_down(s, off); sq += __shfl_down(sq, off); }
  __shared__ float sa[4], sb4[4];
  int wid = t >> 6;
  if ((t & 63) == 0) { sa[wid] = s; sb4[wid] = sq; }
  __syncthreads();
  s = sa[0] + sa[1] + sa[2] + sa[3];
  sq = sb4[0] + sb4[1] + sb4[2] + sb4[3];
  float mean = s * (1.0f / 512.0f);
  float var = sq * (1.0f / 512.0f) - mean * mean;
  float rstd = rsqrtf(var + EPSF);
  out[(size_t)row * DIMC + t] = f2b((x0 - mean) * rstd * w[t] + bprm[t]);
  out[(size_t)row * DIMC + t + 256] = f2b((x1 - mean) * rstd * w[t + 256] + bprm[t + 256]);
}

// ---------------- final LN on CLS tokens -> f32 (B,1024) ----------------
__global__ __launch_bounds__(256) void ln_cls_k(const float* __restrict__ xs,
    const float* __restrict__ ys, const float* __restrict__ w1, const float* __restrict__ b1,
    const float* __restrict__ w2, const float* __restrict__ b2, float* __restrict__ cls) {
  int gb = blockIdx.x;
  int half = gb & 1, b = gb >> 1;
  const float* src = half ? (ys + (size_t)b * NSPE * DIMC) : (xs + (size_t)b * NSPA * DIMC);
  const float* w = half ? w2 : w1;
  const float* bp = half ? b2 : b1;
  int t = threadIdx.x;
  float x0 = src[t], x1 = src[t + 256];
  float s = x0 + x1, sq = x0 * x0 + x1 * x1;
  for (int off = 32; off; off >>= 1) { s += __shfl_down(s, off); sq += __shfl_down(sq, off); }
  __shared__ float sa[4], sb4[4];
  int wid = t >> 6;
  if ((t & 63) == 0) { sa[wid] = s; sb4[wid] = sq; }
  __syncthreads();
  s = sa[0] + sa[1] + sa[2] + sa[3];
  sq = sb4[0] + sb4[1] + sb4[2] + sb4[3];
  float mean = s * (1.0f / 512.0f);
  float var = sq * (1.0f / 512.0f) - mean * mean;
  float rstd = rsqrtf(var + EPSF);
  cls[(size_t)b * 1024 + half * DIMC + t] = (x0 - mean) * rstd * w[t] + bp[t];
  cls[(size_t)b * 1024 + half * DIMC + t + 256] = (x1 - mean) * rstd * w[t + 256] + bp[t + 256];
}

// ================= MFMA GEMM (unchanged) =================
template <int MODE>
__global__ __launch_bounds__(256) void mgemm_k(const u16* __restrict__ A, const u16* __restrict__ Bw,
    const float* __restrict__ bias, float* outf, u16* outb, int M, int N, int K,
    const float* aux0, const float* aux1, const float* aux2) {
  __shared__ u16 As[128 * 32];
  __shared__ u16 Bs[128 * 32];
  const int t = threadIdx.x;
  const int wid = t >> 6, l = t & 63;
  const int wm = wid >> 1, wn = wid & 1;
  const int fr = l & 15, kg = l >> 4;
  const int n0 = blockIdx.x * 128, m0 = blockIdx.y * 128;
  const int sr = l >> 2;
  const int sc4 = l & 3;
  const int scg = sc4 ^ (sr & 3);
  const int rdsw = (fr & 3);

  f32x4 acc[4][4];
#pragma unroll
  for (int i = 0; i < 4; i++)
#pragma unroll
    for (int j = 0; j < 4; j++) acc[i][j] = (f32x4){0.f, 0.f, 0.f, 0.f};

  for (int kq = 0; kq < K; kq += 32) {
#if !HAVE_GLDS
    uint4 ra[2], rb[2];
#pragma unroll
    for (int i = 0; i < 2; i++) {
      int r = wid * 32 + i * 16 + sr;
      ra[i] = *reinterpret_cast<const uint4*>(A + (size_t)(m0 + r) * K + kq + scg * 8);
      rb[i] = *reinterpret_cast<const uint4*>(Bw + (size_t)(n0 + r) * K + kq + scg * 8);
    }
#endif
    __syncthreads();
#if HAVE_GLDS
#pragma unroll
    for (int i = 0; i < 2; i++) {
      int r = wid * 32 + i * 16 + sr;
      gl_lds16(A + (size_t)(m0 + r) * K + kq + scg * 8, &As[(wid * 32 + i * 16) * 32]);
      gl_lds16(Bw + (size_t)(n0 + r) * K + kq + scg * 8, &Bs[(wid * 32 + i * 16) * 32]);
    }
#else
#pragma unroll
    for (int i = 0; i < 2; i++) {
      int r = wid * 32 + i * 16 + sr;
      *reinterpret_cast<uint4*>(&As[r * 32 + sc4 * 8]) = ra[i];
      *reinterpret_cast<uint4*>(&Bs[r * 32 + sc4 * 8]) = rb[i];
    }
#endif
    __syncthreads();
    bf16x8 af[4], bfr[4];
#pragma unroll
    for (int mi = 0; mi < 4; mi++) {
      int r = wm * 64 + mi * 16 + fr;
      af[mi] = *reinterpret_cast<const bf16x8*>(&As[r * 32 + (kg ^ rdsw) * 8]);
    }
#pragma unroll
    for (int nj = 0; nj < 4; nj++) {
      int n = wn * 64 + nj * 16 + fr;
      bfr[nj] = *reinterpret_cast<const bf16x8*>(&Bs[n * 32 + (kg ^ rdsw) * 8]);
    }
#pragma unroll
    for (int mi = 0; mi < 4; mi++)
#pragma unroll
      for (int nj = 0; nj < 4; nj++)
        acc[mi][nj] = __builtin_amdgcn_mfma_f32_16x16x32_bf16(af[mi], bfr[nj], acc[mi][nj], 0, 0, 0);
  }

#pragma unroll
  for (int mi = 0; mi < 4; mi++) {
#pragma unroll
    for (int q = 0; q < 4; q++) {
      int m = m0 + wm * 64 + mi * 16 + kg * 4 + q;
#pragma unroll
      for (int nj = 0; nj < 4; nj++) {
        int n = n0 + wn * 64 + nj * 16 + fr;
        float v = acc[mi][nj][q];
        if (MODE == 0) {
          outb[(size_t)m * N + n] = f2b(v + bias[n]);
        } else if (MODE == 1) {
          float z = v + bias[n];
          outb[(size_t)m * N + n] = f2b(0.5f * z * (1.0f + erff(z * 0.70710678118f)));
        } else if (MODE == 2) {
          size_t idx = (size_t)m * N + n;
          outf[idx] = v + bias[n] + aux0[idx];
        } else if (MODE == 3) {
          int b = m / NPIX, p = m - b * NPIX;
          float z = fmaxf(v * aux0[n] + aux1[n], 0.f) + aux2[(size_t)(p + 1) * DIMC + n];
          outf[((size_t)b * NSPA + p + 1) * DIMC + n] = z;
        } else if (MODE == 4) {
          int b = m / BANDS, band = m - b * BANDS;
          float z = fmaxf(v + bias[n], 0.f) + aux0[(size_t)(band + 1) * DIMC + n];
          outf[((size_t)b * NSPE + band + 1) * DIMC + n] = z;
        } else if (MODE == 5) {
          float z = v + bias[n];
          int tk, sidx;
          if (m < MXROWS) {
            int b = m / NSPA; tk = m - b * NSPA; sidx = b;
          } else {
            int ry = m - MXROWS; int b = ry / NSPE; tk = ry - b * NSPE; sidx = 128 + b;
          }
          if (tk == 0) outb[(size_t)sidx * DIMC + n] = f2b(z);
          else outf[(size_t)m * N + n] += z;
        }
      }
    }
  }
}

// ---------------- CLS swap ----------------
__global__ __launch_bounds__(256) void cls_swap_k(float* __restrict__ xsc,
                                                  const u16* __restrict__ clsprj) {
  int b = blockIdx.x, t = threadIdx.x;
  size_t xrow = (size_t)b * NSPA * DIMC;
  size_t yrow = ((size_t)MXROWS + (size_t)b * NSPE) * DIMC;
#pragma unroll
  for (int q = 0; q < 2; q++) {
    int d = t + q * 256;
    xsc[xrow + d] = 2.0f * xsc[xrow + d] + b2f(clsprj[(size_t)(128 + b) * DIMC + d]);
    xsc[yrow + d] = 2.0f * xsc[yrow + d] + b2f(clsprj[(size_t)b * DIMC + d]);
  }
}

// ================= V transpose: qkv V-part -> VT [(b*8+h)*64+d][KP] (zero-padded) =================
template <int NTOK, int KP>
__global__ __launch_bounds__(256) void vt_k(const u16* __restrict__ qkv, u16* __restrict__ vtout) {
  __shared__ u16 Vl[64 * 72];
  int h = blockIdx.x, b = blockIdx.y;
  int t = threadIdx.x;
  const size_t rs = 3 * DIMC;
  const u16* src = qkv + (size_t)b * NTOK * rs + 2 * DIMC + h * HD;
  u16* dst = vtout + (size_t)(b * NHEAD + h) * HD * KP;
  for (int kt = 0; kt < KP / 64; kt++) {
    __syncthreads();
#pragma unroll
    for (int p = 0; p < 2; p++) {
      int idx = p * 256 + t;
      int row = idx >> 3, c = idx & 7;
      int tok = kt * 64 + row;
      uint4 v = make_uint4(0, 0, 0, 0);
      if (tok < NTOK) v = *reinterpret_cast<const uint4*>(src + (size_t)tok * rs + c * 8);
      *reinterpret_cast<uint4*>(&Vl[row * 72 + c * 8]) = v;
    }
    __syncthreads();
    int d = t & 63, tg = t >> 6;
    unsigned pu[8];
#pragma unroll
    for (int i = 0; i < 8; i++) {
      unsigned a = Vl[(tg * 16 + 2 * i) * 72 + d];
      unsigned bb2 = Vl[(tg * 16 + 2 * i + 1) * 72 + d];
      pu[i] = (bb2 << 16) | a;
    }
    uint4 o0 = make_uint4(pu[0], pu[1], pu[2], pu[3]);
    uint4 o1 = make_uint4(pu[4], pu[5], pu[6], pu[7]);
    u16* dp = dst + (size_t)d * KP + kt * 64 + tg * 16;
    *reinterpret_cast<uint4*>(dp) = o0;
    *reinterpret_cast<uint4*>(dp + 8) = o1;
  }
}

// ================= MFMA flash attention, swapped-operand (S^T / O^T) =================
// Block = (qtile, h, b); 4 waves; wave w owns q-rows qt*64+w*16..+15.
// LDS tiles 64x64 bf16, slot c holds global chunk c^(row&7) (pre-swizzled source, rule #21).
__device__ __forceinline__ int fsw(int row, int chunk) {
  return row * 64 + ((chunk ^ (row & 7)) << 3);
}
// stage one 64x64 bf16 tile; wave w covers rows w*16..+15; gsrc points at tile row 0.
__device__ __forceinline__ void stage64(const u16* __restrict__ gsrc, size_t gstride,
                                        u16* lds, int w, int l) {
#pragma unroll
  for (int i = 0; i < 2; i++) {
    int r = w * 16 + i * 8 + (l >> 3);
    int c = l & 7;
    int scg = c ^ (r & 7);
    const u16* g = gsrc + (size_t)r * gstride + scg * 8;
#if HAVE_GLDS
    gl_lds16(g, &lds[(w * 16 + i * 8) * 64]);
#else
    *reinterpret_cast<uint4*>(&lds[r * 64 + c * 8]) = *reinterpret_cast<const uint4*>(g);
#endif
  }
}

__global__ __launch_bounds__(256) void flashm_k(const u16* __restrict__ qkv,
    const u16* __restrict__ vt, u16* __restrict__ o, int N, int kpad, float scale) {
  __shared__ u16 Qs[64 * 64], Ks[64 * 64], Vs[64 * 64];
  __shared__ u16 Ol[64 * 72];
  const int qt = blockIdx.x, h = blockIdx.y, b = blockIdx.z;
  const int t = threadIdx.x;
  const int w = t >> 6, l = t & 63;
  const int lr = l & 15, lk = l >> 4;
  const size_t rs = 3 * DIMC;
  const size_t qbase = (size_t)b * N * rs + h * HD;
  const u16* vbase = vt + (size_t)(b * NHEAD + h) * HD * kpad;

  // ---- stage Q tile (rows qt*64..+63) ----
  stage64(qkv + qbase + (size_t)(qt * 64) * rs, rs, Qs, w, l);
  __syncthreads();
  // Q B-fragments (col = this wave's q-row = w*16+lr), hoisted for all tiles
  bf16x8 bq0 = *reinterpret_cast<const bf16x8*>(&Qs[fsw(w * 16 + lr, lk)]);
  bf16x8 bq1 = *reinterpret_cast<const bf16x8*>(&Qs[fsw(w * 16 + lr, 4 + lk)]);

  float m_i = -1e30f, l_i = 0.f;
  f32x4 oacc[4];
#pragma unroll
  for (int mi = 0; mi < 4; mi++) oacc[mi] = (f32x4){0.f, 0.f, 0.f, 0.f};

  const int nkt = (kpad + 63) >> 6;
  for (int kt = 0; kt < nkt; kt++) {
    __syncthreads();  // previous tile's reads done
    stage64(qkv + qbase + DIMC + (size_t)(kt * 64) * rs, rs, Ks, w, l);   // K rows (tokens)
    stage64(vbase + kt * 64, (size_t)kpad, Vs, w, l);                     // VT rows (dims)
    __syncthreads();

    // S^T = K · Q^T : st[mi] covers krows mi*16..+15 (local), qcols = wave's 16 rows
    f32x4 st[4];
#pragma unroll
    for (int mi = 0; mi < 4; mi++) st[mi] = (f32x4){0.f, 0.f, 0.f, 0.f};
#pragma unroll
    for (int mi = 0; mi < 4; mi++) {
      bf16x8 ak0 = *reinterpret_cast<const bf16x8*>(&Ks[fsw(mi * 16 + lr, lk)]);
      bf16x8 ak1 = *reinterpret_cast<const bf16x8*>(&Ks[fsw(mi * 16 + lr, 4 + lk)]);
      st[mi] = __builtin_amdgcn_mfma_f32_16x16x32_bf16(ak0, bq0, st[mi], 0, 0, 0);
      st[mi] = __builtin_amdgcn_mfma_f32_16x16x32_bf16(ak1, bq1, st[mi], 0, 0, 0);
    }

    // online softmax: lane holds 16 k-values of ONE q-row (col = lr) -> scalar m/l
    float sv[4][4];
    float tmax = -1e30f;
#pragma unroll
    for (int mi = 0; mi < 4; mi++)
#pragma unroll
      for (int q = 0; q < 4; q++) {
        int kgl = kt * 64 + mi * 16 + lk * 4 + q;
        float v = (kgl < N) ? st[mi][q] * scale : -1e30f;
        sv[mi][q] = v;
        tmax = fmaxf(tmax, v);
      }
    tmax = fmaxf(tmax, __shfl_xor(tmax, 16));
    tmax = fmaxf(tmax, __shfl_xor(tmax, 32));
    float mn = fmaxf(m_i, tmax);
    float corr = __expf(m_i - mn);
    m_i = mn;
    float rsum = 0.f;
#pragma unroll
    for (int mi = 0; mi < 4; mi++)
#pragma unroll
      for (int q = 0; q < 4; q++) {
        float p = __expf(sv[mi][q] - mn);
        sv[mi][q] = p;
        rsum += p;
      }
    rsum += __shfl_xor(rsum, 16);
    rsum += __shfl_xor(rsum, 32);
    l_i = l_i * corr + rsum;
#pragma unroll
    for (int mi = 0; mi < 4; mi++) oacc[mi] *= corr;

    // pack P^T pairs and redistribute in-register to PV B-fragments (P row-frags)
    unsigned pk[4][2];
#pragma unroll
    for (int mi = 0; mi < 4; mi++) {
      pk[mi][0] = ((unsigned)f2b(sv[mi][1]) << 16) | (unsigned)f2b(sv[mi][0]);
      pk[mi][1] = ((unsigned)f2b(sv[mi][3]) << 16) | (unsigned)f2b(sv[mi][2]);
    }
    int src0 = lr + 32 * (lk & 1);
    int src1 = src0 + 16;
    bool hi = lk >= 2;
    bf16x8 pbv[2];
#pragma unroll
    for (int c = 0; c < 2; c++) {
      unsigned a0 = __shfl(pk[2 * c][0], src0), b0 = __shfl(pk[2 * c + 1][0], src0);
      unsigned a1 = __shfl(pk[2 * c][1], src0), b1 = __shfl(pk[2 * c + 1][1], src0);
      unsigned a2 = __shfl(pk[2 * c][0], src1), b2 = __shfl(pk[2 * c + 1][0], src1);
      unsigned a3 = __shfl(pk[2 * c][1], src1), b3 = __shfl(pk[2 * c + 1][1], src1);
      union { unsigned u[4]; bf16x8 v; } pu;
      pu.u[0] = hi ? b0 : a0;
      pu.u[1] = hi ? b1 : a1;
      pu.u[2] = hi ? b2 : a2;
      pu.u[3] = hi ? b3 : a3;
      pbv[c] = pu.v;
    }

    // O^T += VT · P^T  (A = VT rows = dims, B = P row-frags)
#pragma unroll
    for (int mi = 0; mi < 4; mi++) {
      bf16x8 av0 = *reinterpret_cast<const bf16x8*>(&Vs[fsw(mi * 16 + lr, lk)]);
      bf16x8 av1 = *reinterpret_cast<const bf16x8*>(&Vs[fsw(mi * 16 + lr, 4 + lk)]);
      oacc[mi] = __builtin_amdgcn_mfma_f32_16x16x32_bf16(av0, pbv[0], oacc[mi], 0, 0, 0);
      oacc[mi] = __builtin_amdgcn_mfma_f32_16x16x32_bf16(av1, pbv[1], oacc[mi], 0, 0, 0);
    }
  }

  // ---- O^T -> LDS (packed b64), transpose, coalesced global write ----
  float invl = 1.0f / l_i;
#pragma unroll
  for (int mi = 0; mi < 4; mi++) {
    unsigned lo = ((unsigned)f2b(oacc[mi][1] * invl) << 16) | (unsigned)f2b(oacc[mi][0] * invl);
    unsigned hi2 = ((unsigned)f2b(oacc[mi][3] * invl) << 16) | (unsigned)f2b(oacc[mi][2] * invl);
    uint2 pr; pr.x = lo; pr.y = hi2;
    *reinterpret_cast<uint2*>(&Ol[(w * 16 + lr) * 72 + mi * 16 + lk * 4]) = pr;
  }
  __syncthreads();
  {
    int row = t >> 2, c4 = t & 3;
    int qrow = qt * 64 + row;
    if (qrow < N) {
      uint4 v0 = *reinterpret_cast<const uint4*>(&Ol[row * 72 + c4 * 8]);
      uint4 v1 = *reinterpret_cast<const uint4*>(&Ol[row * 72 + (c4 + 4) * 8]);
      u16* op = o + ((size_t)b * N + qrow) * DIMC + h * HD;
      *reinterpret_cast<uint4*>(op + c4 * 8) = v0;
      *reinterpret_cast<uint4*>(op + (c4 + 4) * 8) = v1;
    }
  }
}

// ---------------- head ----------------
__global__ __launch_bounds__(256) void head_k(const float* __restrict__ cls,
    const float* __restrict__ hw, const float* __restrict__ hb, float* __restrict__ out) {
  __shared__ float cl[1024];
  __shared__ float part[256];
  int b = blockIdx.x, t = threadIdx.x;
  for (int idx = t; idx < 1024; idx += 256) cl[idx] = cls[(size_t)b * 1024 + idx];
  __syncthreads();
  int c = t >> 4, sl = t & 15;
  float p = 0.f;
  for (int j = 0; j < 64; j++) p += cl[sl * 64 + j] * hw[(size_t)c * 1024 + sl * 64 + j];
  part[t] = p;
  __syncthreads();
  if (sl == 0) {
    float sum = hb[c];
    for (int q = 0; q < 16; q++) sum += part[c * 16 + q];
    out[(size_t)b * 16 + c] = sum;
  }
}

extern "C" void kernel_launch(void* const* d_in, const int* in_sizes, int n_in,
                              void* d_out, int out_size, void* d_ws, size_t ws_size,
                              hipStream_t stream) {
  const float* x        = (const float*)d_in[0];
  const float* conv_h_w = (const float*)d_in[1];
  const float* conv_h_b = (const float*)d_in[2];
  const float* bn_h_g   = (const float*)d_in[3];
  const float* bn_h_b   = (const float*)d_in[4];
  const float* bn_h_m   = (const float*)d_in[5];
  const float* bn_h_v   = (const float*)d_in[6];
  const float* cnn_conv_w = (const float*)d_in[7];
  const float* cnn_conv_b = (const float*)d_in[8];
  const float* cnn_bn_g = (const float*)d_in[9];
  const float* cnn_bn_b = (const float*)d_in[10];
  const float* cnn_bn_m = (const float*)d_in[11];
  const float* cnn_bn_v = (const float*)d_in[12];
  const float* cnn_fc_w = (const float*)d_in[13];
  const float* cnn_fc_b = (const float*)d_in[14];
  const float* spa_cls  = (const float*)d_in[15];
  const float* spe_cls  = (const float*)d_in[16];
  const float* spa_pos  = (const float*)d_in[17];
  const float* spe_pos  = (const float*)d_in[18];
  const float* blk_n1_w = (const float*)d_in[19];
  const float* blk_n1_b = (const float*)d_in[20];
  const float* blk_n2_w = (const float*)d_in[21];
  const float* blk_n2_b = (const float*)d_in[22];
  const float* blk_qkv_w = (const float*)d_in[23];
  const float* blk_qkv_b = (const float*)d_in[24];
  const float* blk_proj_w = (const float*)d_in[25];
  const float* blk_proj_b = (const float*)d_in[26];
  const float* blk_fc1_w = (const float*)d_in[27];
  const float* blk_fc1_b = (const float*)d_in[28];
  const float* blk_fc2_w = (const float*)d_in[29];
  const float* blk_fc2_b = (const float*)d_in[30];
  const float* norm1_w  = (const float*)d_in[31];
  const float* norm1_b  = (const float*)d_in[32];
  const float* norm2_w  = (const float*)d_in[33];
  const float* norm2_b  = (const float*)d_in[34];
  const float* head_w   = (const float*)d_in[35];
  const float* head_b   = (const float*)d_in[36];

  char* ws = (char*)d_ws;
  size_t off = 0;
  auto take = [&](size_t bytes) -> char* {
    char* p = ws + off;
    off = (off + bytes + 255) & ~(size_t)255;
    return p;
  };
  const int Mx = MXROWS, M2 = M2ROWS;
  const int Mc = NB * NPIX;   // 28800
  const int Mf = NB * BANDS;  // 3840
  float* xsc  = (float*)take((size_t)M2 * DIMC * 4);
  float* ysb  = xsc + (size_t)Mx * DIMC;
  u16* xyin   = (u16*)take((size_t)M2 * DIMC * 2);      // LN out; vtx overlays during attention
  u16* qkvxy  = (u16*)take((size_t)M2 * 3 * DIMC * 2);
  u16* oxy    = (u16*)take((size_t)M2 * DIMC * 2);
  u16* clsprj = (u16*)take((size_t)256 * DIMC * 2);
  float* clsb = (float*)take((size_t)NB * 1024 * 4);
  u16* pooled = (u16*)take((size_t)Mf * 128 * 2);
  u16* qkvWb  = (u16*)take((size_t)2 * 3 * DIMC * DIMC * 2);
  u16* projWb = (u16*)take((size_t)2 * DIMC * DIMC * 2);
  u16* fc1Wb  = (u16*)take((size_t)2 * DIMC * DIMC * 2);
  u16* fc2Wb  = (u16*)take((size_t)2 * DIMC * DIMC * 2);
  u16* fcWb   = (u16*)take((size_t)DIMC * 128 * 2);
  u16* convWb = (u16*)take((size_t)DIMC * KCONV * 2);
  float* bnsc = (float*)take(DIMC * 4);
  float* bnsh = (float*)take(DIMC * 4);
  u16* vty    = (u16*)take((size_t)NB * NHEAD * HD * 64 * 2);  // 8.4MB
  u16* Acol   = qkvxy;
  u16* vtx    = xyin;  // 33.55MB <= xyin (33.69MB); xyin dead between qkv-GEMM and LN2

  // ---- weight prep ----
  cvt_k<<<1024, 256, 0, stream>>>(blk_qkv_w, qkvWb, 2 * 3 * DIMC * DIMC);
  cvt_k<<<1024, 256, 0, stream>>>(blk_proj_w, projWb, 2 * DIMC * DIMC);
  cvt_k<<<1024, 256, 0, stream>>>(blk_fc1_w, fc1Wb, 2 * DIMC * DIMC);
  cvt_k<<<1024, 256, 0, stream>>>(blk_fc2_w, fc2Wb, 2 * DIMC * DIMC);
  cvt_k<<<256, 256, 0, stream>>>(cnn_fc_w, fcWb, DIMC * 128);
  convw_k<<<(DIMC * KCONV + 255) / 256, 256, 0, stream>>>(conv_h_w, convWb);
  bnprep_k<<<2, 256, 0, stream>>>(bn_h_g, bn_h_b, bn_h_m, bn_h_v, conv_h_b, bnsc, bnsh);

  // ---- stem ----
  cls_init_k<<<NB, 256, 0, stream>>>(spa_cls, spe_cls, spa_pos, spe_pos, xsc, ysb);
  im2col_k<<<(Mc * 32 + 255) / 256, 256, 0, stream>>>(x, Acol);
  mgemm_k<3><<<dim3(4, Mc / 128), 256, 0, stream>>>(Acol, convWb, nullptr, xsc, nullptr,
      Mc, DIMC, KCONV, bnsc, bnsh, spa_pos);
  cnn_conv_k<<<Mf / 2, 256, 0, stream>>>(x, cnn_conv_w, cnn_conv_b, cnn_bn_g, cnn_bn_b,
                                         cnn_bn_m, cnn_bn_v, pooled);
  mgemm_k<4><<<dim3(4, Mf / 128), 256, 0, stream>>>(pooled, fcWb, cnn_fc_b, ysb, nullptr,
      Mf, DIMC, 128, spe_pos, nullptr, nullptr);

  // ---- transformer blocks ----
  for (int i = 0; i < 2; i++) {
    const float* n1w = blk_n1_w + i * DIMC;
    const float* n1b = blk_n1_b + i * DIMC;
    const float* n2w = blk_n2_w + i * DIMC;
    const float* n2b = blk_n2_b + i * DIMC;
    const u16* qkvW = qkvWb + (size_t)i * 3 * DIMC * DIMC;
    const float* qkvB = blk_qkv_b + (size_t)i * 3 * DIMC;
    const u16* projW = projWb + (size_t)i * DIMC * DIMC;
    const float* projB = blk_proj_b + (size_t)i * DIMC;
    const u16* fc1W = fc1Wb + (size_t)i * DIMC * DIMC;
    const float* fc1B = blk_fc1_b + (size_t)i * DIMC;
    const u16* fc2W = fc2Wb + (size_t)i * DIMC * DIMC;
    const float* fc2B = blk_fc2_b + (size_t)i * DIMC;

    ln_c_k<1><<<M2, 256, 0, stream>>>(xsc, n1w, n1b, xyin);

    mgemm_k<0><<<dim3(12, M2 / 128), 256, 0, stream>>>(xyin, qkvW, qkvB, nullptr, qkvxy,
        M2, 3 * DIMC, DIMC, nullptr, nullptr, nullptr);

    vt_k<NSPA, 256><<<dim3(NHEAD, NB), 256, 0, stream>>>(qkvxy, vtx);
    vt_k<NSPE, 64><<<dim3(NHEAD, NB), 256, 0, stream>>>(qkvxy + (size_t)Mx * 3 * DIMC, vty);

    flashm_k<<<dim3(4, NHEAD, NB), 256, 0, stream>>>(qkvxy, vtx, oxy, NSPA, 256, 0.125f);
    flashm_k<<<dim3(1, NHEAD, NB), 256, 0, stream>>>(qkvxy + (size_t)Mx * 3 * DIMC, vty,
                                                     oxy + (size_t)Mx * DIMC, NSPE, 64, 0.125f);

    mgemm_k<5><<<dim3(4, M2 / 128), 256, 0, stream>>>(oxy, projW, projB, xsc, clsprj,
        M2, DIMC, DIMC, nullptr, nullptr, nullptr);
    cls_swap_k<<<NB, 256, 0, stream>>>(xsc, clsprj);

    ln_c_k<0><<<M2, 256, 0, stream>>>(xsc, n2w, n2b, xyin);
    mgemm_k<1><<<dim3(4, M2 / 128), 256, 0, stream>>>(xyin, fc1W, fc1B, nullptr, qkvxy,
        M2, DIMC, DIMC, nullptr, nullptr, nullptr);
    mgemm_k<2><<<dim3(4, M2 / 128), 256, 0, stream>>>(qkvxy, fc2W, fc2B, xsc, nullptr,
        M2, DIMC, DIMC, xsc, nullptr, nullptr);
  }

  // ---- head ----
  ln_cls_k<<<NB * 2, 256, 0, stream>>>(xsc, ysb, norm1_w, norm1_b, norm2_w, norm2_b, clsb);
  head_k<<<NB, 256, 0, stream>>>(clsb, head_w, head_b, (float*)d_out);
}

// Round 6
// 872.719 us; speedup vs baseline: 6.0307x; 1.0757x over previous
//
#include <hip/hip_runtime.h>
#include <hip/hip_bf16.h>

typedef unsigned short u16;
typedef __attribute__((ext_vector_type(8))) short bf16x8;
typedef __attribute__((ext_vector_type(4))) float f32x4;

#define NB 128
#define BANDS 30
#define HWD 15
#define NPIX 225
#define DIMC 512
#define NHEAD 8
#define HD 64
#define NSPA 226
#define NSPE 31
#define EPSF 1e-5f
#define KCONV 320     // 270 padded to multiple of 64
#define MXROWS 28928  // NB*NSPA
#define MYROWS 3968   // NB*NSPE
#define M2ROWS 32896  // MXROWS+MYROWS

__device__ __forceinline__ float b2f(u16 u) { return __uint_as_float(((unsigned)u) << 16); }
__device__ __forceinline__ u16 f2b(float f) {
  __hip_bfloat16 h = __float2bfloat16(f);
  return *reinterpret_cast<u16*>(&h);
}

#if __has_builtin(__builtin_amdgcn_global_load_lds)
#define HAVE_GLDS 1
__device__ __forceinline__ void gl_lds16(const void* g, void* l) {
  __builtin_amdgcn_global_load_lds((const __attribute__((address_space(1))) void*)g,
                                   (__attribute__((address_space(3))) void*)l, 16, 0, 0);
}
#else
#define HAVE_GLDS 0
#endif

// ---------------- weight f32 -> bf16 ----------------
__global__ __launch_bounds__(256) void cvt_k(const float* __restrict__ s, u16* __restrict__ d, int n) {
  for (int i = blockIdx.x * 256 + threadIdx.x; i < n; i += gridDim.x * 256) d[i] = f2b(s[i]);
}

// conv_h_w (512,270) -> padded bf16 (512,320)
__global__ __launch_bounds__(256) void convw_k(const float* __restrict__ w, u16* __restrict__ d) {
  int i = blockIdx.x * 256 + threadIdx.x;
  if (i >= DIMC * KCONV) return;
  int r = i / KCONV, c = i - r * KCONV;
  d[i] = (c < 270) ? f2b(w[r * 270 + c]) : (u16)0;
}

// BN fold
__global__ __launch_bounds__(256) void bnprep_k(const float* __restrict__ g, const float* __restrict__ bb,
    const float* __restrict__ bm, const float* __restrict__ bv, const float* __restrict__ cb,
    float* __restrict__ sc, float* __restrict__ sh) {
  int n = blockIdx.x * 256 + threadIdx.x;
  if (n < DIMC) {
    float inv = g[n] * rsqrtf(bv[n] + EPSF);
    sc[n] = inv;
    sh[n] = (cb[n] - bm[n]) * inv + bb[n];
  }
}

// ---------------- im2col: x (128,30,15,15) f32 -> Acol (28800, 320) bf16 ----------------
// one thread per (m, 8-col group); writes one uint4.
__global__ __launch_bounds__(256) void im2col_k(const float* __restrict__ x, u16* __restrict__ Ac) {
  int idx = blockIdx.x * 256 + threadIdx.x;  // m*40 + g
  if (idx >= 28800 * 40) return;
  int m = idx / 40, g = idx - m * 40;
  int b = m / NPIX, p = m - b * NPIX;
  int i = p / 15, j = p - i * 15;
  union { u16 v[8]; uint4 u; } out;
#pragma unroll
  for (int e = 0; e < 8; e++) {
    int c = g * 8 + e;
    float v = 0.f;
    if (c < 270) {
      int band = c / 9, q = c - band * 9;
      int di = q / 3, dj = q - di * 3;
      int ii = i + di - 1, jj = j + dj - 1;
      if ((unsigned)ii < 15u && (unsigned)jj < 15u)
        v = x[((size_t)b * BANDS + band) * NPIX + ii * 15 + jj];
    }
    out.v[e] = f2b(v);
  }
  *reinterpret_cast<uint4*>(Ac + (size_t)m * KCONV + g * 8) = out.u;
}

// ---------------- CLS row init ----------------
__global__ __launch_bounds__(256) void cls_init_k(const float* __restrict__ spa_cls,
    const float* __restrict__ spe_cls, const float* __restrict__ spa_pos,
    const float* __restrict__ spe_pos, float* __restrict__ xs, float* __restrict__ ys) {
  int b = blockIdx.x, t = threadIdx.x;
  int d0 = t, d1 = t + 256;
  xs[(size_t)b * NSPA * DIMC + d0] = spa_cls[d0] + spa_pos[d0];
  xs[(size_t)b * NSPA * DIMC + d1] = spa_cls[d1] + spa_pos[d1];
  ys[(size_t)b * NSPE * DIMC + d0] = spe_cls[d0] + spe_pos[d0];
  ys[(size_t)b * NSPE * DIMC + d1] = spe_cls[d1] + spe_pos[d1];
}

// ------------- per-band CNN conv + BN + ReLU + mean (register-rolling rows) -------------
__global__ __launch_bounds__(256) void cnn_conv_k(const float* __restrict__ x,
    const float* __restrict__ w, const float* __restrict__ cb, const float* __restrict__ g,
    const float* __restrict__ bb, const float* __restrict__ bm, const float* __restrict__ bv,
    u16* __restrict__ pooled) {
  __shared__ float img[2][NPIX];
  int b0 = blockIdx.x * 2;
  int t = threadIdx.x;
  for (int idx = t; idx < 2 * NPIX; idx += 256) ((float*)img)[idx] = x[(size_t)b0 * NPIX + idx];
  __syncthreads();
  int half = t >> 7, ch = t & 127;
  const float* im = img[half];
  float inv = g[ch] * rsqrtf(bv[ch] + EPSF);
  float beta = bb[ch] - bm[ch] * inv;
  float w9[9];
#pragma unroll
  for (int q = 0; q < 9; q++) w9[q] = w[ch * 9 + q] * inv;
  float bias = cb[ch] * inv + beta;

  float rm[15], rc[15], rp[15];
#pragma unroll
  for (int j = 0; j < 15; j++) { rm[j] = 0.f; rc[j] = im[j]; }
  float sum = 0.f;
  for (int i = 0; i < 15; i++) {
#pragma unroll
    for (int j = 0; j < 15; j++) rp[j] = (i < 14) ? im[(i + 1) * 15 + j] : 0.f;
    float a[15];
#pragma unroll
    for (int j = 0; j < 15; j++) a[j] = fmaf(w9[4], rc[j], bias);
#pragma unroll
    for (int j = 0; j < 15; j++) {
      if (j > 0)  a[j] = fmaf(w9[3], rc[j - 1], a[j]);
      if (j < 14) a[j] = fmaf(w9[5], rc[j + 1], a[j]);
      a[j] = fmaf(w9[1], rm[j], a[j]);
      if (j > 0)  a[j] = fmaf(w9[0], rm[j - 1], a[j]);
      if (j < 14) a[j] = fmaf(w9[2], rm[j + 1], a[j]);
      a[j] = fmaf(w9[7], rp[j], a[j]);
      if (j > 0)  a[j] = fmaf(w9[6], rp[j - 1], a[j]);
      if (j < 14) a[j] = fmaf(w9[8], rp[j + 1], a[j]);
    }
#pragma unroll
    for (int j = 0; j < 15; j++) sum += fmaxf(a[j], 0.f);
#pragma unroll
    for (int j = 0; j < 15; j++) { rm[j] = rc[j]; rc[j] = rp[j]; }
  }
  pooled[(size_t)(b0 + half) * 128 + ch] = f2b(sum * (1.0f / 225.0f));
}

// ---------------- LayerNorm over combined rows ----------------
template <int GATHER>
__global__ __launch_bounds__(256) void ln_c_k(const float* __restrict__ xsc,
    const float* __restrict__ w, const float* __restrict__ bprm, u16* __restrict__ out) {
  int row = blockIdx.x;
  const float* src;
  if (GATHER) {
    if (row < MXROWS) {
      int b = row / NSPA, tk = row - b * NSPA;
      src = (tk == 0) ? xsc + ((size_t)MXROWS + (size_t)b * NSPE) * DIMC
                      : xsc + (size_t)row * DIMC;
    } else {
      int ry = row - MXROWS;
      int b = ry / NSPE, tk = ry - b * NSPE;
      src = (tk == 0) ? xsc + (size_t)b * NSPA * DIMC : xsc + (size_t)row * DIMC;
    }
  } else {
    src = xsc + (size_t)row * DIMC;
  }
  int t = threadIdx.x;
  float x0 = src[t], x1 = src[t + 256];
  float s = x0 + x1, sq = x0 * x0 + x1 * x1;
  for (int off = 32; off; off >>= 1) { s += __shfl_down(s, off); sq += __shfl_down(sq, off); }
  __shared__ float sa[4], sb4[4];
  int wid = t >> 6;
  if ((t & 63) == 0) { sa[wid] = s; sb4[wid] = sq; }
  __syncthreads();
  s = sa[0] + sa[1] + sa[2] + sa[3];
  sq = sb4[0] + sb4[1] + sb4[2] + sb4[3];
  float mean = s * (1.0f / 512.0f);
  float var = sq * (1.0f / 512.0f) - mean * mean;
  float rstd = rsqrtf(var + EPSF);
  out[(size_t)row * DIMC + t] = f2b((x0 - mean) * rstd * w[t] + bprm[t]);
  out[(size_t)row * DIMC + t + 256] = f2b((x1 - mean) * rstd * w[t + 256] + bprm[t + 256]);
}

// ---------------- final LN on CLS tokens -> f32 (B,1024) ----------------
__global__ __launch_bounds__(256) void ln_cls_k(const float* __restrict__ xs,
    const float* __restrict__ ys, const float* __restrict__ w1, const float* __restrict__ b1,
    const float* __restrict__ w2, const float* __restrict__ b2, float* __restrict__ cls) {
  int gb = blockIdx.x;
  int half = gb & 1, b = gb >> 1;
  const float* src = half ? (ys + (size_t)b * NSPE * DIMC) : (xs + (size_t)b * NSPA * DIMC);
  const float* w = half ? w2 : w1;
  const float* bp = half ? b2 : b1;
  int t = threadIdx.x;
  float x0 = src[t], x1 = src[t + 256];
  float s = x0 + x1, sq = x0 * x0 + x1 * x1;
  for (int off = 32; off; off >>= 1) { s += __shfl_down(s, off); sq += __shfl_down(sq, off); }
  __shared__ float sa[4], sb4[4];
  int wid = t >> 6;
  if ((t & 63) == 0) { sa[wid] = s; sb4[wid] = sq; }
  __syncthreads();
  s = sa[0] + sa[1] + sa[2] + sa[3];
  sq = sb4[0] + sb4[1] + sb4[2] + sb4[3];
  float mean = s * (1.0f / 512.0f);
  float var = sq * (1.0f / 512.0f) - mean * mean;
  float rstd = rsqrtf(var + EPSF);
  cls[(size_t)b * 1024 + half * DIMC + t] = (x0 - mean) * rstd * w[t] + bp[t];
  cls[(size_t)b * 1024 + half * DIMC + t + 256] = (x1 - mean) * rstd * w[t + 256] + bp[t + 256];
}

// ================= MFMA GEMM, BK=64, st_16x32-style swizzle, XCD-chunked blocks =================
// LDS rows 128B (full bank wrap); slot s of row r holds global chunk s^(r&7).
// MODE 0: bf16 out = acc+bias   MODE 1: bf16 gelu   MODE 2: f32 acc+bias+resid
// MODE 3: conv scatter          MODE 4: fc_spe scatter
// MODE 5: proj+residual-combine (CLS rows -> clsprj side buffer)
template <int MODE>
__global__ __launch_bounds__(256) void mgemm_k(const u16* __restrict__ A, const u16* __restrict__ Bw,
    const float* __restrict__ bias, float* outf, u16* outb, int M, int N, int K,
    const float* aux0, const float* aux1, const float* aux2) {
  __shared__ u16 As[128 * 64];
  __shared__ u16 Bs[128 * 64];
  const int t = threadIdx.x;
  const int wid = t >> 6, l = t & 63;
  const int wm = wid >> 1, wn = wid & 1;
  const int fr = l & 15, kg = l >> 4;

  // bijective XCD-chunked swizzle (m204): contiguous logical ids per XCD
  const int nx = gridDim.x, nwg = nx * gridDim.y;
  int hlin = blockIdx.y * nx + blockIdx.x;
  int xcd = hlin & 7, j = hlin >> 3;
  int q8 = nwg >> 3, r8 = nwg & 7;
  int L = (xcd < r8 ? xcd * (q8 + 1) : r8 * (q8 + 1) + (xcd - r8) * q8) + j;
  const int n0 = (L % nx) * 128, m0 = (L / nx) * 128;

  const int srow = l >> 3;   // 0..7 within an 8-row staging slice
  const int sslot = l & 7;   // slot this lane's 16B lands in

  f32x4 acc[4][4];
#pragma unroll
  for (int i = 0; i < 4; i++)
#pragma unroll
    for (int j2 = 0; j2 < 4; j2++) acc[i][j2] = (f32x4){0.f, 0.f, 0.f, 0.f};

  for (int kq = 0; kq < K; kq += 64) {
#if !HAVE_GLDS
    uint4 ra[4], rb[4];
#pragma unroll
    for (int i = 0; i < 4; i++) {
      int r = wid * 32 + i * 8 + srow;
      int cg = sslot ^ (r & 7);
      ra[i] = *reinterpret_cast<const uint4*>(A + (size_t)(m0 + r) * K + kq + cg * 8);
      rb[i] = *reinterpret_cast<const uint4*>(Bw + (size_t)(n0 + r) * K + kq + cg * 8);
    }
#endif
    __syncthreads();  // previous compute done before overwrite
#if HAVE_GLDS
#pragma unroll
    for (int i = 0; i < 4; i++) {
      int r = wid * 32 + i * 8 + srow;
      int cg = sslot ^ (r & 7);
      gl_lds16(A + (size_t)(m0 + r) * K + kq + cg * 8, &As[(wid * 32 + i * 8) * 64]);
      gl_lds16(Bw + (size_t)(n0 + r) * K + kq + cg * 8, &Bs[(wid * 32 + i * 8) * 64]);
    }
#else
#pragma unroll
    for (int i = 0; i < 4; i++) {
      int r = wid * 32 + i * 8 + srow;
      *reinterpret_cast<uint4*>(&As[r * 64 + sslot * 8]) = ra[i];
      *reinterpret_cast<uint4*>(&Bs[r * 64 + sslot * 8]) = rb[i];
    }
#endif
    __syncthreads();  // staged
#pragma unroll
    for (int h = 0; h < 2; h++) {
      bf16x8 af[4], bfr[4];
#pragma unroll
      for (int mi = 0; mi < 4; mi++) {
        int r = wm * 64 + mi * 16 + fr;
        af[mi] = *reinterpret_cast<const bf16x8*>(&As[r * 64 + (((h * 4 + kg) ^ (fr & 7)) * 8)]);
      }
#pragma unroll
      for (int nj = 0; nj < 4; nj++) {
        int n = wn * 64 + nj * 16 + fr;
        bfr[nj] = *reinterpret_cast<const bf16x8*>(&Bs[n * 64 + (((h * 4 + kg) ^ (fr & 7)) * 8)]);
      }
#pragma unroll
      for (int mi = 0; mi < 4; mi++)
#pragma unroll
        for (int nj = 0; nj < 4; nj++)
          acc[mi][nj] = __builtin_amdgcn_mfma_f32_16x16x32_bf16(af[mi], bfr[nj], acc[mi][nj], 0, 0, 0);
    }
  }

#pragma unroll
  for (int mi = 0; mi < 4; mi++) {
#pragma unroll
    for (int q = 0; q < 4; q++) {
      int m = m0 + wm * 64 + mi * 16 + kg * 4 + q;
#pragma unroll
      for (int nj = 0; nj < 4; nj++) {
        int n = n0 + wn * 64 + nj * 16 + fr;
        float v = acc[mi][nj][q];
        if (MODE == 0) {
          outb[(size_t)m * N + n] = f2b(v + bias[n]);
        } else if (MODE == 1) {
          float z = v + bias[n];
          outb[(size_t)m * N + n] = f2b(0.5f * z * (1.0f + erff(z * 0.70710678118f)));
        } else if (MODE == 2) {
          size_t idx = (size_t)m * N + n;
          outf[idx] = v + bias[n] + aux0[idx];
        } else if (MODE == 3) {
          int b = m / NPIX, p = m - b * NPIX;
          float z = fmaxf(v * aux0[n] + aux1[n], 0.f) + aux2[(size_t)(p + 1) * DIMC + n];
          outf[((size_t)b * NSPA + p + 1) * DIMC + n] = z;
        } else if (MODE == 4) {
          int b = m / BANDS, band = m - b * BANDS;
          float z = fmaxf(v + bias[n], 0.f) + aux0[(size_t)(band + 1) * DIMC + n];
          outf[((size_t)b * NSPE + band + 1) * DIMC + n] = z;
        } else if (MODE == 5) {
          float z = v + bias[n];
          int tk, sidx;
          if (m < MXROWS) {
            int b = m / NSPA; tk = m - b * NSPA; sidx = b;
          } else {
            int ry = m - MXROWS; int b = ry / NSPE; tk = ry - b * NSPE; sidx = 128 + b;
          }
          if (tk == 0) outb[(size_t)sidx * DIMC + n] = f2b(z);
          else outf[(size_t)m * N + n] += z;
        }
      }
    }
  }
}

// ---------------- CLS swap ----------------
__global__ __launch_bounds__(256) void cls_swap_k(float* __restrict__ xsc,
                                                  const u16* __restrict__ clsprj) {
  int b = blockIdx.x, t = threadIdx.x;
  size_t xrow = (size_t)b * NSPA * DIMC;
  size_t yrow = ((size_t)MXROWS + (size_t)b * NSPE) * DIMC;
#pragma unroll
  for (int q = 0; q < 2; q++) {
    int d = t + q * 256;
    xsc[xrow + d] = 2.0f * xsc[xrow + d] + b2f(clsprj[(size_t)(128 + b) * DIMC + d]);
    xsc[yrow + d] = 2.0f * xsc[yrow + d] + b2f(clsprj[(size_t)b * DIMC + d]);
  }
}

// ================= V transpose =================
template <int NTOK, int KP>
__global__ __launch_bounds__(256) void vt_k(const u16* __restrict__ qkv, u16* __restrict__ vtout) {
  __shared__ u16 Vl[64 * 72];
  int h = blockIdx.x, b = blockIdx.y;
  int t = threadIdx.x;
  const size_t rs = 3 * DIMC;
  const u16* src = qkv + (size_t)b * NTOK * rs + 2 * DIMC + h * HD;
  u16* dst = vtout + (size_t)(b * NHEAD + h) * HD * KP;
  for (int kt = 0; kt < KP / 64; kt++) {
    __syncthreads();
#pragma unroll
    for (int p = 0; p < 2; p++) {
      int idx = p * 256 + t;
      int row = idx >> 3, c = idx & 7;
      int tok = kt * 64 + row;
      uint4 v = make_uint4(0, 0, 0, 0);
      if (tok < NTOK) v = *reinterpret_cast<const uint4*>(src + (size_t)tok * rs + c * 8);
      *reinterpret_cast<uint4*>(&Vl[row * 72 + c * 8]) = v;
    }
    __syncthreads();
    int d = t & 63, tg = t >> 6;
    unsigned pu[8];
#pragma unroll
    for (int i = 0; i < 8; i++) {
      unsigned a = Vl[(tg * 16 + 2 * i) * 72 + d];
      unsigned bb2 = Vl[(tg * 16 + 2 * i + 1) * 72 + d];
      pu[i] = (bb2 << 16) | a;
    }
    uint4 o0 = make_uint4(pu[0], pu[1], pu[2], pu[3]);
    uint4 o1 = make_uint4(pu[4], pu[5], pu[6], pu[7]);
    u16* dp = dst + (size_t)d * KP + kt * 64 + tg * 16;
    *reinterpret_cast<uint4*>(dp) = o0;
    *reinterpret_cast<uint4*>(dp + 8) = o1;
  }
}

// ================= MFMA flash attention, swapped-operand (unchanged) =================
__device__ __forceinline__ int fsw(int row, int chunk) {
  return row * 64 + ((chunk ^ (row & 7)) << 3);
}
__device__ __forceinline__ void stage64(const u16* __restrict__ gsrc, size_t gstride,
                                        u16* lds, int w, int l) {
#pragma unroll
  for (int i = 0; i < 2; i++) {
    int r = w * 16 + i * 8 + (l >> 3);
    int c = l & 7;
    int scg = c ^ (r & 7);
    const u16* g = gsrc + (size_t)r * gstride + scg * 8;
#if HAVE_GLDS
    gl_lds16(g, &lds[(w * 16 + i * 8) * 64]);
#else
    *reinterpret_cast<uint4*>(&lds[r * 64 + c * 8]) = *reinterpret_cast<const uint4*>(g);
#endif
  }
}

__global__ __launch_bounds__(256) void flashm_k(const u16* __restrict__ qkv,
    const u16* __restrict__ vt, u16* __restrict__ o, int N, int kpad, float scale) {
  __shared__ u16 Qs[64 * 64], Ks[64 * 64], Vs[64 * 64];
  __shared__ u16 Ol[64 * 72];
  const int qt = blockIdx.x, h = blockIdx.y, b = blockIdx.z;
  const int t = threadIdx.x;
  const int w = t >> 6, l = t & 63;
  const int lr = l & 15, lk = l >> 4;
  const size_t rs = 3 * DIMC;
  const size_t qbase = (size_t)b * N * rs + h * HD;
  const u16* vbase = vt + (size_t)(b * NHEAD + h) * HD * kpad;

  stage64(qkv + qbase + (size_t)(qt * 64) * rs, rs, Qs, w, l);
  __syncthreads();
  bf16x8 bq0 = *reinterpret_cast<const bf16x8*>(&Qs[fsw(w * 16 + lr, lk)]);
  bf16x8 bq1 = *reinterpret_cast<const bf16x8*>(&Qs[fsw(w * 16 + lr, 4 + lk)]);

  float m_i = -1e30f, l_i = 0.f;
  f32x4 oacc[4];
#pragma unroll
  for (int mi = 0; mi < 4; mi++) oacc[mi] = (f32x4){0.f, 0.f, 0.f, 0.f};

  const int nkt = (kpad + 63) >> 6;
  for (int kt = 0; kt < nkt; kt++) {
    __syncthreads();
    stage64(qkv + qbase + DIMC + (size_t)(kt * 64) * rs, rs, Ks, w, l);
    stage64(vbase + kt * 64, (size_t)kpad, Vs, w, l);
    __syncthreads();

    f32x4 st[4];
#pragma unroll
    for (int mi = 0; mi < 4; mi++) st[mi] = (f32x4){0.f, 0.f, 0.f, 0.f};
#pragma unroll
    for (int mi = 0; mi < 4; mi++) {
      bf16x8 ak0 = *reinterpret_cast<const bf16x8*>(&Ks[fsw(mi * 16 + lr, lk)]);
      bf16x8 ak1 = *reinterpret_cast<const bf16x8*>(&Ks[fsw(mi * 16 + lr, 4 + lk)]);
      st[mi] = __builtin_amdgcn_mfma_f32_16x16x32_bf16(ak0, bq0, st[mi], 0, 0, 0);
      st[mi] = __builtin_amdgcn_mfma_f32_16x16x32_bf16(ak1, bq1, st[mi], 0, 0, 0);
    }

    float sv[4][4];
    float tmax = -1e30f;
#pragma unroll
    for (int mi = 0; mi < 4; mi++)
#pragma unroll
      for (int q = 0; q < 4; q++) {
        int kgl = kt * 64 + mi * 16 + lk * 4 + q;
        float v = (kgl < N) ? st[mi][q] * scale : -1e30f;
        sv[mi][q] = v;
        tmax = fmaxf(tmax, v);
      }
    tmax = fmaxf(tmax, __shfl_xor(tmax, 16));
    tmax = fmaxf(tmax, __shfl_xor(tmax, 32));
    float mn = fmaxf(m_i, tmax);
    float corr = __expf(m_i - mn);
    m_i = mn;
    float rsum = 0.f;
#pragma unroll
    for (int mi = 0; mi < 4; mi++)
#pragma unroll
      for (int q = 0; q < 4; q++) {
        float p = __expf(sv[mi][q] - mn);
        sv[mi][q] = p;
        rsum += p;
      }
    rsum += __shfl_xor(rsum, 16);
    rsum += __shfl_xor(rsum, 32);
    l_i = l_i * corr + rsum;
#pragma unroll
    for (int mi = 0; mi < 4; mi++) oacc[mi] *= corr;

    unsigned pk[4][2];
#pragma unroll
    for (int mi = 0; mi < 4; mi++) {
      pk[mi][0] = ((unsigned)f2b(sv[mi][1]) << 16) | (unsigned)f2b(sv[mi][0]);
      pk[mi][1] = ((unsigned)f2b(sv[mi][3]) << 16) | (unsigned)f2b(sv[mi][2]);
    }
    int src0 = lr + 32 * (lk & 1);
    int src1 = src0 + 16;
    bool hi = lk >= 2;
    bf16x8 pbv[2];
#pragma unroll
    for (int c = 0; c < 2; c++) {
      unsigned a0 = __shfl(pk[2 * c][0], src0), b0 = __shfl(pk[2 * c + 1][0], src0);
      unsigned a1 = __shfl(pk[2 * c][1], src0), b1 = __shfl(pk[2 * c + 1][1], src0);
      unsigned a2 = __shfl(pk[2 * c][0], src1), b2 = __shfl(pk[2 * c + 1][0], src1);
      unsigned a3 = __shfl(pk[2 * c][1], src1), b3 = __shfl(pk[2 * c + 1][1], src1);
      union { unsigned u[4]; bf16x8 v; } pu;
      pu.u[0] = hi ? b0 : a0;
      pu.u[1] = hi ? b1 : a1;
      pu.u[2] = hi ? b2 : a2;
      pu.u[3] = hi ? b3 : a3;
      pbv[c] = pu.v;
    }

#pragma unroll
    for (int mi = 0; mi < 4; mi++) {
      bf16x8 av0 = *reinterpret_cast<const bf16x8*>(&Vs[fsw(mi * 16 + lr, lk)]);
      bf16x8 av1 = *reinterpret_cast<const bf16x8*>(&Vs[fsw(mi * 16 + lr, 4 + lk)]);
      oacc[mi] = __builtin_amdgcn_mfma_f32_16x16x32_bf16(av0, pbv[0], oacc[mi], 0, 0, 0);
      oacc[mi] = __builtin_amdgcn_mfma_f32_16x16x32_bf16(av1, pbv[1], oacc[mi], 0, 0, 0);
    }
  }

  float invl = 1.0f / l_i;
#pragma unroll
  for (int mi = 0; mi < 4; mi++) {
    unsigned lo = ((unsigned)f2b(oacc[mi][1] * invl) << 16) | (unsigned)f2b(oacc[mi][0] * invl);
    unsigned hi2 = ((unsigned)f2b(oacc[mi][3] * invl) << 16) | (unsigned)f2b(oacc[mi][2] * invl);
    uint2 pr; pr.x = lo; pr.y = hi2;
    *reinterpret_cast<uint2*>(&Ol[(w * 16 + lr) * 72 + mi * 16 + lk * 4]) = pr;
  }
  __syncthreads();
  {
    int row = t >> 2, c4 = t & 3;
    int qrow = qt * 64 + row;
    if (qrow < N) {
      uint4 v0 = *reinterpret_cast<const uint4*>(&Ol[row * 72 + c4 * 8]);
      uint4 v1 = *reinterpret_cast<const uint4*>(&Ol[row * 72 + (c4 + 4) * 8]);
      u16* op = o + ((size_t)b * N + qrow) * DIMC + h * HD;
      *reinterpret_cast<uint4*>(op + c4 * 8) = v0;
      *reinterpret_cast<uint4*>(op + (c4 + 4) * 8) = v1;
    }
  }
}

// ---------------- head ----------------
__global__ __launch_bounds__(256) void head_k(const float* __restrict__ cls,
    const float* __restrict__ hw, const float* __restrict__ hb, float* __restrict__ out) {
  __shared__ float cl[1024];
  __shared__ float part[256];
  int b = blockIdx.x, t = threadIdx.x;
  for (int idx = t; idx < 1024; idx += 256) cl[idx] = cls[(size_t)b * 1024 + idx];
  __syncthreads();
  int c = t >> 4, sl = t & 15;
  float p = 0.f;
  for (int j = 0; j < 64; j++) p += cl[sl * 64 + j] * hw[(size_t)c * 1024 + sl * 64 + j];
  part[t] = p;
  __syncthreads();
  if (sl == 0) {
    float sum = hb[c];
    for (int q = 0; q < 16; q++) sum += part[c * 16 + q];
    out[(size_t)b * 16 + c] = sum;
  }
}

extern "C" void kernel_launch(void* const* d_in, const int* in_sizes, int n_in,
                              void* d_out, int out_size, void* d_ws, size_t ws_size,
                              hipStream_t stream) {
  const float* x        = (const float*)d_in[0];
  const float* conv_h_w = (const float*)d_in[1];
  const float* conv_h_b = (const float*)d_in[2];
  const float* bn_h_g   = (const float*)d_in[3];
  const float* bn_h_b   = (const float*)d_in[4];
  const float* bn_h_m   = (const float*)d_in[5];
  const float* bn_h_v   = (const float*)d_in[6];
  const float* cnn_conv_w = (const float*)d_in[7];
  const float* cnn_conv_b = (const float*)d_in[8];
  const float* cnn_bn_g = (const float*)d_in[9];
  const float* cnn_bn_b = (const float*)d_in[10];
  const float* cnn_bn_m = (const float*)d_in[11];
  const float* cnn_bn_v = (const float*)d_in[12];
  const float* cnn_fc_w = (const float*)d_in[13];
  const float* cnn_fc_b = (const float*)d_in[14];
  const float* spa_cls  = (const float*)d_in[15];
  const float* spe_cls  = (const float*)d_in[16];
  const float* spa_pos  = (const float*)d_in[17];
  const float* spe_pos  = (const float*)d_in[18];
  const float* blk_n1_w = (const float*)d_in[19];
  const float* blk_n1_b = (const float*)d_in[20];
  const float* blk_n2_w = (const float*)d_in[21];
  const float* blk_n2_b = (const float*)d_in[22];
  const float* blk_qkv_w = (const float*)d_in[23];
  const float* blk_qkv_b = (const float*)d_in[24];
  const float* blk_proj_w = (const float*)d_in[25];
  const float* blk_proj_b = (const float*)d_in[26];
  const float* blk_fc1_w = (const float*)d_in[27];
  const float* blk_fc1_b = (const float*)d_in[28];
  const float* blk_fc2_w = (const float*)d_in[29];
  const float* blk_fc2_b = (const float*)d_in[30];
  const float* norm1_w  = (const float*)d_in[31];
  const float* norm1_b  = (const float*)d_in[32];
  const float* norm2_w  = (const float*)d_in[33];
  const float* norm2_b  = (const float*)d_in[34];
  const float* head_w   = (const float*)d_in[35];
  const float* head_b   = (const float*)d_in[36];

  char* ws = (char*)d_ws;
  size_t off = 0;
  auto take = [&](size_t bytes) -> char* {
    char* p = ws + off;
    off = (off + bytes + 255) & ~(size_t)255;
    return p;
  };
  const int Mx = MXROWS, M2 = M2ROWS;
  const int Mc = NB * NPIX;   // 28800
  const int Mf = NB * BANDS;  // 3840
  float* xsc  = (float*)take((size_t)M2 * DIMC * 4);
  float* ysb  = xsc + (size_t)Mx * DIMC;
  u16* xyin   = (u16*)take((size_t)M2 * DIMC * 2);      // LN out; vtx overlays during attention
  u16* qkvxy  = (u16*)take((size_t)M2 * 3 * DIMC * 2);
  u16* oxy    = (u16*)take((size_t)M2 * DIMC * 2);
  u16* clsprj = (u16*)take((size_t)256 * DIMC * 2);
  float* clsb = (float*)take((size_t)NB * 1024 * 4);
  u16* pooled = (u16*)take((size_t)Mf * 128 * 2);
  u16* qkvWb  = (u16*)take((size_t)2 * 3 * DIMC * DIMC * 2);
  u16* projWb = (u16*)take((size_t)2 * DIMC * DIMC * 2);
  u16* fc1Wb  = (u16*)take((size_t)2 * DIMC * DIMC * 2);
  u16* fc2Wb  = (u16*)take((size_t)2 * DIMC * DIMC * 2);
  u16* fcWb   = (u16*)take((size_t)DIMC * 128 * 2);
  u16* convWb = (u16*)take((size_t)DIMC * KCONV * 2);
  float* bnsc = (float*)take(DIMC * 4);
  float* bnsh = (float*)take(DIMC * 4);
  u16* vty    = (u16*)take((size_t)NB * NHEAD * HD * 64 * 2);  // 8.4MB
  u16* Acol   = qkvxy;   // 28800*320*2 = 18.4MB << qkvxy
  u16* vtx    = xyin;    // 33.55MB <= xyin; xyin dead between qkv-GEMM and LN2

  // ---- weight prep ----
  cvt_k<<<1024, 256, 0, stream>>>(blk_qkv_w, qkvWb, 2 * 3 * DIMC * DIMC);
  cvt_k<<<1024, 256, 0, stream>>>(blk_proj_w, projWb, 2 * DIMC * DIMC);
  cvt_k<<<1024, 256, 0, stream>>>(blk_fc1_w, fc1Wb, 2 * DIMC * DIMC);
  cvt_k<<<1024, 256, 0, stream>>>(blk_fc2_w, fc2Wb, 2 * DIMC * DIMC);
  cvt_k<<<256, 256, 0, stream>>>(cnn_fc_w, fcWb, DIMC * 128);
  convw_k<<<(DIMC * KCONV + 255) / 256, 256, 0, stream>>>(conv_h_w, convWb);
  bnprep_k<<<2, 256, 0, stream>>>(bn_h_g, bn_h_b, bn_h_m, bn_h_v, conv_h_b, bnsc, bnsh);

  // ---- stem ----
  cls_init_k<<<NB, 256, 0, stream>>>(spa_cls, spe_cls, spa_pos, spe_pos, xsc, ysb);
  im2col_k<<<(Mc * 40 + 255) / 256, 256, 0, stream>>>(x, Acol);
  mgemm_k<3><<<dim3(4, Mc / 128), 256, 0, stream>>>(Acol, convWb, nullptr, xsc, nullptr,
      Mc, DIMC, KCONV, bnsc, bnsh, spa_pos);
  cnn_conv_k<<<Mf / 2, 256, 0, stream>>>(x, cnn_conv_w, cnn_conv_b, cnn_bn_g, cnn_bn_b,
                                         cnn_bn_m, cnn_bn_v, pooled);
  mgemm_k<4><<<dim3(4, Mf / 128), 256, 0, stream>>>(pooled, fcWb, cnn_fc_b, ysb, nullptr,
      Mf, DIMC, 128, spe_pos, nullptr, nullptr);

  // ---- transformer blocks ----
  for (int i = 0; i < 2; i++) {
    const float* n1w = blk_n1_w + i * DIMC;
    const float* n1b = blk_n1_b + i * DIMC;
    const float* n2w = blk_n2_w + i * DIMC;
    const float* n2b = blk_n2_b + i * DIMC;
    const u16* qkvW = qkvWb + (size_t)i * 3 * DIMC * DIMC;
    const float* qkvB = blk_qkv_b + (size_t)i * 3 * DIMC;
    const u16* projW = projWb + (size_t)i * DIMC * DIMC;
    const float* projB = blk_proj_b + (size_t)i * DIMC;
    const u16* fc1W = fc1Wb + (size_t)i * DIMC * DIMC;
    const float* fc1B = blk_fc1_b + (size_t)i * DIMC;
    const u16* fc2W = fc2Wb + (size_t)i * DIMC * DIMC;
    const float* fc2B = blk_fc2_b + (size_t)i * DIMC;

    ln_c_k<1><<<M2, 256, 0, stream>>>(xsc, n1w, n1b, xyin);

    mgemm_k<0><<<dim3(12, M2 / 128), 256, 0, stream>>>(xyin, qkvW, qkvB, nullptr, qkvxy,
        M2, 3 * DIMC, DIMC, nullptr, nullptr, nullptr);

    vt_k<NSPA, 256><<<dim3(NHEAD, NB), 256, 0, stream>>>(qkvxy, vtx);
    vt_k<NSPE, 64><<<dim3(NHEAD, NB), 256, 0, stream>>>(qkvxy + (size_t)Mx * 3 * DIMC, vty);

    flashm_k<<<dim3(4, NHEAD, NB), 256, 0, stream>>>(qkvxy, vtx, oxy, NSPA, 256, 0.125f);
    flashm_k<<<dim3(1, NHEAD, NB), 256, 0, stream>>>(qkvxy + (size_t)Mx * 3 * DIMC, vty,
                                                     oxy + (size_t)Mx * DIMC, NSPE, 64, 0.125f);

    mgemm_k<5><<<dim3(4, M2 / 128), 256, 0, stream>>>(oxy, projW, projB, xsc, clsprj,
        M2, DIMC, DIMC, nullptr, nullptr, nullptr);
    cls_swap_k<<<NB, 256, 0, stream>>>(xsc, clsprj);

    ln_c_k<0><<<M2, 256, 0, stream>>>(xsc, n2w, n2b, xyin);
    mgemm_k<1><<<dim3(4, M2 / 128), 256, 0, stream>>>(xyin, fc1W, fc1B, nullptr, qkvxy,
        M2, DIMC, DIMC, nullptr, nullptr, nullptr);
    mgemm_k<2><<<dim3(4, M2 / 128), 256, 0, stream>>>(qkvxy, fc2W, fc2B, xsc, nullptr,
        M2, DIMC, DIMC, xsc, nullptr, nullptr);
  }

  // ---- head ----
  ln_cls_k<<<NB * 2, 256, 0, stream>>>(xsc, ysb, norm1_w, norm1_b, norm2_w, norm2_b, clsb);
  head_k<<<NB, 256, 0, stream>>>(clsb, head_w, head_b, (float*)d_out);
}

// Round 7
// 830.701 us; speedup vs baseline: 6.3357x; 1.0506x over previous
//
#include <hip/hip_runtime.h>
#include <hip/hip_bf16.h>

typedef unsigned short u16;
typedef __attribute__((ext_vector_type(8))) short bf16x8;
typedef __attribute__((ext_vector_type(4))) float f32x4;

#define NB 128
#define BANDS 30
#define HWD 15
#define NPIX 225
#define DIMC 512
#define NHEAD 8
#define HD 64
#define NSPA 226
#define NSPE 31
#define EPSF 1e-5f
#define KCONV 320     // 270 padded to multiple of 64
#define MXROWS 28928  // NB*NSPA
#define MYROWS 3968   // NB*NSPE
#define M2ROWS 32896  // MXROWS+MYROWS

__device__ __forceinline__ float b2f(u16 u) { return __uint_as_float(((unsigned)u) << 16); }
__device__ __forceinline__ u16 f2b(float f) {
  __hip_bfloat16 h = __float2bfloat16(f);
  return *reinterpret_cast<u16*>(&h);
}

#if __has_builtin(__builtin_amdgcn_global_load_lds)
#define HAVE_GLDS 1
__device__ __forceinline__ void gl_lds16(const void* g, void* l) {
  __builtin_amdgcn_global_load_lds((const __attribute__((address_space(1))) void*)g,
                                   (__attribute__((address_space(3))) void*)l, 16, 0, 0);
}
#else
#define HAVE_GLDS 0
#endif

// ---------------- weight f32 -> bf16 ----------------
__global__ __launch_bounds__(256) void cvt_k(const float* __restrict__ s, u16* __restrict__ d, int n) {
  for (int i = blockIdx.x * 256 + threadIdx.x; i < n; i += gridDim.x * 256) d[i] = f2b(s[i]);
}

// conv_h_w (512,270) -> padded bf16 (512,320)
__global__ __launch_bounds__(256) void convw_k(const float* __restrict__ w, u16* __restrict__ d) {
  int i = blockIdx.x * 256 + threadIdx.x;
  if (i >= DIMC * KCONV) return;
  int r = i / KCONV, c = i - r * KCONV;
  d[i] = (c < 270) ? f2b(w[r * 270 + c]) : (u16)0;
}

// BN fold
__global__ __launch_bounds__(256) void bnprep_k(const float* __restrict__ g, const float* __restrict__ bb,
    const float* __restrict__ bm, const float* __restrict__ bv, const float* __restrict__ cb,
    float* __restrict__ sc, float* __restrict__ sh) {
  int n = blockIdx.x * 256 + threadIdx.x;
  if (n < DIMC) {
    float inv = g[n] * rsqrtf(bv[n] + EPSF);
    sc[n] = inv;
    sh[n] = (cb[n] - bm[n]) * inv + bb[n];
  }
}

// ---------------- im2col: x (128,30,15,15) f32 -> Acol (28800, 320) bf16 ----------------
__global__ __launch_bounds__(256) void im2col_k(const float* __restrict__ x, u16* __restrict__ Ac) {
  int idx = blockIdx.x * 256 + threadIdx.x;  // m*40 + g
  if (idx >= 28800 * 40) return;
  int m = idx / 40, g = idx - m * 40;
  int b = m / NPIX, p = m - b * NPIX;
  int i = p / 15, j = p - i * 15;
  union { u16 v[8]; uint4 u; } out;
#pragma unroll
  for (int e = 0; e < 8; e++) {
    int c = g * 8 + e;
    float v = 0.f;
    if (c < 270) {
      int band = c / 9, q = c - band * 9;
      int di = q / 3, dj = q - di * 3;
      int ii = i + di - 1, jj = j + dj - 1;
      if ((unsigned)ii < 15u && (unsigned)jj < 15u)
        v = x[((size_t)b * BANDS + band) * NPIX + ii * 15 + jj];
    }
    out.v[e] = f2b(v);
  }
  *reinterpret_cast<uint4*>(Ac + (size_t)m * KCONV + g * 8) = out.u;
}

// ---------------- CLS row init ----------------
__global__ __launch_bounds__(256) void cls_init_k(const float* __restrict__ spa_cls,
    const float* __restrict__ spe_cls, const float* __restrict__ spa_pos,
    const float* __restrict__ spe_pos, float* __restrict__ xs, float* __restrict__ ys) {
  int b = blockIdx.x, t = threadIdx.x;
  int d0 = t, d1 = t + 256;
  xs[(size_t)b * NSPA * DIMC + d0] = spa_cls[d0] + spa_pos[d0];
  xs[(size_t)b * NSPA * DIMC + d1] = spa_cls[d1] + spa_pos[d1];
  ys[(size_t)b * NSPE * DIMC + d0] = spe_cls[d0] + spe_pos[d0];
  ys[(size_t)b * NSPE * DIMC + d1] = spe_cls[d1] + spe_pos[d1];
}

// ------------- per-band CNN conv + BN + ReLU + mean (register-rolling rows) -------------
__global__ __launch_bounds__(256) void cnn_conv_k(const float* __restrict__ x,
    const float* __restrict__ w, const float* __restrict__ cb, const float* __restrict__ g,
    const float* __restrict__ bb, const float* __restrict__ bm, const float* __restrict__ bv,
    u16* __restrict__ pooled) {
  __shared__ float img[2][NPIX];
  int b0 = blockIdx.x * 2;
  int t = threadIdx.x;
  for (int idx = t; idx < 2 * NPIX; idx += 256) ((float*)img)[idx] = x[(size_t)b0 * NPIX + idx];
  __syncthreads();
  int half = t >> 7, ch = t & 127;
  const float* im = img[half];
  float inv = g[ch] * rsqrtf(bv[ch] + EPSF);
  float beta = bb[ch] - bm[ch] * inv;
  float w9[9];
#pragma unroll
  for (int q = 0; q < 9; q++) w9[q] = w[ch * 9 + q] * inv;
  float bias = cb[ch] * inv + beta;

  float rm[15], rc[15], rp[15];
#pragma unroll
  for (int j = 0; j < 15; j++) { rm[j] = 0.f; rc[j] = im[j]; }
  float sum = 0.f;
  for (int i = 0; i < 15; i++) {
#pragma unroll
    for (int j = 0; j < 15; j++) rp[j] = (i < 14) ? im[(i + 1) * 15 + j] : 0.f;
    float a[15];
#pragma unroll
    for (int j = 0; j < 15; j++) a[j] = fmaf(w9[4], rc[j], bias);
#pragma unroll
    for (int j = 0; j < 15; j++) {
      if (j > 0)  a[j] = fmaf(w9[3], rc[j - 1], a[j]);
      if (j < 14) a[j] = fmaf(w9[5], rc[j + 1], a[j]);
      a[j] = fmaf(w9[1], rm[j], a[j]);
      if (j > 0)  a[j] = fmaf(w9[0], rm[j - 1], a[j]);
      if (j < 14) a[j] = fmaf(w9[2], rm[j + 1], a[j]);
      a[j] = fmaf(w9[7], rp[j], a[j]);
      if (j > 0)  a[j] = fmaf(w9[6], rp[j - 1], a[j]);
      if (j < 14) a[j] = fmaf(w9[8], rp[j + 1], a[j]);
    }
#pragma unroll
    for (int j = 0; j < 15; j++) sum += fmaxf(a[j], 0.f);
#pragma unroll
    for (int j = 0; j < 15; j++) { rm[j] = rc[j]; rc[j] = rp[j]; }
  }
  pooled[(size_t)(b0 + half) * 128 + ch] = f2b(sum * (1.0f / 225.0f));
}

// ---------------- LayerNorm, wave-per-row, vectorized (4 rows/block) ----------------
template <int GATHER>
__global__ __launch_bounds__(256) void ln_v_k(const float* __restrict__ xsc,
    const float* __restrict__ w, const float* __restrict__ bprm, u16* __restrict__ out) {
  int wid = threadIdx.x >> 6, lane = threadIdx.x & 63;
  int row = blockIdx.x * 4 + wid;
  const float* src;
  if (GATHER) {
    if (row < MXROWS) {
      int b = row / NSPA, tk = row - b * NSPA;
      src = (tk == 0) ? xsc + ((size_t)MXROWS + (size_t)b * NSPE) * DIMC
                      : xsc + (size_t)row * DIMC;
    } else {
      int ry = row - MXROWS;
      int b = ry / NSPE, tk = ry - b * NSPE;
      src = (tk == 0) ? xsc + (size_t)b * NSPA * DIMC : xsc + (size_t)row * DIMC;
    }
  } else {
    src = xsc + (size_t)row * DIMC;
  }
  float4 a0 = *reinterpret_cast<const float4*>(src + lane * 8);
  float4 a1 = *reinterpret_cast<const float4*>(src + lane * 8 + 4);
  float s = a0.x + a0.y + a0.z + a0.w + a1.x + a1.y + a1.z + a1.w;
  float sq = a0.x * a0.x + a0.y * a0.y + a0.z * a0.z + a0.w * a0.w +
             a1.x * a1.x + a1.y * a1.y + a1.z * a1.z + a1.w * a1.w;
#pragma unroll
  for (int off = 1; off <= 32; off <<= 1) { s += __shfl_xor(s, off); sq += __shfl_xor(sq, off); }
  float mean = s * (1.0f / 512.0f);
  float var = sq * (1.0f / 512.0f) - mean * mean;
  float rstd = rsqrtf(var + EPSF);
  float4 w0 = *reinterpret_cast<const float4*>(w + lane * 8);
  float4 w1 = *reinterpret_cast<const float4*>(w + lane * 8 + 4);
  float4 b0 = *reinterpret_cast<const float4*>(bprm + lane * 8);
  float4 b1 = *reinterpret_cast<const float4*>(bprm + lane * 8 + 4);
  union { u16 v[8]; uint4 u; } r;
  r.v[0] = f2b((a0.x - mean) * rstd * w0.x + b0.x);
  r.v[1] = f2b((a0.y - mean) * rstd * w0.y + b0.y);
  r.v[2] = f2b((a0.z - mean) * rstd * w0.z + b0.z);
  r.v[3] = f2b((a0.w - mean) * rstd * w0.w + b0.w);
  r.v[4] = f2b((a1.x - mean) * rstd * w1.x + b1.x);
  r.v[5] = f2b((a1.y - mean) * rstd * w1.y + b1.y);
  r.v[6] = f2b((a1.z - mean) * rstd * w1.z + b1.z);
  r.v[7] = f2b((a1.w - mean) * rstd * w1.w + b1.w);
  *reinterpret_cast<uint4*>(out + (size_t)row * DIMC + lane * 8) = r.u;
}

// ---------------- final LN on CLS tokens -> f32 (B,1024) ----------------
__global__ __launch_bounds__(256) void ln_cls_k(const float* __restrict__ xs,
    const float* __restrict__ ys, const float* __restrict__ w1, const float* __restrict__ b1,
    const float* __restrict__ w2, const float* __restrict__ b2, float* __restrict__ cls) {
  int gb = blockIdx.x;
  int half = gb & 1, b = gb >> 1;
  const float* src = half ? (ys + (size_t)b * NSPE * DIMC) : (xs + (size_t)b * NSPA * DIMC);
  const float* w = half ? w2 : w1;
  const float* bp = half ? b2 : b1;
  int t = threadIdx.x;
  float x0 = src[t], x1 = src[t + 256];
  float s = x0 + x1, sq = x0 * x0 + x1 * x1;
  for (int off = 32; off; off >>= 1) { s += __shfl_down(s, off); sq += __shfl_down(sq, off); }
  __shared__ float sa[4], sb4[4];
  int wid = t >> 6;
  if ((t & 63) == 0) { sa[wid] = s; sb4[wid] = sq; }
  __syncthreads();
  s = sa[0] + sa[1] + sa[2] + sa[3];
  sq = sb4[0] + sb4[1] + sb4[2] + sb4[3];
  float mean = s * (1.0f / 512.0f);
  float var = sq * (1.0f / 512.0f) - mean * mean;
  float rstd = rsqrtf(var + EPSF);
  cls[(size_t)b * 1024 + half * DIMC + t] = (x0 - mean) * rstd * w[t] + bp[t];
  cls[(size_t)b * 1024 + half * DIMC + t + 256] = (x1 - mean) * rstd * w[t + 256] + bp[t + 256];
}

// ================= MFMA GEMM, BK=64, slot-XOR swizzle, XCD-chunked blocks (unchanged) =================
template <int MODE>
__global__ __launch_bounds__(256) void mgemm_k(const u16* __restrict__ A, const u16* __restrict__ Bw,
    const float* __restrict__ bias, float* outf, u16* outb, int M, int N, int K,
    const float* aux0, const float* aux1, const float* aux2) {
  __shared__ u16 As[128 * 64];
  __shared__ u16 Bs[128 * 64];
  const int t = threadIdx.x;
  const int wid = t >> 6, l = t & 63;
  const int wm = wid >> 1, wn = wid & 1;
  const int fr = l & 15, kg = l >> 4;

  const int nx = gridDim.x, nwg = nx * gridDim.y;
  int hlin = blockIdx.y * nx + blockIdx.x;
  int xcd = hlin & 7, j = hlin >> 3;
  int q8 = nwg >> 3, r8 = nwg & 7;
  int L = (xcd < r8 ? xcd * (q8 + 1) : r8 * (q8 + 1) + (xcd - r8) * q8) + j;
  const int n0 = (L % nx) * 128, m0 = (L / nx) * 128;

  const int srow = l >> 3;
  const int sslot = l & 7;

  f32x4 acc[4][4];
#pragma unroll
  for (int i = 0; i < 4; i++)
#pragma unroll
    for (int j2 = 0; j2 < 4; j2++) acc[i][j2] = (f32x4){0.f, 0.f, 0.f, 0.f};

  for (int kq = 0; kq < K; kq += 64) {
#if !HAVE_GLDS
    uint4 ra[4], rb[4];
#pragma unroll
    for (int i = 0; i < 4; i++) {
      int r = wid * 32 + i * 8 + srow;
      int cg = sslot ^ (r & 7);
      ra[i] = *reinterpret_cast<const uint4*>(A + (size_t)(m0 + r) * K + kq + cg * 8);
      rb[i] = *reinterpret_cast<const uint4*>(Bw + (size_t)(n0 + r) * K + kq + cg * 8);
    }
#endif
    __syncthreads();
#if HAVE_GLDS
#pragma unroll
    for (int i = 0; i < 4; i++) {
      int r = wid * 32 + i * 8 + srow;
      int cg = sslot ^ (r & 7);
      gl_lds16(A + (size_t)(m0 + r) * K + kq + cg * 8, &As[(wid * 32 + i * 8) * 64]);
      gl_lds16(Bw + (size_t)(n0 + r) * K + kq + cg * 8, &Bs[(wid * 32 + i * 8) * 64]);
    }
#else
#pragma unroll
    for (int i = 0; i < 4; i++) {
      int r = wid * 32 + i * 8 + srow;
      *reinterpret_cast<uint4*>(&As[r * 64 + sslot * 8]) = ra[i];
      *reinterpret_cast<uint4*>(&Bs[r * 64 + sslot * 8]) = rb[i];
    }
#endif
    __syncthreads();
#pragma unroll
    for (int h = 0; h < 2; h++) {
      bf16x8 af[4], bfr[4];
#pragma unroll
      for (int mi = 0; mi < 4; mi++) {
        int r = wm * 64 + mi * 16 + fr;
        af[mi] = *reinterpret_cast<const bf16x8*>(&As[r * 64 + (((h * 4 + kg) ^ (fr & 7)) * 8)]);
      }
#pragma unroll
      for (int nj = 0; nj < 4; nj++) {
        int n = wn * 64 + nj * 16 + fr;
        bfr[nj] = *reinterpret_cast<const bf16x8*>(&Bs[n * 64 + (((h * 4 + kg) ^ (fr & 7)) * 8)]);
      }
#pragma unroll
      for (int mi = 0; mi < 4; mi++)
#pragma unroll
        for (int nj = 0; nj < 4; nj++)
          acc[mi][nj] = __builtin_amdgcn_mfma_f32_16x16x32_bf16(af[mi], bfr[nj], acc[mi][nj], 0, 0, 0);
    }
  }

#pragma unroll
  for (int mi = 0; mi < 4; mi++) {
#pragma unroll
    for (int q = 0; q < 4; q++) {
      int m = m0 + wm * 64 + mi * 16 + kg * 4 + q;
#pragma unroll
      for (int nj = 0; nj < 4; nj++) {
        int n = n0 + wn * 64 + nj * 16 + fr;
        float v = acc[mi][nj][q];
        if (MODE == 0) {
          outb[(size_t)m * N + n] = f2b(v + bias[n]);
        } else if (MODE == 1) {
          float z = v + bias[n];
          outb[(size_t)m * N + n] = f2b(0.5f * z * (1.0f + erff(z * 0.70710678118f)));
        } else if (MODE == 2) {
          size_t idx = (size_t)m * N + n;
          outf[idx] = v + bias[n] + aux0[idx];
        } else if (MODE == 3) {
          int b = m / NPIX, p = m - b * NPIX;
          float z = fmaxf(v * aux0[n] + aux1[n], 0.f) + aux2[(size_t)(p + 1) * DIMC + n];
          outf[((size_t)b * NSPA + p + 1) * DIMC + n] = z;
        } else if (MODE == 4) {
          int b = m / BANDS, band = m - b * BANDS;
          float z = fmaxf(v + bias[n], 0.f) + aux0[(size_t)(band + 1) * DIMC + n];
          outf[((size_t)b * NSPE + band + 1) * DIMC + n] = z;
        } else if (MODE == 5) {
          float z = v + bias[n];
          int tk, sidx;
          if (m < MXROWS) {
            int b = m / NSPA; tk = m - b * NSPA; sidx = b;
          } else {
            int ry = m - MXROWS; int b = ry / NSPE; tk = ry - b * NSPE; sidx = 128 + b;
          }
          if (tk == 0) outb[(size_t)sidx * DIMC + n] = f2b(z);
          else outf[(size_t)m * N + n] += z;
        }
      }
    }
  }
}

// ---------------- CLS swap ----------------
__global__ __launch_bounds__(256) void cls_swap_k(float* __restrict__ xsc,
                                                  const u16* __restrict__ clsprj) {
  int b = blockIdx.x, t = threadIdx.x;
  size_t xrow = (size_t)b * NSPA * DIMC;
  size_t yrow = ((size_t)MXROWS + (size_t)b * NSPE) * DIMC;
#pragma unroll
  for (int q = 0; q < 2; q++) {
    int d = t + q * 256;
    xsc[xrow + d] = 2.0f * xsc[xrow + d] + b2f(clsprj[(size_t)(128 + b) * DIMC + d]);
    xsc[yrow + d] = 2.0f * xsc[yrow + d] + b2f(clsprj[(size_t)b * DIMC + d]);
  }
}

// ================= V transpose =================
template <int NTOK, int KP>
__global__ __launch_bounds__(256) void vt_k(const u16* __restrict__ qkv, u16* __restrict__ vtout) {
  __shared__ u16 Vl[64 * 72];
  int h = blockIdx.x, b = blockIdx.y;
  int t = threadIdx.x;
  const size_t rs = 3 * DIMC;
  const u16* src = qkv + (size_t)b * NTOK * rs + 2 * DIMC + h * HD;
  u16* dst = vtout + (size_t)(b * NHEAD + h) * HD * KP;
  for (int kt = 0; kt < KP / 64; kt++) {
    __syncthreads();
#pragma unroll
    for (int p = 0; p < 2; p++) {
      int idx = p * 256 + t;
      int row = idx >> 3, c = idx & 7;
      int tok = kt * 64 + row;
      uint4 v = make_uint4(0, 0, 0, 0);
      if (tok < NTOK) v = *reinterpret_cast<const uint4*>(src + (size_t)tok * rs + c * 8);
      *reinterpret_cast<uint4*>(&Vl[row * 72 + c * 8]) = v;
    }
    __syncthreads();
    int d = t & 63, tg = t >> 6;
    unsigned pu[8];
#pragma unroll
    for (int i = 0; i < 8; i++) {
      unsigned a = Vl[(tg * 16 + 2 * i) * 72 + d];
      unsigned bb2 = Vl[(tg * 16 + 2 * i + 1) * 72 + d];
      pu[i] = (bb2 << 16) | a;
    }
    uint4 o0 = make_uint4(pu[0], pu[1], pu[2], pu[3]);
    uint4 o1 = make_uint4(pu[4], pu[5], pu[6], pu[7]);
    u16* dp = dst + (size_t)d * KP + kt * 64 + tg * 16;
    *reinterpret_cast<uint4*>(dp) = o0;
    *reinterpret_cast<uint4*>(dp + 8) = o1;
  }
}

// ================= shared helpers for flash =================
__device__ __forceinline__ int fsw(int row, int chunk) {
  return row * 64 + ((chunk ^ (row & 7)) << 3);
}
__device__ __forceinline__ void stage64(const u16* __restrict__ gsrc, size_t gstride,
                                        u16* lds, int w, int l) {
#pragma unroll
  for (int i = 0; i < 2; i++) {
    int r = w * 16 + i * 8 + (l >> 3);
    int c = l & 7;
    int scg = c ^ (r & 7);
    const u16* g = gsrc + (size_t)r * gstride + scg * 8;
#if HAVE_GLDS
    gl_lds16(g, &lds[(w * 16 + i * 8) * 64]);
#else
    *reinterpret_cast<uint4*>(&lds[r * 64 + c * 8]) = *reinterpret_cast<const uint4*>(g);
#endif
  }
}

// ================= flashq: spa attention, wave owns a 64-row q-tile =================
// Block = (h, b); 4 waves; wave w owns q-rows w*64..w*64+63. kpad=256 (4 k-tiles).
__global__ __launch_bounds__(256) void flashq_k(const u16* __restrict__ qkv,
    const u16* __restrict__ vt, u16* __restrict__ o, int N, int kpad, float scale) {
  __shared__ u16 Qs[4][64 * 64];   // per-wave Q slice (8KB each)
  __shared__ u16 KV[2][64 * 64];   // K, V tiles; reused as Ol[64][72] in epilogue
  u16* Ks = KV[0];
  u16* Vs = KV[1];
  u16* Ol = KV[0];
  const int h = blockIdx.x, b = blockIdx.y;
  const int t = threadIdx.x;
  const int w = t >> 6, l = t & 63;
  const int lr = l & 15, lk = l >> 4;
  const size_t rs = 3 * DIMC;
  const size_t qbase = (size_t)b * N * rs + h * HD;
  const u16* vbase = vt + (size_t)(b * NHEAD + h) * HD * kpad;

  // ---- per-wave Q stage: 64 rows into own slice ----
#pragma unroll
  for (int i = 0; i < 8; i++) {
    int r = i * 8 + (l >> 3);
    int c = l & 7;
    int scg = c ^ (r & 7);
    const u16* g = qkv + qbase + (size_t)(w * 64 + r) * rs + scg * 8;
#if HAVE_GLDS
    gl_lds16(g, &Qs[w][(i * 8) * 64]);
#else
    *reinterpret_cast<uint4*>(&Qs[w][r * 64 + c * 8]) = *reinterpret_cast<const uint4*>(g);
#endif
  }
  __syncthreads();
  // hoist Q B-fragments (cols = q-rows of own tile)
  bf16x8 bq[4][2];
#pragma unroll
  for (int nj = 0; nj < 4; nj++) {
    bq[nj][0] = *reinterpret_cast<const bf16x8*>(&Qs[w][fsw(nj * 16 + lr, lk)]);
    bq[nj][1] = *reinterpret_cast<const bf16x8*>(&Qs[w][fsw(nj * 16 + lr, 4 + lk)]);
  }

  float m_i[4], l_i[4];
  f32x4 oacc[4][4];  // [mi=d-frag][nj=q-frag]
#pragma unroll
  for (int nj = 0; nj < 4; nj++) { m_i[nj] = -1e30f; l_i[nj] = 0.f; }
#pragma unroll
  for (int mi = 0; mi < 4; mi++)
#pragma unroll
    for (int nj = 0; nj < 4; nj++) oacc[mi][nj] = (f32x4){0.f, 0.f, 0.f, 0.f};

  const int nkt = kpad >> 6;
  for (int kt = 0; kt < nkt; kt++) {
    __syncthreads();
    stage64(qkv + qbase + DIMC + (size_t)(kt * 64) * rs, rs, Ks, w, l);
    stage64(vbase + kt * 64, (size_t)kpad, Vs, w, l);
    __syncthreads();

#pragma unroll
    for (int nj = 0; nj < 4; nj++) {
      // S^T = K · Q^T for this q-frag
      f32x4 st[4];
#pragma unroll
      for (int mi = 0; mi < 4; mi++) st[mi] = (f32x4){0.f, 0.f, 0.f, 0.f};
      __builtin_amdgcn_s_setprio(1);
#pragma unroll
      for (int mi = 0; mi < 4; mi++) {
        bf16x8 ak0 = *reinterpret_cast<const bf16x8*>(&Ks[fsw(mi * 16 + lr, lk)]);
        bf16x8 ak1 = *reinterpret_cast<const bf16x8*>(&Ks[fsw(mi * 16 + lr, 4 + lk)]);
        st[mi] = __builtin_amdgcn_mfma_f32_16x16x32_bf16(ak0, bq[nj][0], st[mi], 0, 0, 0);
        st[mi] = __builtin_amdgcn_mfma_f32_16x16x32_bf16(ak1, bq[nj][1], st[mi], 0, 0, 0);
      }
      __builtin_amdgcn_s_setprio(0);

      // online softmax: lane holds 16 k-values of ONE q-row
      float sv[4][4];
      float tmax = -1e30f;
#pragma unroll
      for (int mi = 0; mi < 4; mi++)
#pragma unroll
        for (int q = 0; q < 4; q++) {
          int kgl = kt * 64 + mi * 16 + lk * 4 + q;
          float v = (kgl < N) ? st[mi][q] * scale : -1e30f;
          sv[mi][q] = v;
          tmax = fmaxf(tmax, v);
        }
      tmax = fmaxf(tmax, __shfl_xor(tmax, 16));
      tmax = fmaxf(tmax, __shfl_xor(tmax, 32));
      float mn = fmaxf(m_i[nj], tmax);
      float corr = __expf(m_i[nj] - mn);
      m_i[nj] = mn;
      float rsum = 0.f;
#pragma unroll
      for (int mi = 0; mi < 4; mi++)
#pragma unroll
        for (int q = 0; q < 4; q++) {
          float p = __expf(sv[mi][q] - mn);
          sv[mi][q] = p;
          rsum += p;
        }
      rsum += __shfl_xor(rsum, 16);
      rsum += __shfl_xor(rsum, 32);
      l_i[nj] = l_i[nj] * corr + rsum;
#pragma unroll
      for (int mi = 0; mi < 4; mi++) oacc[mi][nj] *= corr;

      // pack P^T pairs, redistribute in-register to PV B-fragments
      unsigned pk[4][2];
#pragma unroll
      for (int mi = 0; mi < 4; mi++) {
        pk[mi][0] = ((unsigned)f2b(sv[mi][1]) << 16) | (unsigned)f2b(sv[mi][0]);
        pk[mi][1] = ((unsigned)f2b(sv[mi][3]) << 16) | (unsigned)f2b(sv[mi][2]);
      }
      int src0 = lr + 32 * (lk & 1);
      int src1 = src0 + 16;
      bool hi = lk >= 2;
      bf16x8 pbv[2];
#pragma unroll
      for (int c = 0; c < 2; c++) {
        unsigned a0 = __shfl(pk[2 * c][0], src0), b0 = __shfl(pk[2 * c + 1][0], src0);
        unsigned a1 = __shfl(pk[2 * c][1], src0), b1 = __shfl(pk[2 * c + 1][1], src0);
        unsigned a2 = __shfl(pk[2 * c][0], src1), b2 = __shfl(pk[2 * c + 1][0], src1);
        unsigned a3 = __shfl(pk[2 * c][1], src1), b3 = __shfl(pk[2 * c + 1][1], src1);
        union { unsigned u[4]; bf16x8 v; } pu;
        pu.u[0] = hi ? b0 : a0;
        pu.u[1] = hi ? b1 : a1;
        pu.u[2] = hi ? b2 : a2;
        pu.u[3] = hi ? b3 : a3;
        pbv[c] = pu.v;
      }

      // O^T += VT · P^T
      __builtin_amdgcn_s_setprio(1);
#pragma unroll
      for (int mi = 0; mi < 4; mi++) {
        bf16x8 av0 = *reinterpret_cast<const bf16x8*>(&Vs[fsw(mi * 16 + lr, lk)]);
        bf16x8 av1 = *reinterpret_cast<const bf16x8*>(&Vs[fsw(mi * 16 + lr, 4 + lk)]);
        oacc[mi][nj] = __builtin_amdgcn_mfma_f32_16x16x32_bf16(av0, pbv[0], oacc[mi][nj], 0, 0, 0);
        oacc[mi][nj] = __builtin_amdgcn_mfma_f32_16x16x32_bf16(av1, pbv[1], oacc[mi][nj], 0, 0, 0);
      }
      __builtin_amdgcn_s_setprio(0);
    }
  }

  // ---- epilogue: 4 passes; wave `pass` dumps O^T -> Ol, all waves write global ----
  float invl[4];
#pragma unroll
  for (int nj = 0; nj < 4; nj++) invl[nj] = 1.0f / l_i[nj];
  for (int pass = 0; pass < 4; pass++) {
    __syncthreads();  // Ol region free (Vs reads / previous pass reads done)
    if (w == pass) {
#pragma unroll
      for (int mi = 0; mi < 4; mi++)
#pragma unroll
        for (int nj = 0; nj < 4; nj++) {
          unsigned lo = ((unsigned)f2b(oacc[mi][nj][1] * invl[nj]) << 16) |
                        (unsigned)f2b(oacc[mi][nj][0] * invl[nj]);
          unsigned hi2 = ((unsigned)f2b(oacc[mi][nj][3] * invl[nj]) << 16) |
                         (unsigned)f2b(oacc[mi][nj][2] * invl[nj]);
          uint2 pr; pr.x = lo; pr.y = hi2;
          *reinterpret_cast<uint2*>(&Ol[(nj * 16 + lr) * 72 + mi * 16 + lk * 4]) = pr;
        }
    }
    __syncthreads();
    int row = t >> 2, c4 = t & 3;
    int qrow = pass * 64 + row;
    if (qrow < N) {
      uint4 v0 = *reinterpret_cast<const uint4*>(&Ol[row * 72 + c4 * 8]);
      uint4 v1 = *reinterpret_cast<const uint4*>(&Ol[row * 72 + (c4 + 4) * 8]);
      u16* op = o + ((size_t)b * N + qrow) * DIMC + h * HD;
      *reinterpret_cast<uint4*>(op + c4 * 8) = v0;
      *reinterpret_cast<uint4*>(op + (c4 + 4) * 8) = v1;
    }
  }
}

// ================= flashm: spe attention (verified round-5 kernel, unchanged) =================
__global__ __launch_bounds__(256) void flashm_k(const u16* __restrict__ qkv,
    const u16* __restrict__ vt, u16* __restrict__ o, int N, int kpad, float scale) {
  __shared__ u16 Qs[64 * 64], Ks[64 * 64], Vs[64 * 64];
  __shared__ u16 Ol[64 * 72];
  const int qt = blockIdx.x, h = blockIdx.y, b = blockIdx.z;
  const int t = threadIdx.x;
  const int w = t >> 6, l = t & 63;
  const int lr = l & 15, lk = l >> 4;
  const size_t rs = 3 * DIMC;
  const size_t qbase = (size_t)b * N * rs + h * HD;
  const u16* vbase = vt + (size_t)(b * NHEAD + h) * HD * kpad;

  stage64(qkv + qbase + (size_t)(qt * 64) * rs, rs, Qs, w, l);
  __syncthreads();
  bf16x8 bq0 = *reinterpret_cast<const bf16x8*>(&Qs[fsw(w * 16 + lr, lk)]);
  bf16x8 bq1 = *reinterpret_cast<const bf16x8*>(&Qs[fsw(w * 16 + lr, 4 + lk)]);

  float m_i = -1e30f, l_i = 0.f;
  f32x4 oacc[4];
#pragma unroll
  for (int mi = 0; mi < 4; mi++) oacc[mi] = (f32x4){0.f, 0.f, 0.f, 0.f};

  const int nkt = (kpad + 63) >> 6;
  for (int kt = 0; kt < nkt; kt++) {
    __syncthreads();
    stage64(qkv + qbase + DIMC + (size_t)(kt * 64) * rs, rs, Ks, w, l);
    stage64(vbase + kt * 64, (size_t)kpad, Vs, w, l);
    __syncthreads();

    f32x4 st[4];
#pragma unroll
    for (int mi = 0; mi < 4; mi++) st[mi] = (f32x4){0.f, 0.f, 0.f, 0.f};
#pragma unroll
    for (int mi = 0; mi < 4; mi++) {
      bf16x8 ak0 = *reinterpret_cast<const bf16x8*>(&Ks[fsw(mi * 16 + lr, lk)]);
      bf16x8 ak1 = *reinterpret_cast<const bf16x8*>(&Ks[fsw(mi * 16 + lr, 4 + lk)]);
      st[mi] = __builtin_amdgcn_mfma_f32_16x16x32_bf16(ak0, bq0, st[mi], 0, 0, 0);
      st[mi] = __builtin_amdgcn_mfma_f32_16x16x32_bf16(ak1, bq1, st[mi], 0, 0, 0);
    }

    float sv[4][4];
    float tmax = -1e30f;
#pragma unroll
    for (int mi = 0; mi < 4; mi++)
#pragma unroll
      for (int q = 0; q < 4; q++) {
        int kgl = kt * 64 + mi * 16 + lk * 4 + q;
        float v = (kgl < N) ? st[mi][q] * scale : -1e30f;
        sv[mi][q] = v;
        tmax = fmaxf(tmax, v);
      }
    tmax = fmaxf(tmax, __shfl_xor(tmax, 16));
    tmax = fmaxf(tmax, __shfl_xor(tmax, 32));
    float mn = fmaxf(m_i, tmax);
    float corr = __expf(m_i - mn);
    m_i = mn;
    float rsum = 0.f;
#pragma unroll
    for (int mi = 0; mi < 4; mi++)
#pragma unroll
      for (int q = 0; q < 4; q++) {
        float p = __expf(sv[mi][q] - mn);
        sv[mi][q] = p;
        rsum += p;
      }
    rsum += __shfl_xor(rsum, 16);
    rsum += __shfl_xor(rsum, 32);
    l_i = l_i * corr + rsum;
#pragma unroll
    for (int mi = 0; mi < 4; mi++) oacc[mi] *= corr;

    unsigned pk[4][2];
#pragma unroll
    for (int mi = 0; mi < 4; mi++) {
      pk[mi][0] = ((unsigned)f2b(sv[mi][1]) << 16) | (unsigned)f2b(sv[mi][0]);
      pk[mi][1] = ((unsigned)f2b(sv[mi][3]) << 16) | (unsigned)f2b(sv[mi][2]);
    }
    int src0 = lr + 32 * (lk & 1);
    int src1 = src0 + 16;
    bool hi = lk >= 2;
    bf16x8 pbv[2];
#pragma unroll
    for (int c = 0; c < 2; c++) {
      unsigned a0 = __shfl(pk[2 * c][0], src0), b0 = __shfl(pk[2 * c + 1][0], src0);
      unsigned a1 = __shfl(pk[2 * c][1], src0), b1 = __shfl(pk[2 * c + 1][1], src0);
      unsigned a2 = __shfl(pk[2 * c][0], src1), b2 = __shfl(pk[2 * c + 1][0], src1);
      unsigned a3 = __shfl(pk[2 * c][1], src1), b3 = __shfl(pk[2 * c + 1][1], src1);
      union { unsigned u[4]; bf16x8 v; } pu;
      pu.u[0] = hi ? b0 : a0;
      pu.u[1] = hi ? b1 : a1;
      pu.u[2] = hi ? b2 : a2;
      pu.u[3] = hi ? b3 : a3;
      pbv[c] = pu.v;
    }

#pragma unroll
    for (int mi = 0; mi < 4; mi++) {
      bf16x8 av0 = *reinterpret_cast<const bf16x8*>(&Vs[fsw(mi * 16 + lr, lk)]);
      bf16x8 av1 = *reinterpret_cast<const bf16x8*>(&Vs[fsw(mi * 16 + lr, 4 + lk)]);
      oacc[mi] = __builtin_amdgcn_mfma_f32_16x16x32_bf16(av0, pbv[0], oacc[mi], 0, 0, 0);
      oacc[mi] = __builtin_amdgcn_mfma_f32_16x16x32_bf16(av1, pbv[1], oacc[mi], 0, 0, 0);
    }
  }

  float invl = 1.0f / l_i;
#pragma unroll
  for (int mi = 0; mi < 4; mi++) {
    unsigned lo = ((unsigned)f2b(oacc[mi][1] * invl) << 16) | (unsigned)f2b(oacc[mi][0] * invl);
    unsigned hi2 = ((unsigned)f2b(oacc[mi][3] * invl) << 16) | (unsigned)f2b(oacc[mi][2] * invl);
    uint2 pr; pr.x = lo; pr.y = hi2;
    *reinterpret_cast<uint2*>(&Ol[(w * 16 + lr) * 72 + mi * 16 + lk * 4]) = pr;
  }
  __syncthreads();
  {
    int row = t >> 2, c4 = t & 3;
    int qrow = qt * 64 + row;
    if (qrow < N) {
      uint4 v0 = *reinterpret_cast<const uint4*>(&Ol[row * 72 + c4 * 8]);
      uint4 v1 = *reinterpret_cast<const uint4*>(&Ol[row * 72 + (c4 + 4) * 8]);
      u16* op = o + ((size_t)b * N + qrow) * DIMC + h * HD;
      *reinterpret_cast<uint4*>(op + c4 * 8) = v0;
      *reinterpret_cast<uint4*>(op + (c4 + 4) * 8) = v1;
    }
  }
}

// ---------------- head ----------------
__global__ __launch_bounds__(256) void head_k(const float* __restrict__ cls,
    const float* __restrict__ hw, const float* __restrict__ hb, float* __restrict__ out) {
  __shared__ float cl[1024];
  __shared__ float part[256];
  int b = blockIdx.x, t = threadIdx.x;
  for (int idx = t; idx < 1024; idx += 256) cl[idx] = cls[(size_t)b * 1024 + idx];
  __syncthreads();
  int c = t >> 4, sl = t & 15;
  float p = 0.f;
  for (int j = 0; j < 64; j++) p += cl[sl * 64 + j] * hw[(size_t)c * 1024 + sl * 64 + j];
  part[t] = p;
  __syncthreads();
  if (sl == 0) {
    float sum = hb[c];
    for (int q = 0; q < 16; q++) sum += part[c * 16 + q];
    out[(size_t)b * 16 + c] = sum;
  }
}

extern "C" void kernel_launch(void* const* d_in, const int* in_sizes, int n_in,
                              void* d_out, int out_size, void* d_ws, size_t ws_size,
                              hipStream_t stream) {
  const float* x        = (const float*)d_in[0];
  const float* conv_h_w = (const float*)d_in[1];
  const float* conv_h_b = (const float*)d_in[2];
  const float* bn_h_g   = (const float*)d_in[3];
  const float* bn_h_b   = (const float*)d_in[4];
  const float* bn_h_m   = (const float*)d_in[5];
  const float* bn_h_v   = (const float*)d_in[6];
  const float* cnn_conv_w = (const float*)d_in[7];
  const float* cnn_conv_b = (const float*)d_in[8];
  const float* cnn_bn_g = (const float*)d_in[9];
  const float* cnn_bn_b = (const float*)d_in[10];
  const float* cnn_bn_m = (const float*)d_in[11];
  const float* cnn_bn_v = (const float*)d_in[12];
  const float* cnn_fc_w = (const float*)d_in[13];
  const float* cnn_fc_b = (const float*)d_in[14];
  const float* spa_cls  = (const float*)d_in[15];
  const float* spe_cls  = (const float*)d_in[16];
  const float* spa_pos  = (const float*)d_in[17];
  const float* spe_pos  = (const float*)d_in[18];
  const float* blk_n1_w = (const float*)d_in[19];
  const float* blk_n1_b = (const float*)d_in[20];
  const float* blk_n2_w = (const float*)d_in[21];
  const float* blk_n2_b = (const float*)d_in[22];
  const float* blk_qkv_w = (const float*)d_in[23];
  const float* blk_qkv_b = (const float*)d_in[24];
  const float* blk_proj_w = (const float*)d_in[25];
  const float* blk_proj_b = (const float*)d_in[26];
  const float* blk_fc1_w = (const float*)d_in[27];
  const float* blk_fc1_b = (const float*)d_in[28];
  const float* blk_fc2_w = (const float*)d_in[29];
  const float* blk_fc2_b = (const float*)d_in[30];
  const float* norm1_w  = (const float*)d_in[31];
  const float* norm1_b  = (const float*)d_in[32];
  const float* norm2_w  = (const float*)d_in[33];
  const float* norm2_b  = (const float*)d_in[34];
  const float* head_w   = (const float*)d_in[35];
  const float* head_b   = (const float*)d_in[36];

  char* ws = (char*)d_ws;
  size_t off = 0;
  auto take = [&](size_t bytes) -> char* {
    char* p = ws + off;
    off = (off + bytes + 255) & ~(size_t)255;
    return p;
  };
  const int Mx = MXROWS, M2 = M2ROWS;
  const int Mc = NB * NPIX;   // 28800
  const int Mf = NB * BANDS;  // 3840
  float* xsc  = (float*)take((size_t)M2 * DIMC * 4);
  float* ysb  = xsc + (size_t)Mx * DIMC;
  u16* xyin   = (u16*)take((size_t)M2 * DIMC * 2);      // LN out; vtx overlays during attention
  u16* qkvxy  = (u16*)take((size_t)M2 * 3 * DIMC * 2);
  u16* oxy    = (u16*)take((size_t)M2 * DIMC * 2);
  u16* clsprj = (u16*)take((size_t)256 * DIMC * 2);
  float* clsb = (float*)take((size_t)NB * 1024 * 4);
  u16* pooled = (u16*)take((size_t)Mf * 128 * 2);
  u16* qkvWb  = (u16*)take((size_t)2 * 3 * DIMC * DIMC * 2);
  u16* projWb = (u16*)take((size_t)2 * DIMC * DIMC * 2);
  u16* fc1Wb  = (u16*)take((size_t)2 * DIMC * DIMC * 2);
  u16* fc2Wb  = (u16*)take((size_t)2 * DIMC * DIMC * 2);
  u16* fcWb   = (u16*)take((size_t)DIMC * 128 * 2);
  u16* convWb = (u16*)take((size_t)DIMC * KCONV * 2);
  float* bnsc = (float*)take(DIMC * 4);
  float* bnsh = (float*)take(DIMC * 4);
  u16* vty    = (u16*)take((size_t)NB * NHEAD * HD * 64 * 2);  // 8.4MB
  u16* Acol   = qkvxy;   // 18.4MB << qkvxy
  u16* vtx    = xyin;    // 33.55MB <= xyin; xyin dead between qkv-GEMM and LN2

  // ---- weight prep ----
  cvt_k<<<1024, 256, 0, stream>>>(blk_qkv_w, qkvWb, 2 * 3 * DIMC * DIMC);
  cvt_k<<<1024, 256, 0, stream>>>(blk_proj_w, projWb, 2 * DIMC * DIMC);
  cvt_k<<<1024, 256, 0, stream>>>(blk_fc1_w, fc1Wb, 2 * DIMC * DIMC);
  cvt_k<<<1024, 256, 0, stream>>>(blk_fc2_w, fc2Wb, 2 * DIMC * DIMC);
  cvt_k<<<256, 256, 0, stream>>>(cnn_fc_w, fcWb, DIMC * 128);
  convw_k<<<(DIMC * KCONV + 255) / 256, 256, 0, stream>>>(conv_h_w, convWb);
  bnprep_k<<<2, 256, 0, stream>>>(bn_h_g, bn_h_b, bn_h_m, bn_h_v, conv_h_b, bnsc, bnsh);

  // ---- stem ----
  cls_init_k<<<NB, 256, 0, stream>>>(spa_cls, spe_cls, spa_pos, spe_pos, xsc, ysb);
  im2col_k<<<(Mc * 40 + 255) / 256, 256, 0, stream>>>(x, Acol);
  mgemm_k<3><<<dim3(4, Mc / 128), 256, 0, stream>>>(Acol, convWb, nullptr, xsc, nullptr,
      Mc, DIMC, KCONV, bnsc, bnsh, spa_pos);
  cnn_conv_k<<<Mf / 2, 256, 0, stream>>>(x, cnn_conv_w, cnn_conv_b, cnn_bn_g, cnn_bn_b,
                                         cnn_bn_m, cnn_bn_v, pooled);
  mgemm_k<4><<<dim3(4, Mf / 128), 256, 0, stream>>>(pooled, fcWb, cnn_fc_b, ysb, nullptr,
      Mf, DIMC, 128, spe_pos, nullptr, nullptr);

  // ---- transformer blocks ----
  for (int i = 0; i < 2; i++) {
    const float* n1w = blk_n1_w + i * DIMC;
    const float* n1b = blk_n1_b + i * DIMC;
    const float* n2w = blk_n2_w + i * DIMC;
    const float* n2b = blk_n2_b + i * DIMC;
    const u16* qkvW = qkvWb + (size_t)i * 3 * DIMC * DIMC;
    const float* qkvB = blk_qkv_b + (size_t)i * 3 * DIMC;
    const u16* projW = projWb + (size_t)i * DIMC * DIMC;
    const float* projB = blk_proj_b + (size_t)i * DIMC;
    const u16* fc1W = fc1Wb + (size_t)i * DIMC * DIMC;
    const float* fc1B = blk_fc1_b + (size_t)i * DIMC;
    const u16* fc2W = fc2Wb + (size_t)i * DIMC * DIMC;
    const float* fc2B = blk_fc2_b + (size_t)i * DIMC;

    ln_v_k<1><<<M2 / 4, 256, 0, stream>>>(xsc, n1w, n1b, xyin);

    mgemm_k<0><<<dim3(12, M2 / 128), 256, 0, stream>>>(xyin, qkvW, qkvB, nullptr, qkvxy,
        M2, 3 * DIMC, DIMC, nullptr, nullptr, nullptr);

    vt_k<NSPA, 256><<<dim3(NHEAD, NB), 256, 0, stream>>>(qkvxy, vtx);
    vt_k<NSPE, 64><<<dim3(NHEAD, NB), 256, 0, stream>>>(qkvxy + (size_t)Mx * 3 * DIMC, vty);

    flashq_k<<<dim3(NHEAD, NB), 256, 0, stream>>>(qkvxy, vtx, oxy, NSPA, 256, 0.125f);
    flashm_k<<<dim3(1, NHEAD, NB), 256, 0, stream>>>(qkvxy + (size_t)Mx * 3 * DIMC, vty,
                                                     oxy + (size_t)Mx * DIMC, NSPE, 64, 0.125f);

    mgemm_k<5><<<dim3(4, M2 / 128), 256, 0, stream>>>(oxy, projW, projB, xsc, clsprj,
        M2, DIMC, DIMC, nullptr, nullptr, nullptr);
    cls_swap_k<<<NB, 256, 0, stream>>>(xsc, clsprj);

    ln_v_k<0><<<M2 / 4, 256, 0, stream>>>(xsc, n2w, n2b, xyin);
    mgemm_k<1><<<dim3(4, M2 / 128), 256, 0, stream>>>(xyin, fc1W, fc1B, nullptr, qkvxy,
        M2, DIMC, DIMC, nullptr, nullptr, nullptr);
    mgemm_k<2><<<dim3(4, M2 / 128), 256, 0, stream>>>(qkvxy, fc2W, fc2B, xsc, nullptr,
        M2, DIMC, DIMC, xsc, nullptr, nullptr);
  }

  // ---- head ----
  ln_cls_k<<<NB * 2, 256, 0, stream>>>(xsc, ysb, norm1_w, norm1_b, norm2_w, norm2_b, clsb);
  head_k<<<NB, 256, 0, stream>>>(clsb, head_w, head_b, (float*)d_out);
}